// Round 3
// baseline (1644.608 us; speedup 1.0000x reference)
//
#include <hip/hip_runtime.h>
#include <math.h>

// ---------------- constants ----------------
constexpr int B_ = 4, T_ = 1024, C_ = 768, H_ = 12, N_ = 64;
constexpr int BT_ = B_ * T_;                    // 4096
constexpr size_t BTC = (size_t)BT_ * C_;        // 3145728
constexpr float EPS_GN = 0.00064f;
constexpr int NCH = 16;                         // chunks per sequence (1024/64)
constexpr int HC_ = 48 * NCH;                   // 768 head-chunks

typedef __attribute__((ext_vector_type(8))) short bf16x8;
typedef __attribute__((ext_vector_type(4))) float f32x4;
typedef __attribute__((ext_vector_type(4))) unsigned short u16x4;
typedef __attribute__((ext_vector_type(8))) unsigned short u16x8;

#define DEVFN static __device__ __forceinline__

DEVFN unsigned short f2bf(float f) {
    unsigned u = __float_as_uint(f);
    unsigned r = u + 0x7FFFu + ((u >> 16) & 1u);
    return (unsigned short)(r >> 16);
}
DEVFN float bf2f(unsigned short u) { return __uint_as_float(((unsigned)u) << 16); }

template<int CTRL>
DEVFN float dppadd(float x) {
    return x + __int_as_float(__builtin_amdgcn_update_dpp(0, __float_as_int(x), CTRL, 0xF, 0xF, true));
}
#define SWZ_ADD(x, imm) ((x) + __int_as_float(__builtin_amdgcn_ds_swizzle(__float_as_int(x), (imm))))

DEVFN float red64(float x) {
    x = dppadd<0xB1>(x);
    x = dppadd<0x4E>(x);
    x = SWZ_ADD(x, 0x101F);
    x = SWZ_ADD(x, 0x201F);
    x = SWZ_ADD(x, 0x401F);
    x += __shfl_xor(x, 32, 64);
    return x;
}

DEVFN f32x4 mfma16(bf16x8 a, bf16x8 b, f32x4 c) {
    return __builtin_amdgcn_mfma_f32_16x16x32_bf16(a, b, c, 0, 0, 0);
}

// full 64x64x64 GEMM for one wave from LDS [64][72] bf16 operands; ACCUMULATES into acc
DEVFN void wave_gemm64(const unsigned short (*A)[72], const unsigned short (*Bt)[72],
                       f32x4 acc[4][4], int lane) {
    int l15 = lane & 15, l16 = lane >> 4;
#pragma unroll
    for (int kk2 = 0; kk2 < 2; ++kk2) {
        bf16x8 af[4], bfv[4];
#pragma unroll
        for (int m = 0; m < 4; ++m) af[m] = *(const bf16x8*)&A[m * 16 + l15][kk2 * 32 + l16 * 8];
#pragma unroll
        for (int n = 0; n < 4; ++n) bfv[n] = *(const bf16x8*)&Bt[n * 16 + l15][kk2 * 32 + l16 * 8];
#pragma unroll
        for (int m = 0; m < 4; ++m)
#pragma unroll
            for (int n = 0; n < 4; ++n)
                acc[m][n] = mfma16(af[m], bfv[n], acc[m][n]);
    }
}

// ---------------- kernel 1: timeshift + 6 mixes -> bf16 ----------------
__global__ __launch_bounds__(256) void k_prep(const float* __restrict__ x,
    const float* __restrict__ m0, const float* __restrict__ m1, const float* __restrict__ m2,
    const float* __restrict__ m3, const float* __restrict__ m4, const float* __restrict__ m5,
    unsigned short* __restrict__ X6)
{
    int gid = blockIdx.x * 256 + threadIdx.x;
    int i4 = gid * 4;
    int bt = i4 / C_;
    int c  = i4 - bt * C_;
    const float4 xv = *(const float4*)(x + (size_t)bt * C_ + c);
    float px = 0.f, py = 0.f, pz = 0.f, pw = 0.f;
    if ((bt % T_) != 0) {
        const float4 p = *(const float4*)(x + (size_t)(bt - 1) * C_ + c);
        px = p.x; py = p.y; pz = p.z; pw = p.w;
    }
    float d0 = px - xv.x, d1 = py - xv.y, d2 = pz - xv.z, d3 = pw - xv.w;
    const float* mixes[6] = {m0, m1, m2, m3, m4, m5};
#pragma unroll
    for (int m = 0; m < 6; ++m) {
        const float4 mv = *(const float4*)(mixes[m] + c);
        u16x4 pk;
        pk[0] = f2bf(fmaf(d0, mv.x, xv.x));
        pk[1] = f2bf(fmaf(d1, mv.y, xv.y));
        pk[2] = f2bf(fmaf(d2, mv.z, xv.z));
        pk[3] = f2bf(fmaf(d3, mv.w, xv.w));
        *(u16x4*)(X6 + (size_t)m * BTC + (size_t)bt * C_ + c) = pk;
    }
}

// ---------------- kernel 2: fp32 W[R][Cc] -> bf16 W^T[Cc][R] ----------------
__global__ __launch_bounds__(256) void k_transpose(const float* __restrict__ W,
    unsigned short* __restrict__ WT, int R, int Cc)
{
    __shared__ float tile[32][33];
    int tx = threadIdx.x & 31, ty = threadIdx.x >> 5;
#pragma unroll
    for (int j = 0; j < 4; ++j) {
        int rr = blockIdx.y * 32 + ty + j * 8;
        int cc = blockIdx.x * 32 + tx;
        tile[ty + j * 8][tx] = W[(size_t)rr * Cc + cc];
    }
    __syncthreads();
#pragma unroll
    for (int j = 0; j < 4; ++j) {
        int ro = blockIdx.x * 32 + ty + j * 8;
        int co = blockIdx.y * 32 + tx;
        WT[(size_t)ro * R + co] = f2bf(tile[tx][ty + j * 8]);
    }
}

// ---------------- kernel 3: bf16 GEMM  C[M][Nn] = A[M][K] @ Bt[Nn][K]^T ----------------
template<int EPI>
__global__ __launch_bounds__(256) void k_gemm(const unsigned short* __restrict__ A,
    const unsigned short* __restrict__ Bt, void* __restrict__ Cp,
    const float* __restrict__ bias, int M, int Nn, int K)
{
    __shared__ unsigned short As[64][40];
    __shared__ unsigned short Bs[64][40];
    const int t = threadIdx.x, lane = t & 63, wave = t >> 6;
    const int wr = wave >> 1, wc = wave & 1;
    const int bM = blockIdx.y * 64, bN = blockIdx.x * 64;
    const int srow = t >> 2, skc = (t & 3) * 8;
    const int l15 = lane & 15, l16 = lane >> 4;
    f32x4 acc[2][2] = {};

    for (int k0 = 0; k0 < K; k0 += 32) {
        __syncthreads();
        *(int4*)&As[srow][skc] = *(const int4*)(A + (size_t)(bM + srow) * K + k0 + skc);
        *(int4*)&Bs[srow][skc] = *(const int4*)(Bt + (size_t)(bN + srow) * K + k0 + skc);
        __syncthreads();
        bf16x8 af0 = *(const bf16x8*)&As[wr * 32 + l15][l16 * 8];
        bf16x8 af1 = *(const bf16x8*)&As[wr * 32 + 16 + l15][l16 * 8];
        bf16x8 bf0 = *(const bf16x8*)&Bs[wc * 32 + l15][l16 * 8];
        bf16x8 bf1 = *(const bf16x8*)&Bs[wc * 32 + 16 + l15][l16 * 8];
        acc[0][0] = mfma16(af0, bf0, acc[0][0]);
        acc[0][1] = mfma16(af0, bf1, acc[0][1]);
        acc[1][0] = mfma16(af1, bf0, acc[1][0]);
        acc[1][1] = mfma16(af1, bf1, acc[1][1]);
    }

#pragma unroll
    for (int fm = 0; fm < 2; ++fm)
#pragma unroll
        for (int fn = 0; fn < 2; ++fn)
#pragma unroll
            for (int jj = 0; jj < 4; ++jj) {
                int gr = bM + wr * 32 + fm * 16 + l16 * 4 + jj;
                int gc = bN + wc * 32 + fn * 16 + l15;
                float val = acc[fm][fn][jj];
                size_t oi = (size_t)gr * Nn + gc;
                if constexpr (EPI == 0) {
                    ((float*)Cp)[oi] = val;
                } else if constexpr (EPI == 1) {
                    ((unsigned short*)Cp)[oi] = f2bf(val);
                } else if constexpr (EPI == 2) {
                    ((unsigned short*)Cp)[oi] = f2bf(tanhf(val));
                } else if constexpr (EPI == 3) {
                    float z = bias[gc] + val;
                    float sg = 1.f / (1.f + expf(-z));
                    ((float*)Cp)[oi] = expf(-0.60653065971f * sg);
                } else if constexpr (EPI == 4) {
                    float z = bias[gc] + val;
                    ((float*)Cp)[oi] = 1.f / (1.f + expf(-z));
                } else {
                    ((unsigned short*)Cp)[oi] = f2bf(1.f / (1.f + expf(-val)));
                }
            }
}

// ---------------- kernel 4: kk normalize + k update + bonus dot ----------------
__global__ __launch_bounds__(256) void k_kproc(float* __restrict__ k, const float* __restrict__ a,
    const float* __restrict__ r, const float* __restrict__ k_k, const float* __restrict__ k_a,
    const float* __restrict__ r_k, float* __restrict__ kk, float* __restrict__ dotb)
{
    int gw = blockIdx.x * 4 + (threadIdx.x >> 6);
    int lane = threadIdx.x & 63;
    int bt = gw / H_, h = gw - (gw / H_) * H_;
    int c = h * 64 + lane;
    size_t idx = (size_t)bt * C_ + c;
    float kv = k[idx], av = a[idx], rv = r[idx];
    float kkv = kv * k_k[c];
    float ss = red64(kkv * kkv);
    float inv = 1.f / fmaxf(sqrtf(ss), 1e-12f);
    kk[idx] = kkv * inv;
    float knew = kv * (1.f + (av - 1.f) * k_a[c]);
    k[idx] = knew;
    float dot = red64(rv * knew * r_k[c]);
    if (lane == 0) dotb[bt * H_ + h] = dot;
}

// ---------------- F1a: per head-chunk cumprod + transforms -> bf16 ----------------
// Abf = cw_{t-1} * (-kk)   Bbf = kk*a / cw_t   Kbf = k / cw_t   Rbf = r * cw_t
__global__ __launch_bounds__(256) void k_scanprep(const float* __restrict__ wdec,
    const float* __restrict__ kk, const float* __restrict__ asig, const float* __restrict__ kupd,
    const float* __restrict__ r, unsigned short* __restrict__ Abf, unsigned short* __restrict__ Bbf,
    unsigned short* __restrict__ Kbf, unsigned short* __restrict__ Rbf, float* __restrict__ cwL)
{
    __shared__ float CW[64][68];
    int hc = blockIdx.x;
    int g = hc >> 4, c = hc & 15;
    int b = g / H_, h = g - (g / H_) * H_;
    size_t rowb = ((size_t)(b * T_ + c * 64)) * C_ + h * 64;
    int tid = threadIdx.x;
    int t = tid >> 2, j0 = (tid & 3) * 16;
#pragma unroll
    for (int e = 0; e < 16; e += 4)
        *(float4*)&CW[t][j0 + e] = *(const float4*)(wdec + rowb + (size_t)t * C_ + j0 + e);
    __syncthreads();
    if (tid < 64) {
        float cp = 1.f;
#pragma unroll 4
        for (int tt = 0; tt < 64; ++tt) { cp *= CW[tt][tid]; CW[tt][tid] = cp; }
        cwL[hc * 64 + tid] = CW[63][tid];
    }
    __syncthreads();
    size_t base = (size_t)hc * 4096 + t * 64;
    size_t gin = rowb + (size_t)t * C_;
#pragma uroll
    for (int e4 = 0; e4 < 4; ++e4) {
        u16x4 pa, pb, pk, pr;
#pragma unroll
        for (int e = 0; e < 4; ++e) {
            int j = j0 + e4 * 4 + e;
            float cwt = CW[t][j];
            float cwm = t ? CW[t - 1][j] : 1.f;
            float inv = 1.f / cwt;
            float kkv = kk[gin + j], av = asig[gin + j];
            pa[e] = f2bf(-kkv * cwm);
            pb[e] = f2bf(kkv * av * inv);
            pk[e] = f2bf(kupd[gin + j] * inv);
            pr[e] = f2bf(r[gin + j] * cwt);
        }
        int j = j0 + e4 * 4;
        *(u16x4*)(Abf + base + j) = pa;
        *(u16x4*)(Bbf + base + j) = pb;
        *(u16x4*)(Kbf + base + j) = pk;
        *(u16x4*)(Rbf + base + j) = pr;
    }
}

// ---------------- F1b: Gram matrices G(f32,strict) H,P,Q(bf16) ----------------
__global__ __launch_bounds__(256) void k_gram(const unsigned short* __restrict__ Abf,
    const unsigned short* __restrict__ Bbf, const unsigned short* __restrict__ Kbf,
    const unsigned short* __restrict__ Rbf, float* __restrict__ Gf,
    unsigned short* __restrict__ Hbf, unsigned short* __restrict__ Pbf, unsigned short* __restrict__ Qbf)
{
    __shared__ unsigned short SA[4][64][72];
    int hc = blockIdx.x, tid = threadIdx.x;
    size_t base = (size_t)hc * 4096;
    int r = tid >> 2, c0 = (tid & 3) * 16;
    const unsigned short* srcs[4] = {Abf, Bbf, Kbf, Rbf};
#pragma unroll
    for (int bu = 0; bu < 4; ++bu) {
        *(int4*)&SA[bu][r][c0]     = *(const int4*)(srcs[bu] + base + r * 64 + c0);
        *(int4*)&SA[bu][r][c0 + 8] = *(const int4*)(srcs[bu] + base + r * 64 + c0 + 8);
    }
    __syncthreads();
    int wave = tid >> 6, lane = tid & 63;
    int l15 = lane & 15, l16 = lane >> 4;
    const unsigned short (*Aop)[72] = (wave < 2) ? SA[0] : SA[3];
    const unsigned short (*Bop)[72] = (wave & 1) ? SA[2] : SA[1];
    f32x4 acc[4][4] = {};
    wave_gemm64(Aop, Bop, acc, lane);
    bool strict = (wave < 2);
#pragma unroll
    for (int m = 0; m < 4; ++m)
#pragma unroll
        for (int n = 0; n < 4; ++n)
#pragma unroll
            for (int jj = 0; jj < 4; ++jj) {
                int tt = m * 16 + l16 * 4 + jj;
                int ss = n * 16 + l15;
                float val = acc[m][n][jj];
                bool keep = strict ? (tt > ss) : (tt >= ss);
                val = keep ? val : 0.f;
                size_t oi = base + (size_t)tt * 64 + ss;
                if (wave == 0) Gf[oi] = val;
                else if (wave == 1) Hbf[oi] = f2bf(val);
                else if (wave == 2) Pbf[oi] = f2bf(val);
                else Qbf[oi] = f2bf(val);
            }
}

// ---------------- F2: U0rhs = H_strict V ; solve X = (I-G)^-1 [A | U0rhs] ----------------
__global__ __launch_bounds__(128) void k_solve(const float* __restrict__ Gf,
    const unsigned short* __restrict__ Hbf, const unsigned short* __restrict__ Abf,
    const float* __restrict__ vbuf, unsigned short* __restrict__ Wtbf, unsigned short* __restrict__ U0tbf)
{
    __shared__ float Xl[64][132];
    __shared__ char ubuf[18432];
    unsigned short (*Hs)[72]  = (unsigned short (*)[72])ubuf;
    unsigned short (*Vts)[72] = (unsigned short (*)[72])(ubuf + 9216);
    float (*Gs)[68] = (float (*)[68])ubuf;

    int hc = blockIdx.x, tid = threadIdx.x;
    int g = hc >> 4, c = hc & 15;
    int b = g / H_, h = g - (g / H_) * H_;
    size_t rowb = ((size_t)(b * T_ + c * 64)) * C_ + h * 64;
    size_t base = (size_t)hc * 4096;

    // stage H (row-major) and V^T (transposed from vbuf)
    {
        int rr = tid >> 1, cc0 = (tid & 1) * 32;
#pragma unroll
        for (int q = 0; q < 4; ++q)
            *(int4*)&Hs[rr][cc0 + q * 8] = *(const int4*)(Hbf + base + rr * 64 + cc0 + q * 8);
#pragma unroll
        for (int q = 0; q < 8; ++q) {
            float4 v4 = *(const float4*)(vbuf + rowb + (size_t)rr * C_ + cc0 + q * 4);
            Vts[cc0 + q * 4 + 0][rr] = f2bf(v4.x);
            Vts[cc0 + q * 4 + 1][rr] = f2bf(v4.y);
            Vts[cc0 + q * 4 + 2][rr] = f2bf(v4.z);
            Vts[cc0 + q * 4 + 3][rr] = f2bf(v4.w);
        }
    }
    __syncthreads();
    // HV via MFMA: 2 waves, wave w does rows [w*32, w*32+32)
    {
        int wave = tid >> 6, lane = tid & 63;
        int l15 = lane & 15, l16 = lane >> 4;
        f32x4 acc[2][4] = {};
#pragma unroll
        for (int kk2 = 0; kk2 < 2; ++kk2) {
            bf16x8 af[2], bfv[4];
#pragma unroll
            for (int m = 0; m < 2; ++m) af[m] = *(const bf16x8*)&Hs[wave * 32 + m * 16 + l15][kk2 * 32 + l16 * 8];
#pragma unroll
            for (int n = 0; n < 4; ++n) bfv[n] = *(const bf16x8*)&Vts[n * 16 + l15][kk2 * 32 + l16 * 8];
#pragma unroll
            for (int m = 0; m < 2; ++m)
#pragma unroll
                for (int n = 0; n < 4; ++n)
                    acc[m][n] = mfma16(af[m], bfv[n], acc[m][n]);
        }
        __syncthreads();   // HV reads done; ubuf will be reused for G
#pragma unroll
        for (int m = 0; m < 2; ++m)
#pragma unroll
            for (int n = 0; n < 4; ++n)
#pragma unroll
                for (int jj = 0; jj < 4; ++jj) {
                    int tt = wave * 32 + m * 16 + l16 * 4 + jj;
                    int dd = n * 16 + l15;
                    Xl[tt][64 + dd] = acc[m][n][jj];
                }
    }
    // stage A-RHS (bf16->f32) and G
    {
        int rr = tid >> 1, cc0 = (tid & 1) * 32;
#pragma unroll
        for (int q = 0; q < 4; ++q) {
            u16x8 va = *(const u16x8*)(Abf + base + rr * 64 + cc0 + q * 8);
#pragma unroll
            for (int e = 0; e < 8; ++e) Xl[rr][cc0 + q * 8 + e] = bf2f(va[e]);
        }
#pragma unroll
        for (int q = 0; q < 8; ++q)
            *(float4*)&Gs[rr][cc0 + q * 4] = *(const float4*)(Gf + base + rr * 64 + cc0 + q * 4);
    }
    __syncthreads();
    // forward substitution, column d = tid in registers
    float x[64];
#pragma unroll
    for (int tt = 0; tt < 64; ++tt) x[tt] = Xl[tt][tid];
#pragma unroll
    for (int tt = 1; tt < 64; ++tt) {
        float a0 = 0.f, a1 = 0.f, a2 = 0.f, a3 = 0.f;
#pragma unroll
        for (int sq = 0; sq < 16; ++sq) {
            float4 g4 = *(const float4*)&Gs[tt][sq * 4];
            a0 = fmaf(g4.x, x[sq * 4 + 0], a0);
            a1 = fmaf(g4.y, x[sq * 4 + 1], a1);
            a2 = fmaf(g4.z, x[sq * 4 + 2], a2);
            a3 = fmaf(g4.w, x[sq * 4 + 3], a3);
        }
        x[tt] += (a0 + a1) + (a2 + a3);
    }
    // write transposed rows: thread d -> Wt[d][*] or U0t[d-64][*]
    unsigned short* dst = (tid < 64) ? (Wtbf + base + (size_t)tid * 64)
                                     : (U0tbf + base + (size_t)(tid - 64) * 64);
#pragma unroll
    for (int q = 0; q < 8; ++q) {
        u16x8 p;
#pragma unroll
        for (int e = 0; e < 8; ++e) p[e] = f2bf(x[q * 8 + e]);
        *(u16x8*)(dst + q * 8) = p;
    }
}

// ---------------- F3: combine -> Tt(bf16,transposed), Z(f32), E(bf16), F(bf16) ----------------
__global__ __launch_bounds__(256) void k_combine(const unsigned short* __restrict__ Pbf,
    const unsigned short* __restrict__ Qbf, const unsigned short* __restrict__ Wtbf,
    const unsigned short* __restrict__ U0tbf, const unsigned short* __restrict__ Bbf,
    const unsigned short* __restrict__ Kbf, const unsigned short* __restrict__ Rbf,
    const float* __restrict__ vbuf, const float* __restrict__ cwL,
    unsigned short* __restrict__ Ttbf, float* __restrict__ Zf,
    unsigned short* __restrict__ Ebf, unsigned short* __restrict__ Fbf)
{
    __shared__ unsigned short S7[7][64][72];   // 0=P 1=Q 2=Wt 3=U0t 4=Bt 5=Kt 6=Vt
    int hc = blockIdx.x, tid = threadIdx.x;
    int g = hc >> 4, c = hc & 15;
    int b = g / H_, h = g - (g / H_) * H_;
    size_t rowb = ((size_t)(b * T_ + c * 64)) * C_ + h * 64;
    size_t base = (size_t)hc * 4096;
    int r = tid >> 2, c0 = (tid & 3) * 16;
    const unsigned short* rm[4] = {Pbf, Qbf, Wtbf, U0tbf};
#pragma unroll
    for (int bu = 0; bu < 4; ++bu) {
        *(int4*)&S7[bu][r][c0]     = *(const int4*)(rm[bu] + base + r * 64 + c0);
        *(int4*)&S7[bu][r][c0 + 8] = *(const int4*)(rm[bu] + base + r * 64 + c0 + 8);
    }
    {   // transposed: Bt <- Bbf, Kt <- Kbf, Vt <- vbuf
        u16x8 vb0 = *(const u16x8*)(Bbf + base + r * 64 + c0);
        u16x8 vb1 = *(const u16x8*)(Bbf + base + r * 64 + c0 + 8);
        u16x8 vk0 = *(const u16x8*)(Kbf + base + r * 64 + c0);
        u16x8 vk1 = *(const u16x8*)(Kbf + base + r * 64 + c0 + 8);
#pragma unroll
        for (int e = 0; e < 8; ++e) {
            S7[4][c0 + e][r] = vb0[e];
            S7[4][c0 + 8 + e][r] = vb1[e];
            S7[5][c0 + e][r] = vk0[e];
            S7[5][c0 + 8 + e][r] = vk1[e];
        }
#pragma unroll
        for (int q = 0; q < 4; ++q) {
            float4 v4 = *(const float4*)(vbuf + rowb + (size_t)r * C_ + c0 + q * 4);
            S7[6][c0 + q * 4 + 0][r] = f2bf(v4.x);
            S7[6][c0 + q * 4 + 1][r] = f2bf(v4.y);
            S7[6][c0 + q * 4 + 2][r] = f2bf(v4.z);
            S7[6][c0 + q * 4 + 3][r] = f2bf(v4.w);
        }
    }
    __syncthreads();
    int wave = tid >> 6, lane = tid & 63;
    int l15 = lane & 15, l16 = lane >> 4;
    f32x4 acc[4][4] = {};
    if (wave == 0) wave_gemm64(S7[2], S7[4], acc, lane);                                   // W^T Bh
    else if (wave == 1) { wave_gemm64(S7[3], S7[4], acc, lane); wave_gemm64(S7[6], S7[5], acc, lane); } // U0^T Bh + V^T Kh
    else if (wave == 2) wave_gemm64(S7[0], S7[2], acc, lane);                              // P W
    else { wave_gemm64(S7[0], S7[3], acc, lane); wave_gemm64(S7[1], S7[6], acc, lane); }   // P U0 + Q V
#pragma unroll
    for (int m = 0; m < 4; ++m)
#pragma unroll
        for (int n = 0; n < 4; ++n)
#pragma unroll
            for (int jj = 0; jj < 4; ++jj) {
                int ro = m * 16 + l16 * 4 + jj;
                int co = n * 16 + l15;
                float val = acc[m][n][jj];
                if (wave == 0) {
                    val = (val + (ro == co ? 1.f : 0.f)) * cwL[hc * 64 + co];
                    Ttbf[base + (size_t)co * 64 + ro] = f2bf(val);
                } else if (wave == 1) {
                    Zf[base + (size_t)ro * 64 + co] = val * cwL[hc * 64 + co];
                } else if (wave == 2) {
                    val += bf2f(Rbf[base + (size_t)ro * 64 + co]);
                    Ebf[base + (size_t)ro * 64 + co] = f2bf(val);
                } else {
                    Fbf[base + (size_t)ro * 64 + co] = f2bf(val);
                }
            }
}

// ---------------- F4: per-head serial chunk recursion S <- S T + Z ----------------
__global__ __launch_bounds__(256) void k_phaseB(const unsigned short* __restrict__ Ttbf,
    const float* __restrict__ Zf, unsigned short* __restrict__ Sbf)
{
    __shared__ unsigned short Sb[2][64][72];
    __shared__ unsigned short Tt[64][72];
    int g = blockIdx.x, tid = threadIdx.x;
    int r = tid >> 2, c0 = (tid & 3) * 16;
    int4 z4 = {0, 0, 0, 0};
    *(int4*)&Sb[0][r][c0] = z4;
    *(int4*)&Sb[0][r][c0 + 8] = z4;
    int cur = 0;
    int wave = tid >> 6, lane = tid & 63;
    int wr = wave >> 1, wc = wave & 1;
    int l15 = lane & 15, l16 = lane >> 4;
    for (int c = 0; c < NCH; ++c) {
        size_t base = ((size_t)g * NCH + c) * 4096;
        __syncthreads();
        *(int4*)(Sbf + base + r * 64 + c0)     = *(int4*)&Sb[cur][r][c0];
        *(int4*)(Sbf + base + r * 64 + c0 + 8) = *(int4*)&Sb[cur][r][c0 + 8];
        *(int4*)&Tt[r][c0]     = *(const int4*)(Ttbf + base + r * 64 + c0);
        *(int4*)&Tt[r][c0 + 8] = *(const int4*)(Ttbf + base + r * 64 + c0 + 8);
        __syncthreads();
        f32x4 acc[2][2] = {};
#pragma unroll
        for (int kk2 = 0; kk2 < 2; ++kk2) {
            bf16x8 af[2], bfv[2];
#pragma unroll
            for (int m = 0; m < 2; ++m) af[m] = *(const bf16x8*)&Sb[cur][wr * 32 + m * 16 + l15][kk2 * 32 + l16 * 8];
#pragma unroll
            for (int n = 0; n < 2; ++n) bfv[n] = *(const bf16x8*)&Tt[wc * 32 + n * 16 + l15][kk2 * 32 + l16 * 8];
#pragma unroll
            for (int m = 0; m < 2; ++m)
#pragma unroll
                for (int n = 0; n < 2; ++n)
                    acc[m][n] = mfma16(af[m], bfv[n], acc[m][n]);
        }
#pragma unroll
        for (int m = 0; m < 2; ++m)
#pragma unroll
            for (int n = 0; n < 2; ++n)
#pragma unroll
                for (int jj = 0; jj < 4; ++jj) {
                    int ro = wr * 32 + m * 16 + l16 * 4 + jj;
                    int co = wc * 32 + n * 16 + l15;
                    float val = acc[m][n][jj] + Zf[base + (size_t)ro * 64 + co];
                    Sb[cur ^ 1][ro][co] = f2bf(val);
                }
        cur ^= 1;
    }
}

// ---------------- F5: O = E S0^T + F -> obuf ----------------
__global__ __launch_bounds__(256) void k_phaseC(const unsigned short* __restrict__ Ebf,
    const unsigned short* __restrict__ Sbf, const unsigned short* __restrict__ Fbf,
    float* __restrict__ obuf)
{
    __shared__ unsigned short Es[64][72], Ss[64][72];
    int hc = blockIdx.x, tid = threadIdx.x;
    int g = hc >> 4, c = hc & 15;
    int b = g / H_, h = g - (g / H_) * H_;
    size_t rowb = ((size_t)(b * T_ + c * 64)) * C_ + h * 64;
    size_t base = (size_t)hc * 4096;
    int r = tid >> 2, c0 = (tid & 3) * 16;
    *(int4*)&Es[r][c0]     = *(const int4*)(Ebf + base + r * 64 + c0);
    *(int4*)&Es[r][c0 + 8] = *(const int4*)(Ebf + base + r * 64 + c0 + 8);
    *(int4*)&Ss[r][c0]     = *(const int4*)(Sbf + base + r * 64 + c0);
    *(int4*)&Ss[r][c0 + 8] = *(const int4*)(Sbf + base + r * 64 + c0 + 8);
    __syncthreads();
    int wave = tid >> 6, lane = tid & 63;
    int wr = wave >> 1, wc = wave & 1;
    int l15 = lane & 15, l16 = lane >> 4;
    f32x4 acc[2][2] = {};
#pragma unroll
    for (int kk2 = 0; kk2 < 2; ++kk2) {
        bf16x8 af[2], bfv[2];
#pragma unroll
        for (int m = 0; m < 2; ++m) af[m] = *(const bf16x8*)&Es[wr * 32 + m * 16 + l15][kk2 * 32 + l16 * 8];
#pragma unroll
        for (int n = 0; n < 2; ++n) bfv[n] = *(const bf16x8*)&Ss[wc * 32 + n * 16 + l15][kk2 * 32 + l16 * 8];
#pragma unroll
        for (int m = 0; m < 2; ++m)
#pragma unroll
            for (int n = 0; n < 2; ++n)
                acc[m][n] = mfma16(af[m], bfv[n], acc[m][n]);
    }
#pragma unroll
    for (int m = 0; m < 2; ++m)
#pragma unroll
        for (int n = 0; n < 2; ++n)
#pragma unroll
            for (int jj = 0; jj < 4; ++jj) {
                int tt = wr * 32 + m * 16 + l16 * 4 + jj;
                int ii = wc * 32 + n * 16 + l15;
                float val = acc[m][n][jj] + bf2f(Fbf[base + (size_t)tt * 64 + ii]);
                obuf[rowb + (size_t)tt * C_ + ii] = val;
            }
}

// ---------------- kernel 6: groupnorm + bonus + gate -> bf16 ----------------
__global__ __launch_bounds__(256) void k_gnorm(const float* __restrict__ o,
    const float* __restrict__ v, const float* __restrict__ g, const float* __restrict__ dotb,
    const float* __restrict__ gamma, const float* __restrict__ beta,
    unsigned short* __restrict__ yb)
{
    int gw = blockIdx.x * 4 + (threadIdx.x >> 6);
    int lane = threadIdx.x & 63;
    int bt = gw / H_, h = gw - (gw / H_) * H_;
    int c = h * 64 + lane;
    size_t idx = (size_t)bt * C_ + c;
    float ov = o[idx];
    float mean = red64(ov) * 0.015625f;
    float d = ov - mean;
    float var = red64(d * d) * 0.015625f;
    float yn = d * rsqrtf(var + EPS_GN) * gamma[c] + beta[c];
    float dot = dotb[bt * H_ + h];
    float y = (yn + dot * v[idx]) * g[idx];
    yb[idx] = f2bf(y);
}

// ---------------- host ----------------
extern "C" void kernel_launch(void* const* d_in, const int* in_sizes, int n_in,
                              void* d_out, int out_size, void* d_ws, size_t ws_size,
                              hipStream_t stream)
{
    (void)in_sizes; (void)n_in; (void)out_size; (void)ws_size;
    const float* x   = (const float*)d_in[0];
    const float* mr  = (const float*)d_in[1];
    const float* mw  = (const float*)d_in[2];
    const float* mk  = (const float*)d_in[3];
    const float* mv  = (const float*)d_in[4];
    const float* ma  = (const float*)d_in[5];
    const float* mg  = (const float*)d_in[6];
    const float* w0  = (const float*)d_in[7];
    const float* w1  = (const float*)d_in[8];
    const float* w2  = (const float*)d_in[9];
    const float* a0  = (const float*)d_in[10];
    const float* a1  = (const float*)d_in[11];
    const float* a2  = (const float*)d_in[12];
    const float* g1  = (const float*)d_in[13];
    const float* g2  = (const float*)d_in[14];
    const float* k_k = (const float*)d_in[15];
    const float* k_a = (const float*)d_in[16];
    const float* r_k = (const float*)d_in[17];
    const float* Wr  = (const float*)d_in[18];
    const float* Wk  = (const float*)d_in[19];
    const float* Wv  = (const float*)d_in[20];
    const float* Wo  = (const float*)d_in[21];
    const float* gam = (const float*)d_in[22];
    const float* bet = (const float*)d_in[23];

    char* ws = (char*)d_ws;
    constexpr size_t SZF = BTC * 4;
    constexpr size_t SZH = BTC * 2;
    // X6 region: 6 SZH slots
    unsigned short* X6  = (unsigned short*)ws;
    unsigned short* Abf = (unsigned short*)(ws + 0 * SZH);
    unsigned short* Bbf = (unsigned short*)(ws + 1 * SZH);
    unsigned short* Kbf = (unsigned short*)(ws + 2 * SZH);
    unsigned short* Rbf = (unsigned short*)(ws + 3 * SZH);
    float*          Gf  = (float*)(ws + 4 * SZH);
    // F3+ aliases inside X6 region
    unsigned short* Ttbf = Abf;                          // over A (dead after solve)
    float*          Zf   = Gf;                           // over G (dead after solve)
    float*          obuf = (float*)(ws + 1 * SZH);       // over B,K (dead after combine)
    unsigned short* ybf  = (unsigned short*)(ws + 3 * SZH); // over R (dead after combine)

    size_t off = 6 * SZH;
    unsigned short* WrT = (unsigned short*)(ws + off); off += (size_t)768 * 768 * 2;
    unsigned short* WkT = (unsigned short*)(ws + off); off += (size_t)768 * 768 * 2;
    unsigned short* WvT = (unsigned short*)(ws + off); off += (size_t)768 * 768 * 2;
    unsigned short* WoT = (unsigned short*)(ws + off); off += (size_t)768 * 768 * 2;
    unsigned short* w1T = (unsigned short*)(ws + off); off += (size_t)64 * 768 * 2;
    unsigned short* w2T = (unsigned short*)(ws + off); off += (size_t)64 * 768 * 2;
    unsigned short* a1T = (unsigned short*)(ws + off); off += (size_t)64 * 768 * 2;
    unsigned short* a2T = (unsigned short*)(ws + off); off += (size_t)64 * 768 * 2;
    unsigned short* g1T = (unsigned short*)(ws + off); off += (size_t)128 * 768 * 2;
    unsigned short* g2T = (unsigned short*)(ws + off); off += (size_t)128 * 768 * 2;
    float* rbuf  = (float*)(ws + off); off += SZF;
    float* kbuf  = (float*)(ws + off); off += SZF;
    float* vbuf  = (float*)(ws + off); off += SZF;
    float* wdec  = (float*)(ws + off); off += SZF;
    float* abuf  = (float*)(ws + off); off += SZF;
    float* kkbuf = (float*)(ws + off); off += SZF;
    float* gbuf  = (float*)(ws + off); off += SZF;
    unsigned short* hw = (unsigned short*)(ws + off); off += (size_t)4096 * 64 * 2;
    unsigned short* ha = (unsigned short*)(ws + off); off += (size_t)4096 * 64 * 2;
    unsigned short* hg = (unsigned short*)(ws + off); off += (size_t)4096 * 128 * 2;
    // chunked-scan aliases over dead regions
    unsigned short* Hbf   = (unsigned short*)abuf;                 // F1b out (abuf dead post-F1a)
    unsigned short* Pbf   = (unsigned short*)((char*)abuf + SZH);
    unsigned short* Qbf   = (unsigned short*)kkbuf;                // (kkbuf dead post-F1a)
    unsigned short* Fbf   = (unsigned short*)((char*)kkbuf + SZH); // F3 out
    unsigned short* Ebf   = Hbf;                                   // F3 out over H (dead post-F2)
    unsigned short* Sbf   = Pbf;                                   // F4 out over P (dead post-F3)
    unsigned short* Wtbf  = (unsigned short*)wdec;                 // F2 out (wdec dead post-F1a)
    unsigned short* U0tbf = (unsigned short*)((char*)wdec + SZH);
    float* cwL  = (float*)hw;                                      // 768*64 f32
    float* dotb = (float*)ha;                                      // 4096*12 f32

    // 1. timeshift + mixes (order: r,w,k,v,a,g)
    k_prep<<<3072, 256, 0, stream>>>(x, mr, mw, mk, mv, ma, mg, X6);
    // 2. weight transposes -> bf16 B^T
    k_transpose<<<dim3(24, 24), 256, 0, stream>>>(Wr, WrT, 768, 768);
    k_transpose<<<dim3(24, 24), 256, 0, stream>>>(Wk, WkT, 768, 768);
    k_transpose<<<dim3(24, 24), 256, 0, stream>>>(Wv, WvT, 768, 768);
    k_transpose<<<dim3(24, 24), 256, 0, stream>>>(Wo, WoT, 768, 768);
    k_transpose<<<dim3(2, 24), 256, 0, stream>>>(w1, w1T, 768, 64);
    k_transpose<<<dim3(24, 2), 256, 0, stream>>>(w2, w2T, 64, 768);
    k_transpose<<<dim3(2, 24), 256, 0, stream>>>(a1, a1T, 768, 64);
    k_transpose<<<dim3(24, 2), 256, 0, stream>>>(a2, a2T, 64, 768);
    k_transpose<<<dim3(4, 24), 256, 0, stream>>>(g1, g1T, 768, 128);
    k_transpose<<<dim3(24, 4), 256, 0, stream>>>(g2, g2T, 128, 768);
    // 3. low-rank chains
    k_gemm<2><<<dim3(1, 64), 256, 0, stream>>>(X6 + 1 * BTC, w1T, hw + 0, nullptr, 4096, 64, 768);
    // NOTE: hw holds tanh(xw@w1) bf16 until wdec GEMM below; cwL reuses hw AFTER k_scanprep? No:
    // cwL aliases hw and k_scanprep writes it — but hw is consumed by the wdec GEMM right here:
    k_gemm<3><<<dim3(12, 64), 256, 0, stream>>>(hw, w2T, wdec, w0, 4096, 768, 64);
    k_gemm<1><<<dim3(1, 64), 256, 0, stream>>>(X6 + 4 * BTC, a1T, ha, nullptr, 4096, 64, 768);
    k_gemm<4><<<dim3(12, 64), 256, 0, stream>>>(ha, a2T, abuf, a0, 4096, 768, 64);
    k_gemm<5><<<dim3(2, 64), 256, 0, stream>>>(X6 + 5 * BTC, g1T, hg, nullptr, 4096, 128, 768);
    k_gemm<0><<<dim3(12, 64), 256, 0, stream>>>(hg, g2T, gbuf, nullptr, 4096, 768, 128);
    // 4. r,k,v projections
    k_gemm<0><<<dim3(12, 64), 256, 0, stream>>>(X6 + 0 * BTC, WrT, rbuf, nullptr, 4096, 768, 768);
    k_gemm<0><<<dim3(12, 64), 256, 0, stream>>>(X6 + 2 * BTC, WkT, kbuf, nullptr, 4096, 768, 768);
    k_gemm<0><<<dim3(12, 64), 256, 0, stream>>>(X6 + 3 * BTC, WvT, vbuf, nullptr, 4096, 768, 768);
    // 5. kk normalize + k update + bonus dot
    k_kproc<<<12288, 256, 0, stream>>>(kbuf, abuf, rbuf, k_k, k_a, r_k, kkbuf, dotb);
    // 6. chunked generalized delta rule
    k_scanprep<<<HC_, 256, 0, stream>>>(wdec, kkbuf, abuf, kbuf, rbuf, Abf, Bbf, Kbf, Rbf, cwL);
    k_gram<<<HC_, 256, 0, stream>>>(Abf, Bbf, Kbf, Rbf, Gf, Hbf, Pbf, Qbf);
    k_solve<<<HC_, 128, 0, stream>>>(Gf, Hbf, Abf, vbuf, Wtbf, U0tbf);
    k_combine<<<HC_, 256, 0, stream>>>(Pbf, Qbf, Wtbf, U0tbf, Bbf, Kbf, Rbf, vbuf, cwL,
                                       Ttbf, Zf, Ebf, Fbf);
    k_phaseB<<<48, 256, 0, stream>>>(Ttbf, Zf, Sbf);
    k_phaseC<<<HC_, 256, 0, stream>>>(Ebf, Sbf, Fbf, obuf);
    // 7. groupnorm + bonus + gate
    k_gnorm<<<12288, 256, 0, stream>>>(obuf, vbuf, gbuf, dotb, gam, bet, ybf);
    // 8. output projection
    k_gemm<0><<<dim3(12, 64), 256, 0, stream>>>(ybf, WoT, (float*)d_out, nullptr, 4096, 768, 768);
}

// Round 4
// 462.664 us; speedup vs baseline: 3.5546x; 3.5546x over previous
//
#include <hip/hip_runtime.h>
#include <math.h>

// ---------------- constants ----------------
constexpr int B_ = 4, T_ = 1024, C_ = 768, H_ = 12, N_ = 64;
constexpr int BT_ = B_ * T_;                    // 4096
constexpr size_t BTC = (size_t)BT_ * C_;        // 3145728
constexpr float EPS_GN = 0.00064f;
constexpr int NCH = 16;                         // chunks per sequence (1024/64)
constexpr int HC_ = 48 * NCH;                   // 768 head-chunks

typedef __attribute__((ext_vector_type(8))) short bf16x8;
typedef __attribute__((ext_vector_type(4))) float f32x4;
typedef __attribute__((ext_vector_type(4))) unsigned short u16x4;
typedef __attribute__((ext_vector_type(8))) unsigned short u16x8;

#define DEVFN static __device__ __forceinline__

DEVFN unsigned short f2bf(float f) {
    unsigned u = __float_as_uint(f);
    unsigned r = u + 0x7FFFu + ((u >> 16) & 1u);
    return (unsigned short)(r >> 16);
}
DEVFN float bf2f(unsigned short u) { return __uint_as_float(((unsigned)u) << 16); }

template<int CTRL>
DEVFN float dppadd(float x) {
    return x + __int_as_float(__builtin_amdgcn_update_dpp(0, __float_as_int(x), CTRL, 0xF, 0xF, true));
}
#define SWZ_ADD(x, imm) ((x) + __int_as_float(__builtin_amdgcn_ds_swizzle(__float_as_int(x), (imm))))

DEVFN float red64(float x) {
    x = dppadd<0xB1>(x);
    x = dppadd<0x4E>(x);
    x = SWZ_ADD(x, 0x101F);
    x = SWZ_ADD(x, 0x201F);
    x = SWZ_ADD(x, 0x401F);
    x += __shfl_xor(x, 32, 64);
    return x;
}

DEVFN f32x4 mfma16(bf16x8 a, bf16x8 b, f32x4 c) {
    return __builtin_amdgcn_mfma_f32_16x16x32_bf16(a, b, c, 0, 0, 0);
}

// full 64x64x64 GEMM for one wave from LDS [64][72] bf16 operands; ACCUMULATES into acc
DEVFN void wave_gemm64(const unsigned short (*A)[72], const unsigned short (*Bt)[72],
                       f32x4 acc[4][4], int lane) {
    int l15 = lane & 15, l16 = lane >> 4;
#pragma unroll
    for (int kk2 = 0; kk2 < 2; ++kk2) {
        bf16x8 af[4], bfv[4];
#pragma unroll
        for (int m = 0; m < 4; ++m) af[m] = *(const bf16x8*)&A[m * 16 + l15][kk2 * 32 + l16 * 8];
#pragma unroll
        for (int n = 0; n < 4; ++n) bfv[n] = *(const bf16x8*)&Bt[n * 16 + l15][kk2 * 32 + l16 * 8];
#pragma unroll
        for (int m = 0; m < 4; ++m)
#pragma unroll
            for (int n = 0; n < 4; ++n)
                acc[m][n] = mfma16(af[m], bfv[n], acc[m][n]);
    }
}

// 16-rows-per-wave 64x64x64 GEMM: wave w computes output rows [w*16, w*16+16)
DEVFN void gemm16(const unsigned short (*A)[72], const unsigned short (*Bt)[72],
                  f32x4 acc[4], int wave, int lane) {
    int l15 = lane & 15, l16 = lane >> 4;
#pragma unroll
    for (int kk2 = 0; kk2 < 2; ++kk2) {
        bf16x8 af = *(const bf16x8*)&A[wave * 16 + l15][kk2 * 32 + l16 * 8];
        bf16x8 bfv[4];
#pragma unroll
        for (int n = 0; n < 4; ++n) bfv[n] = *(const bf16x8*)&Bt[n * 16 + l15][kk2 * 32 + l16 * 8];
#pragma unroll
        for (int n = 0; n < 4; ++n) acc[n] = mfma16(af, bfv[n], acc[n]);
    }
}

// ---------------- kernel 1: timeshift + 6 mixes -> bf16 ----------------
__global__ __launch_bounds__(256) void k_prep(const float* __restrict__ x,
    const float* __restrict__ m0, const float* __restrict__ m1, const float* __restrict__ m2,
    const float* __restrict__ m3, const float* __restrict__ m4, const float* __restrict__ m5,
    unsigned short* __restrict__ X6)
{
    int gid = blockIdx.x * 256 + threadIdx.x;
    int i4 = gid * 4;
    int bt = i4 / C_;
    int c  = i4 - bt * C_;
    const float4 xv = *(const float4*)(x + (size_t)bt * C_ + c);
    float px = 0.f, py = 0.f, pz = 0.f, pw = 0.f;
    if ((bt % T_) != 0) {
        const float4 p = *(const float4*)(x + (size_t)(bt - 1) * C_ + c);
        px = p.x; py = p.y; pz = p.z; pw = p.w;
    }
    float d0 = px - xv.x, d1 = py - xv.y, d2 = pz - xv.z, d3 = pw - xv.w;
    const float* mixes[6] = {m0, m1, m2, m3, m4, m5};
#pragma unroll
    for (int m = 0; m < 6; ++m) {
        const float4 mv = *(const float4*)(mixes[m] + c);
        u16x4 pk;
        pk[0] = f2bf(fmaf(d0, mv.x, xv.x));
        pk[1] = f2bf(fmaf(d1, mv.y, xv.y));
        pk[2] = f2bf(fmaf(d2, mv.z, xv.z));
        pk[3] = f2bf(fmaf(d3, mv.w, xv.w));
        *(u16x4*)(X6 + (size_t)m * BTC + (size_t)bt * C_ + c) = pk;
    }
}

// ---------------- kernel 2: fp32 W[R][Cc] -> bf16 W^T[Cc][R] ----------------
__global__ __launch_bounds__(256) void k_transpose(const float* __restrict__ W,
    unsigned short* __restrict__ WT, int R, int Cc)
{
    __shared__ float tile[32][33];
    int tx = threadIdx.x & 31, ty = threadIdx.x >> 5;
#pragma unroll
    for (int j = 0; j < 4; ++j) {
        int rr = blockIdx.y * 32 + ty + j * 8;
        int cc = blockIdx.x * 32 + tx;
        tile[ty + j * 8][tx] = W[(size_t)rr * Cc + cc];
    }
    __syncthreads();
#pragma unroll
    for (int j = 0; j < 4; ++j) {
        int ro = blockIdx.x * 32 + ty + j * 8;
        int co = blockIdx.y * 32 + tx;
        WT[(size_t)ro * R + co] = f2bf(tile[tx][ty + j * 8]);
    }
}

// ---------------- kernel 3: bf16 GEMM  C[M][Nn] = A[M][K] @ Bt[Nn][K]^T ----------------
template<int EPI>
__global__ __launch_bounds__(256) void k_gemm(const unsigned short* __restrict__ A,
    const unsigned short* __restrict__ Bt, void* __restrict__ Cp,
    const float* __restrict__ bias, int M, int Nn, int K)
{
    __shared__ unsigned short As[64][40];
    __shared__ unsigned short Bs[64][40];
    const int t = threadIdx.x, lane = t & 63, wave = t >> 6;
    const int wr = wave >> 1, wc = wave & 1;
    const int bM = blockIdx.y * 64, bN = blockIdx.x * 64;
    const int srow = t >> 2, skc = (t & 3) * 8;
    const int l15 = lane & 15, l16 = lane >> 4;
    f32x4 acc[2][2] = {};

    for (int k0 = 0; k0 < K; k0 += 32) {
        __syncthreads();
        *(int4*)&As[srow][skc] = *(const int4*)(A + (size_t)(bM + srow) * K + k0 + skc);
        *(int4*)&Bs[srow][skc] = *(const int4*)(Bt + (size_t)(bN + srow) * K + k0 + skc);
        __syncthreads();
        bf16x8 af0 = *(const bf16x8*)&As[wr * 32 + l15][l16 * 8];
        bf16x8 af1 = *(const bf16x8*)&As[wr * 32 + 16 + l15][l16 * 8];
        bf16x8 bf0 = *(const bf16x8*)&Bs[wc * 32 + l15][l16 * 8];
        bf16x8 bf1 = *(const bf16x8*)&Bs[wc * 32 + 16 + l15][l16 * 8];
        acc[0][0] = mfma16(af0, bf0, acc[0][0]);
        acc[0][1] = mfma16(af0, bf1, acc[0][1]);
        acc[1][0] = mfma16(af1, bf0, acc[1][0]);
        acc[1][1] = mfma16(af1, bf1, acc[1][1]);
    }

#pragma unroll
    for (int fm = 0; fm < 2; ++fm)
#pragma unroll
        for (int fn = 0; fn < 2; ++fn)
#pragma unroll
            for (int jj = 0; jj < 4; ++jj) {
                int gr = bM + wr * 32 + fm * 16 + l16 * 4 + jj;
                int gc = bN + wc * 32 + fn * 16 + l15;
                float val = acc[fm][fn][jj];
                size_t oi = (size_t)gr * Nn + gc;
                if constexpr (EPI == 0) {
                    ((float*)Cp)[oi] = val;
                } else if constexpr (EPI == 1) {
                    ((unsigned short*)Cp)[oi] = f2bf(val);
                } else if constexpr (EPI == 2) {
                    ((unsigned short*)Cp)[oi] = f2bf(tanhf(val));
                } else if constexpr (EPI == 3) {
                    float z = bias[gc] + val;
                    float sg = 1.f / (1.f + expf(-z));
                    ((float*)Cp)[oi] = expf(-0.60653065971f * sg);
                } else if constexpr (EPI == 4) {
                    float z = bias[gc] + val;
                    ((float*)Cp)[oi] = 1.f / (1.f + expf(-z));
                } else {
                    ((unsigned short*)Cp)[oi] = f2bf(1.f / (1.f + expf(-val)));
                }
            }
}

// ---------------- kernel 4: kk normalize + k update + bonus dot ----------------
__global__ __launch_bounds__(256) void k_kproc(float* __restrict__ k, const float* __restrict__ a,
    const float* __restrict__ r, const float* __restrict__ k_k, const float* __restrict__ k_a,
    const float* __restrict__ r_k, float* __restrict__ kk, float* __restrict__ dotb)
{
    int gw = blockIdx.x * 4 + (threadIdx.x >> 6);
    int lane = threadIdx.x & 63;
    int bt = gw / H_, h = gw - (gw / H_) * H_;
    int c = h * 64 + lane;
    size_t idx = (size_t)bt * C_ + c;
    float kv = k[idx], av = a[idx], rv = r[idx];
    float kkv = kv * k_k[c];
    float ss = red64(kkv * kkv);
    float inv = 1.f / fmaxf(sqrtf(ss), 1e-12f);
    kk[idx] = kkv * inv;
    float knew = kv * (1.f + (av - 1.f) * k_a[c]);
    k[idx] = knew;
    float dot = red64(rv * knew * r_k[c]);
    if (lane == 0) dotb[bt * H_ + h] = dot;
}

// ---------------- F1a: per head-chunk cumprod + transforms -> bf16 ----------------
__global__ __launch_bounds__(256) void k_scanprep(const float* __restrict__ wdec,
    const float* __restrict__ kk, const float* __restrict__ asig, const float* __restrict__ kupd,
    const float* __restrict__ r, unsigned short* __restrict__ Abf, unsigned short* __restrict__ Bbf,
    unsigned short* __restrict__ Kbf, unsigned short* __restrict__ Rbf, float* __restrict__ cwL)
{
    __shared__ float CW[64][68];
    int hc = blockIdx.x;
    int g = hc >> 4, c = hc & 15;
    int b = g / H_, h = g - (g / H_) * H_;
    size_t rowb = ((size_t)(b * T_ + c * 64)) * C_ + h * 64;
    int tid = threadIdx.x;
    int t = tid >> 2, j0 = (tid & 3) * 16;
#pragma unroll
    for (int e = 0; e < 16; e += 4)
        *(float4*)&CW[t][j0 + e] = *(const float4*)(wdec + rowb + (size_t)t * C_ + j0 + e);
    __syncthreads();
    if (tid < 64) {
        float cp = 1.f;
#pragma unroll 4
        for (int tt = 0; tt < 64; ++tt) { cp *= CW[tt][tid]; CW[tt][tid] = cp; }
        cwL[hc * 64 + tid] = CW[63][tid];
    }
    __syncthreads();
    size_t base = (size_t)hc * 4096 + t * 64;
    size_t gin = rowb + (size_t)t * C_;
#pragma unroll
    for (int e4 = 0; e4 < 4; ++e4) {
        u16x4 pa, pb, pk, pr;
#pragma unroll
        for (int e = 0; e < 4; ++e) {
            int j = j0 + e4 * 4 + e;
            float cwt = CW[t][j];
            float cwm = t ? CW[t - 1][j] : 1.f;
            float inv = 1.f / cwt;
            float kkv = kk[gin + j], av = asig[gin + j];
            pa[e] = f2bf(-kkv * cwm);
            pb[e] = f2bf(kkv * av * inv);
            pk[e] = f2bf(kupd[gin + j] * inv);
            pr[e] = f2bf(r[gin + j] * cwt);
        }
        int j = j0 + e4 * 4;
        *(u16x4*)(Abf + base + j) = pa;
        *(u16x4*)(Bbf + base + j) = pb;
        *(u16x4*)(Kbf + base + j) = pk;
        *(u16x4*)(Rbf + base + j) = pr;
    }
}

// ---------------- F1b: Gram matrices G(f32,strict) H,P,Q(bf16) ----------------
__global__ __launch_bounds__(256) void k_gram(const unsigned short* __restrict__ Abf,
    const unsigned short* __restrict__ Bbf, const unsigned short* __restrict__ Kbf,
    const unsigned short* __restrict__ Rbf, float* __restrict__ Gf,
    unsigned short* __restrict__ Hbf, unsigned short* __restrict__ Pbf, unsigned short* __restrict__ Qbf)
{
    __shared__ unsigned short SA[4][64][72];
    int hc = blockIdx.x, tid = threadIdx.x;
    size_t base = (size_t)hc * 4096;
    int r = tid >> 2, c0 = (tid & 3) * 16;
    const unsigned short* srcs[4] = {Abf, Bbf, Kbf, Rbf};
#pragma unroll
    for (int bu = 0; bu < 4; ++bu) {
        *(int4*)&SA[bu][r][c0]     = *(const int4*)(srcs[bu] + base + r * 64 + c0);
        *(int4*)&SA[bu][r][c0 + 8] = *(const int4*)(srcs[bu] + base + r * 64 + c0 + 8);
    }
    __syncthreads();
    int wave = tid >> 6, lane = tid & 63;
    int l15 = lane & 15, l16 = lane >> 4;
    const unsigned short (*Aop)[72] = (wave < 2) ? SA[0] : SA[3];
    const unsigned short (*Bop)[72] = (wave & 1) ? SA[2] : SA[1];
    f32x4 acc[4][4] = {};
    wave_gemm64(Aop, Bop, acc, lane);
    bool strict = (wave < 2);
#pragma unroll
    for (int m = 0; m < 4; ++m)
#pragma unroll
        for (int n = 0; n < 4; ++n)
#pragma unroll
            for (int jj = 0; jj < 4; ++jj) {
                int tt = m * 16 + l16 * 4 + jj;
                int ss = n * 16 + l15;
                float val = acc[m][n][jj];
                bool keep = strict ? (tt > ss) : (tt >= ss);
                val = keep ? val : 0.f;
                size_t oi = base + (size_t)tt * 64 + ss;
                if (wave == 0) Gf[oi] = val;
                else if (wave == 1) Hbf[oi] = f2bf(val);
                else if (wave == 2) Pbf[oi] = f2bf(val);
                else Qbf[oi] = f2bf(val);
            }
}

// ---------------- F2 (v2): P = (I-G)^-1 via nilpotent factorization, all MFMA ----------------
// (I-G)^-1 = (I+G)(I+G^2)(I+G^4)(I+G^8)(I+G^16)(I+G^32)  [G strictly lower, G^64 = 0]
// Then W^T = (P A)^T, U0^T = (P (H V))^T.
__global__ __launch_bounds__(256) void k_solve(const float* __restrict__ Gf,
    const unsigned short* __restrict__ Hbf, const unsigned short* __restrict__ Abf,
    const float* __restrict__ vbuf, unsigned short* __restrict__ Wtbf, unsigned short* __restrict__ U0tbf)
{
    __shared__ unsigned short Gc[64][72], GcT[64][72], Sx[64][72], SxT[64][72], Pm[64][72];
    int hc = blockIdx.x, tid = threadIdx.x;
    int g = hc >> 4, c = hc & 15;
    int b = g / H_, h = g - (g / H_) * H_;
    size_t rowb = ((size_t)(b * T_ + c * 64)) * C_ + h * 64;
    size_t base = (size_t)hc * 4096;
    int r = tid >> 2, c0 = (tid & 3) * 16;
    int wave = tid >> 6, lane = tid & 63;
    int l15 = lane & 15, l16 = lane >> 4;

    // stage G (f32, strictly lower incl. zero diag) -> Gc, GcT, Pm = I+G
#pragma unroll
    for (int q = 0; q < 4; ++q) {
        float4 g4 = *(const float4*)(Gf + base + (size_t)r * 64 + c0 + q * 4);
        float gv[4] = {g4.x, g4.y, g4.z, g4.w};
#pragma unroll
        for (int e = 0; e < 4; ++e) {
            int cc = c0 + q * 4 + e;
            unsigned short gb = f2bf(gv[e]);
            Gc[r][cc] = gb;
            GcT[cc][r] = gb;
            Pm[r][cc] = (r == cc) ? (unsigned short)0x3F80 : gb;   // diag(G)=0 -> P diag = 1.0
        }
    }
    __syncthreads();

#pragma unroll
    for (int it = 0; it < 5; ++it) {
        const unsigned short (*Gs_)[72]  = (it & 1) ? Sx  : Gc;
        const unsigned short (*GsT_)[72] = (it & 1) ? SxT : GcT;
        unsigned short (*Ds_)[72]  = (it & 1) ? Gc  : Sx;
        unsigned short (*DsT_)[72] = (it & 1) ? GcT : SxT;
        // S = Gcur^2
        {
            f32x4 acc[4] = {};
            gemm16(Gs_, GsT_, acc, wave, lane);
#pragma unroll
            for (int n = 0; n < 4; ++n)
#pragma unroll
                for (int jj = 0; jj < 4; ++jj) {
                    int ro = wave * 16 + l16 * 4 + jj, co = n * 16 + l15;
                    unsigned short sb = f2bf(acc[n][jj]);
                    Ds_[ro][co] = sb;
                    DsT_[co][ro] = sb;
                }
        }
        __syncthreads();
        // P = P + P*S   (each wave owns its 16 rows of P: in-place safe)
        {
            f32x4 acc[4] = {};
            gemm16(Pm, DsT_, acc, wave, lane);
#pragma unroll
            for (int n = 0; n < 4; ++n)
#pragma unroll
                for (int jj = 0; jj < 4; ++jj) {
                    int ro = wave * 16 + l16 * 4 + jj, co = n * 16 + l15;
                    Pm[ro][co] = f2bf(acc[n][jj] + bf2f(Pm[ro][co]));
                }
        }
        __syncthreads();
    }

    // reuse buffers: Gc <- A^T, GcT <- V^T, Sx <- H
#pragma unroll
    for (int q = 0; q < 2; ++q) {
        u16x8 va = *(const u16x8*)(Abf + base + (size_t)r * 64 + c0 + q * 8);
#pragma unroll
        for (int e = 0; e < 8; ++e) Gc[c0 + q * 8 + e][r] = va[e];
    }
#pragma unroll
    for (int q = 0; q < 4; ++q) {
        float4 v4 = *(const float4*)(vbuf + rowb + (size_t)r * C_ + c0 + q * 4);
        GcT[c0 + q * 4 + 0][r] = f2bf(v4.x);
        GcT[c0 + q * 4 + 1][r] = f2bf(v4.y);
        GcT[c0 + q * 4 + 2][r] = f2bf(v4.z);
        GcT[c0 + q * 4 + 3][r] = f2bf(v4.w);
    }
    *(int4*)&Sx[r][c0]     = *(const int4*)(Hbf + base + (size_t)r * 64 + c0);
    *(int4*)&Sx[r][c0 + 8] = *(const int4*)(Hbf + base + (size_t)r * 64 + c0 + 8);
    __syncthreads();
    // (H V)^T -> SxT
    {
        f32x4 acc[4] = {};
        gemm16(Sx, GcT, acc, wave, lane);
#pragma unroll
        for (int n = 0; n < 4; ++n)
#pragma unroll
            for (int jj = 0; jj < 4; ++jj) {
                int ro = wave * 16 + l16 * 4 + jj, co = n * 16 + l15;
                SxT[co][ro] = f2bf(acc[n][jj]);
            }
    }
    __syncthreads();
    // W = P A  (B-op = A^T in Gc), U0 = P (HV) (B-op = (HV)^T in SxT); write transposed to global
    {
        f32x4 wacc[4] = {}, uacc[4] = {};
        gemm16(Pm, Gc, wacc, wave, lane);
        gemm16(Pm, SxT, uacc, wave, lane);
#pragma unroll
        for (int n = 0; n < 4; ++n)
#pragma unroll
            for (int jj = 0; jj < 4; ++jj) {
                int ro = wave * 16 + l16 * 4 + jj, co = n * 16 + l15;
                Wtbf[base + (size_t)co * 64 + ro]  = f2bf(wacc[n][jj]);
                U0tbf[base + (size_t)co * 64 + ro] = f2bf(uacc[n][jj]);
            }
    }
}

// ---------------- F3: combine -> Tt(bf16,transposed), Z(f32), E(bf16), F(bf16) ----------------
__global__ __launch_bounds__(256) void k_combine(const unsigned short* __restrict__ Pbf,
    const unsigned short* __restrict__ Qbf, const unsigned short* __restrict__ Wtbf,
    const unsigned short* __restrict__ U0tbf, const unsigned short* __restrict__ Bbf,
    const unsigned short* __restrict__ Kbf, const unsigned short* __restrict__ Rbf,
    const float* __restrict__ vbuf, const float* __restrict__ cwL,
    unsigned short* __restrict__ Ttbf, float* __restrict__ Zf,
    unsigned short* __restrict__ Ebf, unsigned short* __restrict__ Fbf)
{
    __shared__ unsigned short S7[7][64][72];   // 0=P 1=Q 2=Wt 3=U0t 4=Bt 5=Kt 6=Vt
    int hc = blockIdx.x, tid = threadIdx.x;
    int g = hc >> 4, c = hc & 15;
    int b = g / H_, h = g - (g / H_) * H_;
    size_t rowb = ((size_t)(b * T_ + c * 64)) * C_ + h * 64;
    size_t base = (size_t)hc * 4096;
    int r = tid >> 2, c0 = (tid & 3) * 16;
    const unsigned short* rm[4] = {Pbf, Qbf, Wtbf, U0tbf};
#pragma unroll
    for (int bu = 0; bu < 4; ++bu) {
        *(int4*)&S7[bu][r][c0]     = *(const int4*)(rm[bu] + base + r * 64 + c0);
        *(int4*)&S7[bu][r][c0 + 8] = *(const int4*)(rm[bu] + base + r * 64 + c0 + 8);
    }
    {
        u16x8 vb0 = *(const u16x8*)(Bbf + base + r * 64 + c0);
        u16x8 vb1 = *(const u16x8*)(Bbf + base + r * 64 + c0 + 8);
        u16x8 vk0 = *(const u16x8*)(Kbf + base + r * 64 + c0);
        u16x8 vk1 = *(const u16x8*)(Kbf + base + r * 64 + c0 + 8);
#pragma unroll
        for (int e = 0; e < 8; ++e) {
            S7[4][c0 + e][r] = vb0[e];
            S7[4][c0 + 8 + e][r] = vb1[e];
            S7[5][c0 + e][r] = vk0[e];
            S7[5][c0 + 8 + e][r] = vk1[e];
        }
#pragma unroll
        for (int q = 0; q < 4; ++q) {
            float4 v4 = *(const float4*)(vbuf + rowb + (size_t)r * C_ + c0 + q * 4);
            S7[6][c0 + q * 4 + 0][r] = f2bf(v4.x);
            S7[6][c0 + q * 4 + 1][r] = f2bf(v4.y);
            S7[6][c0 + q * 4 + 2][r] = f2bf(v4.z);
            S7[6][c0 + q * 4 + 3][r] = f2bf(v4.w);
        }
    }
    __syncthreads();
    int wave = tid >> 6, lane = tid & 63;
    int l15 = lane & 15, l16 = lane >> 4;
    f32x4 acc[4][4] = {};
    if (wave == 0) wave_gemm64(S7[2], S7[4], acc, lane);
    else if (wave == 1) { wave_gemm64(S7[3], S7[4], acc, lane); wave_gemm64(S7[6], S7[5], acc, lane); }
    else if (wave == 2) wave_gemm64(S7[0], S7[2], acc, lane);
    else { wave_gemm64(S7[0], S7[3], acc, lane); wave_gemm64(S7[1], S7[6], acc, lane); }
#pragma unroll
    for (int m = 0; m < 4; ++m)
#pragma unroll
        for (int n = 0; n < 4; ++n)
#pragma unroll
            for (int jj = 0; jj < 4; ++jj) {
                int ro = m * 16 + l16 * 4 + jj;
                int co = n * 16 + l15;
                float val = acc[m][n][jj];
                if (wave == 0) {
                    val = (val + (ro == co ? 1.f : 0.f)) * cwL[hc * 64 + co];
                    Ttbf[base + (size_t)co * 64 + ro] = f2bf(val);
                } else if (wave == 1) {
                    Zf[base + (size_t)ro * 64 + co] = val * cwL[hc * 64 + co];
                } else if (wave == 2) {
                    val += bf2f(Rbf[base + (size_t)ro * 64 + co]);
                    Ebf[base + (size_t)ro * 64 + co] = f2bf(val);
                } else {
                    Fbf[base + (size_t)ro * 64 + co] = f2bf(val);
                }
            }
}

// ---------------- F4: per-head serial chunk recursion S <- S T + Z ----------------
__global__ __launch_bounds__(256) void k_phaseB(const unsigned short* __restrict__ Ttbf,
    const float* __restrict__ Zf, unsigned short* __restrict__ Sbf)
{
    __shared__ unsigned short Sb[2][64][72];
    __shared__ unsigned short Tt[64][72];
    int g = blockIdx.x, tid = threadIdx.x;
    int r = tid >> 2, c0 = (tid & 3) * 16;
    int4 z4 = {0, 0, 0, 0};
    *(int4*)&Sb[0][r][c0] = z4;
    *(int4*)&Sb[0][r][c0 + 8] = z4;
    int cur = 0;
    int wave = tid >> 6, lane = tid & 63;
    int wr = wave >> 1, wc = wave & 1;
    int l15 = lane & 15, l16 = lane >> 4;
    for (int c = 0; c < NCH; ++c) {
        size_t base = ((size_t)g * NCH + c) * 4096;
        __syncthreads();
        *(int4*)(Sbf + base + r * 64 + c0)     = *(int4*)&Sb[cur][r][c0];
        *(int4*)(Sbf + base + r * 64 + c0 + 8) = *(int4*)&Sb[cur][r][c0 + 8];
        *(int4*)&Tt[r][c0]     = *(const int4*)(Ttbf + base + r * 64 + c0);
        *(int4*)&Tt[r][c0 + 8] = *(const int4*)(Ttbf + base + r * 64 + c0 + 8);
        __syncthreads();
        f32x4 acc[2][2] = {};
#pragma unroll
        for (int kk2 = 0; kk2 < 2; ++kk2) {
            bf16x8 af[2], bfv[2];
#pragma unroll
            for (int m = 0; m < 2; ++m) af[m] = *(const bf16x8*)&Sb[cur][wr * 32 + m * 16 + l15][kk2 * 32 + l16 * 8];
#pragma unroll
            for (int n = 0; n < 2; ++n) bfv[n] = *(const bf16x8*)&Tt[wc * 32 + n * 16 + l15][kk2 * 32 + l16 * 8];
#pragma unroll
            for (int m = 0; m < 2; ++m)
#pragma unroll
                for (int n = 0; n < 2; ++n)
                    acc[m][n] = mfma16(af[m], bfv[n], acc[m][n]);
        }
#pragma unroll
        for (int m = 0; m < 2; ++m)
#pragma unroll
            for (int n = 0; n < 2; ++n)
#pragma unroll
                for (int jj = 0; jj < 4; ++jj) {
                    int ro = wr * 32 + m * 16 + l16 * 4 + jj;
                    int co = wc * 32 + n * 16 + l15;
                    float val = acc[m][n][jj] + Zf[base + (size_t)ro * 64 + co];
                    Sb[cur ^ 1][ro][co] = f2bf(val);
                }
        cur ^= 1;
    }
}

// ---------------- F5: O = E S0^T + F -> obuf ----------------
__global__ __launch_bounds__(256) void k_phaseC(const unsigned short* __restrict__ Ebf,
    const unsigned short* __restrict__ Sbf, const unsigned short* __restrict__ Fbf,
    float* __restrict__ obuf)
{
    __shared__ unsigned short Es[64][72], Ss[64][72];
    int hc = blockIdx.x, tid = threadIdx.x;
    int g = hc >> 4, c = hc & 15;
    int b = g / H_, h = g - (g / H_) * H_;
    size_t rowb = ((size_t)(b * T_ + c * 64)) * C_ + h * 64;
    size_t base = (size_t)hc * 4096;
    int r = tid >> 2, c0 = (tid & 3) * 16;
    *(int4*)&Es[r][c0]     = *(const int4*)(Ebf + base + r * 64 + c0);
    *(int4*)&Es[r][c0 + 8] = *(const int4*)(Ebf + base + r * 64 + c0 + 8);
    *(int4*)&Ss[r][c0]     = *(const int4*)(Sbf + base + r * 64 + c0);
    *(int4*)&Ss[r][c0 + 8] = *(const int4*)(Sbf + base + r * 64 + c0 + 8);
    __syncthreads();
    int wave = tid >> 6, lane = tid & 63;
    int wr = wave >> 1, wc = wave & 1;
    int l15 = lane & 15, l16 = lane >> 4;
    f32x4 acc[2][2] = {};
#pragma unroll
    for (int kk2 = 0; kk2 < 2; ++kk2) {
        bf16x8 af[2], bfv[2];
#pragma unroll
        for (int m = 0; m < 2; ++m) af[m] = *(const bf16x8*)&Es[wr * 32 + m * 16 + l15][kk2 * 32 + l16 * 8];
#pragma unroll
        for (int n = 0; n < 2; ++n) bfv[n] = *(const bf16x8*)&Ss[wc * 32 + n * 16 + l15][kk2 * 32 + l16 * 8];
#pragma unroll
        for (int m = 0; m < 2; ++m)
#pragma unroll
            for (int n = 0; n < 2; ++n)
                acc[m][n] = mfma16(af[m], bfv[n], acc[m][n]);
    }
#pragma unroll
    for (int m = 0; m < 2; ++m)
#pragma unroll
        for (int n = 0; n < 2; ++n)
#pragma unroll
            for (int jj = 0; jj < 4; ++jj) {
                int tt = wr * 32 + m * 16 + l16 * 4 + jj;
                int ii = wc * 32 + n * 16 + l15;
                float val = acc[m][n][jj] + bf2f(Fbf[base + (size_t)tt * 64 + ii]);
                obuf[rowb + (size_t)tt * C_ + ii] = val;
            }
}

// ---------------- kernel 6: groupnorm + bonus + gate -> bf16 ----------------
__global__ __launch_bounds__(256) void k_gnorm(const float* __restrict__ o,
    const float* __restrict__ v, const float* __restrict__ g, const float* __restrict__ dotb,
    const float* __restrict__ gamma, const float* __restrict__ beta,
    unsigned short* __restrict__ yb)
{
    int gw = blockIdx.x * 4 + (threadIdx.x >> 6);
    int lane = threadIdx.x & 63;
    int bt = gw / H_, h = gw - (gw / H_) * H_;
    int c = h * 64 + lane;
    size_t idx = (size_t)bt * C_ + c;
    float ov = o[idx];
    float mean = red64(ov) * 0.015625f;
    float d = ov - mean;
    float var = red64(d * d) * 0.015625f;
    float yn = d * rsqrtf(var + EPS_GN) * gamma[c] + beta[c];
    float dot = dotb[bt * H_ + h];
    float y = (yn + dot * v[idx]) * g[idx];
    yb[idx] = f2bf(y);
}

// ---------------- host ----------------
extern "C" void kernel_launch(void* const* d_in, const int* in_sizes, int n_in,
                              void* d_out, int out_size, void* d_ws, size_t ws_size,
                              hipStream_t stream)
{
    (void)in_sizes; (void)n_in; (void)out_size; (void)ws_size;
    const float* x   = (const float*)d_in[0];
    const float* mr  = (const float*)d_in[1];
    const float* mw  = (const float*)d_in[2];
    const float* mk  = (const float*)d_in[3];
    const float* mv  = (const float*)d_in[4];
    const float* ma  = (const float*)d_in[5];
    const float* mg  = (const float*)d_in[6];
    const float* w0  = (const float*)d_in[7];
    const float* w1  = (const float*)d_in[8];
    const float* w2  = (const float*)d_in[9];
    const float* a0  = (const float*)d_in[10];
    const float* a1  = (const float*)d_in[11];
    const float* a2  = (const float*)d_in[12];
    const float* g1  = (const float*)d_in[13];
    const float* g2  = (const float*)d_in[14];
    const float* k_k = (const float*)d_in[15];
    const float* k_a = (const float*)d_in[16];
    const float* r_k = (const float*)d_in[17];
    const float* Wr  = (const float*)d_in[18];
    const float* Wk  = (const float*)d_in[19];
    const float* Wv  = (const float*)d_in[20];
    const float* Wo  = (const float*)d_in[21];
    const float* gam = (const float*)d_in[22];
    const float* bet = (const float*)d_in[23];

    char* ws = (char*)d_ws;
    constexpr size_t SZF = BTC * 4;
    constexpr size_t SZH = BTC * 2;
    unsigned short* X6  = (unsigned short*)ws;
    unsigned short* Abf = (unsigned short*)(ws + 0 * SZH);
    unsigned short* Bbf = (unsigned short*)(ws + 1 * SZH);
    unsigned short* Kbf = (unsigned short*)(ws + 2 * SZH);
    unsigned short* Rbf = (unsigned short*)(ws + 3 * SZH);
    float*          Gf  = (float*)(ws + 4 * SZH);
    unsigned short* Ttbf = Abf;
    float*          Zf   = Gf;
    float*          obuf = (float*)(ws + 1 * SZH);
    unsigned short* ybf  = (unsigned short*)(ws + 3 * SZH);

    size_t off = 6 * SZH;
    unsigned short* WrT = (unsigned short*)(ws + off); off += (size_t)768 * 768 * 2;
    unsigned short* WkT = (unsigned short*)(ws + off); off += (size_t)768 * 768 * 2;
    unsigned short* WvT = (unsigned short*)(ws + off); off += (size_t)768 * 768 * 2;
    unsigned short* WoT = (unsigned short*)(ws + off); off += (size_t)768 * 768 * 2;
    unsigned short* w1T = (unsigned short*)(ws + off); off += (size_t)64 * 768 * 2;
    unsigned short* w2T = (unsigned short*)(ws + off); off += (size_t)64 * 768 * 2;
    unsigned short* a1T = (unsigned short*)(ws + off); off += (size_t)64 * 768 * 2;
    unsigned short* a2T = (unsigned short*)(ws + off); off += (size_t)64 * 768 * 2;
    unsigned short* g1T = (unsigned short*)(ws + off); off += (size_t)128 * 768 * 2;
    unsigned short* g2T = (unsigned short*)(ws + off); off += (size_t)128 * 768 * 2;
    float* rbuf  = (float*)(ws + off); off += SZF;
    float* kbuf  = (float*)(ws + off); off += SZF;
    float* vbuf  = (float*)(ws + off); off += SZF;
    float* wdec  = (float*)(ws + off); off += SZF;
    float* abuf  = (float*)(ws + off); off += SZF;
    float* kkbuf = (float*)(ws + off); off += SZF;
    float* gbuf  = (float*)(ws + off); off += SZF;
    unsigned short* hw = (unsigned short*)(ws + off); off += (size_t)4096 * 64 * 2;
    unsigned short* ha = (unsigned short*)(ws + off); off += (size_t)4096 * 64 * 2;
    unsigned short* hg = (unsigned short*)(ws + off); off += (size_t)4096 * 128 * 2;
    unsigned short* Hbf   = (unsigned short*)abuf;
    unsigned short* Pbf   = (unsigned short*)((char*)abuf + SZH);
    unsigned short* Qbf   = (unsigned short*)kkbuf;
    unsigned short* Fbf   = (unsigned short*)((char*)kkbuf + SZH);
    unsigned short* Ebf   = Hbf;
    unsigned short* Sbf   = Pbf;
    unsigned short* Wtbf  = (unsigned short*)wdec;
    unsigned short* U0tbf = (unsigned short*)((char*)wdec + SZH);
    float* cwL  = (float*)hw;
    float* dotb = (float*)ha;

    k_prep<<<3072, 256, 0, stream>>>(x, mr, mw, mk, mv, ma, mg, X6);
    k_transpose<<<dim3(24, 24), 256, 0, stream>>>(Wr, WrT, 768, 768);
    k_transpose<<<dim3(24, 24), 256, 0, stream>>>(Wk, WkT, 768, 768);
    k_transpose<<<dim3(24, 24), 256, 0, stream>>>(Wv, WvT, 768, 768);
    k_transpose<<<dim3(24, 24), 256, 0, stream>>>(Wo, WoT, 768, 768);
    k_transpose<<<dim3(2, 24), 256, 0, stream>>>(w1, w1T, 768, 64);
    k_transpose<<<dim3(24, 2), 256, 0, stream>>>(w2, w2T, 64, 768);
    k_transpose<<<dim3(2, 24), 256, 0, stream>>>(a1, a1T, 768, 64);
    k_transpose<<<dim3(24, 2), 256, 0, stream>>>(a2, a2T, 64, 768);
    k_transpose<<<dim3(4, 24), 256, 0, stream>>>(g1, g1T, 768, 128);
    k_transpose<<<dim3(24, 4), 256, 0, stream>>>(g2, g2T, 128, 768);
    k_gemm<2><<<dim3(1, 64), 256, 0, stream>>>(X6 + 1 * BTC, w1T, hw, nullptr, 4096, 64, 768);
    k_gemm<3><<<dim3(12, 64), 256, 0, stream>>>(hw, w2T, wdec, w0, 4096, 768, 64);
    k_gemm<1><<<dim3(1, 64), 256, 0, stream>>>(X6 + 4 * BTC, a1T, ha, nullptr, 4096, 64, 768);
    k_gemm<4><<<dim3(12, 64), 256, 0, stream>>>(ha, a2T, abuf, a0, 4096, 768, 64);
    k_gemm<5><<<dim3(2, 64), 256, 0, stream>>>(X6 + 5 * BTC, g1T, hg, nullptr, 4096, 128, 768);
    k_gemm<0><<<dim3(12, 64), 256, 0, stream>>>(hg, g2T, gbuf, nullptr, 4096, 768, 128);
    k_gemm<0><<<dim3(12, 64), 256, 0, stream>>>(X6 + 0 * BTC, WrT, rbuf, nullptr, 4096, 768, 768);
    k_gemm<0><<<dim3(12, 64), 256, 0, stream>>>(X6 + 2 * BTC, WkT, kbuf, nullptr, 4096, 768, 768);
    k_gemm<0><<<dim3(12, 64), 256, 0, stream>>>(X6 + 3 * BTC, WvT, vbuf, nullptr, 4096, 768, 768);
    k_kproc<<<12288, 256, 0, stream>>>(kbuf, abuf, rbuf, k_k, k_a, r_k, kkbuf, dotb);
    k_scanprep<<<HC_, 256, 0, stream>>>(wdec, kkbuf, abuf, kbuf, rbuf, Abf, Bbf, Kbf, Rbf, cwL);
    k_gram<<<HC_, 256, 0, stream>>>(Abf, Bbf, Kbf, Rbf, Gf, Hbf, Pbf, Qbf);
    k_solve<<<HC_, 256, 0, stream>>>(Gf, Hbf, Abf, vbuf, Wtbf, U0tbf);
    k_combine<<<HC_, 256, 0, stream>>>(Pbf, Qbf, Wtbf, U0tbf, Bbf, Kbf, Rbf, vbuf, cwL,
                                       Ttbf, Zf, Ebf, Fbf);
    k_phaseB<<<48, 256, 0, stream>>>(Ttbf, Zf, Sbf);
    k_phaseC<<<HC_, 256, 0, stream>>>(Ebf, Sbf, Fbf, obuf);
    k_gnorm<<<12288, 256, 0, stream>>>(obuf, vbuf, gbuf, dotb, gam, bet, ybf);
    k_gemm<0><<<dim3(12, 64), 256, 0, stream>>>(ybf, WoT, (float*)d_out, nullptr, 4096, 768, 768);
}

// Round 6
// 448.568 us; speedup vs baseline: 3.6663x; 1.0314x over previous
//
#include <hip/hip_runtime.h>
#include <math.h>

// ---------------- constants ----------------
constexpr int B_ = 4, T_ = 1024, C_ = 768, H_ = 12, N_ = 64;
constexpr int BT_ = B_ * T_;                    // 4096
constexpr size_t BTC = (size_t)BT_ * C_;        // 3145728
constexpr float EPS_GN = 0.00064f;
constexpr int NCH = 16;                         // chunks per sequence (1024/64)
constexpr int HC_ = 48 * NCH;                   // 768 head-chunks

typedef __attribute__((ext_vector_type(8))) short bf16x8;
typedef __attribute__((ext_vector_type(4))) float f32x4;
typedef __attribute__((ext_vector_type(4))) unsigned short u16x4;
typedef __attribute__((ext_vector_type(8))) unsigned short u16x8;

#define DEVFN static __device__ __forceinline__

DEVFN unsigned short f2bf(float f) {
    unsigned u = __float_as_uint(f);
    unsigned r = u + 0x7FFFu + ((u >> 16) & 1u);
    return (unsigned short)(r >> 16);
}
DEVFN float bf2f(unsigned short u) { return __uint_as_float(((unsigned)u) << 16); }

template<int CTRL>
DEVFN float dppadd(float x) {
    return x + __int_as_float(__builtin_amdgcn_update_dpp(0, __float_as_int(x), CTRL, 0xF, 0xF, true));
}
#define SWZ_ADD(x, imm) ((x) + __int_as_float(__builtin_amdgcn_ds_swizzle(__float_as_int(x), (imm))))

DEVFN float red64(float x) {
    x = dppadd<0xB1>(x);
    x = dppadd<0x4E>(x);
    x = SWZ_ADD(x, 0x101F);
    x = SWZ_ADD(x, 0x201F);
    x = SWZ_ADD(x, 0x401F);
    x += __shfl_xor(x, 32, 64);
    return x;
}

DEVFN f32x4 mfma16(bf16x8 a, bf16x8 b, f32x4 c) {
    return __builtin_amdgcn_mfma_f32_16x16x32_bf16(a, b, c, 0, 0, 0);
}

typedef const __attribute__((address_space(1))) unsigned int* gas_t;
typedef __attribute__((address_space(3))) unsigned int* las_t;
DEVFN void gload16(const void* g, void* l) {
    __builtin_amdgcn_global_load_lds((gas_t)g, (las_t)l, 16, 0, 0);
}

// full 64x64x64 GEMM for one wave from LDS [64][72] bf16 operands; ACCUMULATES into acc
DEVFN void wave_gemm64(const unsigned short (*A)[72], const unsigned short (*Bt)[72],
                       f32x4 acc[4][4], int lane) {
    int l15 = lane & 15, l16 = lane >> 4;
#pragma unroll
    for (int kk2 = 0; kk2 < 2; ++kk2) {
        bf16x8 af[4], bfv[4];
#pragma unroll
        for (int m = 0; m < 4; ++m) af[m] = *(const bf16x8*)&A[m * 16 + l15][kk2 * 32 + l16 * 8];
#pragma unroll
        for (int n = 0; n < 4; ++n) bfv[n] = *(const bf16x8*)&Bt[n * 16 + l15][kk2 * 32 + l16 * 8];
#pragma unroll
        for (int m = 0; m < 4; ++m)
#pragma unroll
            for (int n = 0; n < 4; ++n)
                acc[m][n] = mfma16(af[m], bfv[n], acc[m][n]);
    }
}

// 16-rows-per-wave 64x64x64 GEMM: wave w computes output rows [w*16, w*16+16)
DEVFN void gemm16(const unsigned short (*A)[72], const unsigned short (*Bt)[72],
                  f32x4 acc[4], int wave, int lane) {
    int l15 = lane & 15, l16 = lane >> 4;
#pragma unroll
    for (int kk2 = 0; kk2 < 2; ++kk2) {
        bf16x8 af = *(const bf16x8*)&A[wave * 16 + l15][kk2 * 32 + l16 * 8];
        bf16x8 bfv[4];
#pragma unroll
        for (int n = 0; n < 4; ++n) bfv[n] = *(const bf16x8*)&Bt[n * 16 + l15][kk2 * 32 + l16 * 8];
#pragma unroll
        for (int n = 0; n < 4; ++n) acc[n] = mfma16(af, bfv[n], acc[n]);
    }
}

// ---------------- kernel 1: timeshift + 6 mixes -> bf16 ----------------
__global__ __launch_bounds__(256) void k_prep(const float* __restrict__ x,
    const float* __restrict__ m0, const float* __restrict__ m1, const float* __restrict__ m2,
    const float* __restrict__ m3, const float* __restrict__ m4, const float* __restrict__ m5,
    unsigned short* __restrict__ X6)
{
    int gid = blockIdx.x * 256 + threadIdx.x;
    int i4 = gid * 4;
    int bt = i4 / C_;
    int c  = i4 - bt * C_;
    const float4 xv = *(const float4*)(x + (size_t)bt * C_ + c);
    float px = 0.f, py = 0.f, pz = 0.f, pw = 0.f;
    if ((bt % T_) != 0) {
        const float4 p = *(const float4*)(x + (size_t)(bt - 1) * C_ + c);
        px = p.x; py = p.y; pz = p.z; pw = p.w;
    }
    float d0 = px - xv.x, d1 = py - xv.y, d2 = pz - xv.z, d3 = pw - xv.w;
    const float* mixes[6] = {m0, m1, m2, m3, m4, m5};
#pragma unroll
    for (int m = 0; m < 6; ++m) {
        const float4 mv = *(const float4*)(mixes[m] + c);
        u16x4 pk;
        pk[0] = f2bf(fmaf(d0, mv.x, xv.x));
        pk[1] = f2bf(fmaf(d1, mv.y, xv.y));
        pk[2] = f2bf(fmaf(d2, mv.z, xv.z));
        pk[3] = f2bf(fmaf(d3, mv.w, xv.w));
        *(u16x4*)(X6 + (size_t)m * BTC + (size_t)bt * C_ + c) = pk;
    }
}

// ---------------- kernel 2: fp32 W[R][Cc] -> bf16 W^T[Cc][R] ----------------
__global__ __launch_bounds__(256) void k_transpose(const float* __restrict__ W,
    unsigned short* __restrict__ WT, int R, int Cc)
{
    __shared__ float tile[32][33];
    int tx = threadIdx.x & 31, ty = threadIdx.x >> 5;
#pragma unroll
    for (int j = 0; j < 4; ++j) {
        int rr = blockIdx.y * 32 + ty + j * 8;
        int cc = blockIdx.x * 32 + tx;
        tile[ty + j * 8][tx] = W[(size_t)rr * Cc + cc];
    }
    __syncthreads();
#pragma unroll
    for (int j = 0; j < 4; ++j) {
        int ro = blockIdx.x * 32 + ty + j * 8;
        int co = blockIdx.y * 32 + tx;
        WT[(size_t)ro * R + co] = f2bf(tile[tx][ty + j * 8]);
    }
}

// ---------------- kernel 3a: 64-tile bf16 GEMM (small N) ----------------
// EPI: 1 raw bf16, 2 tanh bf16, 5 sigmoid bf16
template<int EPI>
__global__ __launch_bounds__(256) void k_gemm(const unsigned short* __restrict__ A,
    const unsigned short* __restrict__ Bt, void* __restrict__ Cp,
    const float* __restrict__ bias, int M, int Nn, int K)
{
    __shared__ unsigned short As[64][40];
    __shared__ unsigned short Bs[64][40];
    const int t = threadIdx.x, lane = t & 63, wave = t >> 6;
    const int wr = wave >> 1, wc = wave & 1;
    const int bM = blockIdx.y * 64, bN = blockIdx.x * 64;
    const int srow = t >> 2, skc = (t & 3) * 8;
    const int l15 = lane & 15, l16 = lane >> 4;
    f32x4 acc[2][2] = {};

    for (int k0 = 0; k0 < K; k0 += 32) {
        __syncthreads();
        *(int4*)&As[srow][skc] = *(const int4*)(A + (size_t)(bM + srow) * K + k0 + skc);
        *(int4*)&Bs[srow][skc] = *(const int4*)(Bt + (size_t)(bN + srow) * K + k0 + skc);
        __syncthreads();
        bf16x8 af0 = *(const bf16x8*)&As[wr * 32 + l15][l16 * 8];
        bf16x8 af1 = *(const bf16x8*)&As[wr * 32 + 16 + l15][l16 * 8];
        bf16x8 bf0 = *(const bf16x8*)&Bs[wc * 32 + l15][l16 * 8];
        bf16x8 bf1 = *(const bf16x8*)&Bs[wc * 32 + 16 + l15][l16 * 8];
        acc[0][0] = mfma16(af0, bf0, acc[0][0]);
        acc[0][1] = mfma16(af0, bf1, acc[0][1]);
        acc[1][0] = mfma16(af1, bf0, acc[1][0]);
        acc[1][1] = mfma16(af1, bf1, acc[1][1]);
    }

#pragma unroll
    for (int fm = 0; fm < 2; ++fm)
#pragma unroll
        for (int fn = 0; fn < 2; ++fn)
#pragma unroll
            for (int jj = 0; jj < 4; ++jj) {
                int gr = bM + wr * 32 + fm * 16 + l16 * 4 + jj;
                int gc = bN + wc * 32 + fn * 16 + l15;
                float val = acc[fm][fn][jj];
                size_t oi = (size_t)gr * Nn + gc;
                if constexpr (EPI == 1) {
                    ((unsigned short*)Cp)[oi] = f2bf(val);
                } else if constexpr (EPI == 2) {
                    ((unsigned short*)Cp)[oi] = f2bf(tanhf(val));
                } else {
                    ((unsigned short*)Cp)[oi] = f2bf(1.f / (1.f + expf(-val)));
                }
            }
}

// ---------------- kernel 3b: 128x128-tile GEMM with global_load_lds (m97 structure) ----------------
// EPI: 0 raw f32, 3 w-decay f32(bias), 4 sigmoid f32(bias)
template<int EPI>
__global__ __launch_bounds__(256) void k_gemm128(const unsigned short* __restrict__ A,
    const unsigned short* __restrict__ Bt, void* __restrict__ Cp,
    const float* __restrict__ bias, int M, int Nn, int K)
{
    __shared__ unsigned short As[128][32];
    __shared__ unsigned short Bs[128][32];
    const int tid = threadIdx.x, lane = tid & 63, wave = tid >> 6;
    const int wr = wave >> 1, wc = wave & 1;
    const int bM = blockIdx.y * 128, bN = blockIdx.x * 128;
    const int l15 = lane & 15, l16 = lane >> 4;
    const int srow = lane >> 2, scol = (lane & 3) * 8;
    f32x4 acc[4][4] = {};

    for (int k0 = 0; k0 < K; k0 += 32) {
        __syncthreads();
#pragma unroll
        for (int i = 0; i < 2; ++i) {
            int ch = i * 4 + wave;                 // chunk 0..7 (16 rows each)
            int row = ch * 16 + srow;
            gload16(A  + (size_t)(bM + row) * K + k0 + scol, &As[0][0] + ch * 512 + lane * 8);
            gload16(Bt + (size_t)(bN + row) * K + k0 + scol, &Bs[0][0] + ch * 512 + lane * 8);
        }
        __syncthreads();
        bf16x8 af[4], bfv[4];
#pragma unroll
        for (int m = 0; m < 4; ++m) af[m]  = *(const bf16x8*)&As[wr * 64 + m * 16 + l15][l16 * 8];
#pragma unroll
        for (int n = 0; n < 4; ++n) bfv[n] = *(const bf16x8*)&Bs[wc * 64 + n * 16 + l15][l16 * 8];
#pragma unroll
        for (int m = 0; m < 4; ++m)
#pragma unroll
            for (int n = 0; n < 4; ++n)
                acc[m][n] = mfma16(af[m], bfv[n], acc[m][n]);
    }

#pragma unroll
    for (int m = 0; m < 4; ++m)
#pragma unroll
        for (int n = 0; n < 4; ++n)
#pragma unroll
            for (int jj = 0; jj < 4; ++jj) {
                int gr = bM + wr * 64 + m * 16 + l16 * 4 + jj;
                int gc = bN + wc * 64 + n * 16 + l15;
                float val = acc[m][n][jj];
                size_t oi = (size_t)gr * Nn + gc;
                if constexpr (EPI == 0) {
                    ((float*)Cp)[oi] = val;
                } else if constexpr (EPI == 3) {
                    float z = bias[gc] + val;
                    float sg = 1.f / (1.f + expf(-z));
                    ((float*)Cp)[oi] = expf(-0.60653065971f * sg);
                } else {
                    float z = bias[gc] + val;
                    ((float*)Cp)[oi] = 1.f / (1.f + expf(-z));
                }
            }
}

// ---------------- kernel 4: kk normalize + k update + bonus dot ----------------
__global__ __launch_bounds__(256) void k_kproc(float* __restrict__ k, const float* __restrict__ a,
    const float* __restrict__ r, const float* __restrict__ k_k, const float* __restrict__ k_a,
    const float* __restrict__ r_k, float* __restrict__ kk, float* __restrict__ dotb)
{
    int gw = blockIdx.x * 4 + (threadIdx.x >> 6);
    int lane = threadIdx.x & 63;
    int bt = gw / H_, h = gw - (gw / H_) * H_;
    int c = h * 64 + lane;
    size_t idx = (size_t)bt * C_ + c;
    float kv = k[idx], av = a[idx], rv = r[idx];
    float kkv = kv * k_k[c];
    float ss = red64(kkv * kkv);
    float inv = 1.f / fmaxf(sqrtf(ss), 1e-12f);
    kk[idx] = kkv * inv;
    float knew = kv * (1.f + (av - 1.f) * k_a[c]);
    k[idx] = knew;
    float dot = red64(rv * knew * r_k[c]);
    if (lane == 0) dotb[bt * H_ + h] = dot;
}

// ---------------- F1a v2: cumprod + transforms, coalesced 32B stores ----------------
__global__ __launch_bounds__(256) void k_scanprep(const float* __restrict__ wdec,
    const float* __restrict__ kk, const float* __restrict__ asig, const float* __restrict__ kupd,
    const float* __restrict__ r, unsigned short* __restrict__ Abf, unsigned short* __restrict__ Bbf,
    unsigned short* __restrict__ Kbf, unsigned short* __restrict__ Rbf, float* __restrict__ cwL)
{
    __shared__ float CW[64][68];
    int hc = blockIdx.x;
    int g = hc >> 4, c = hc & 15;
    int b = g / H_, h = g - (g / H_) * H_;
    size_t rowb = ((size_t)(b * T_ + c * 64)) * C_ + h * 64;
    int tid = threadIdx.x;
    int t = tid >> 2, j0 = (tid & 3) * 16;
#pragma unroll
    for (int e = 0; e < 16; e += 4)
        *(float4*)&CW[t][j0 + e] = *(const float4*)(wdec + rowb + (size_t)t * C_ + j0 + e);
    __syncthreads();
    if (tid < 64) {
        float cp = 1.f;
#pragma unroll 4
        for (int tt = 0; tt < 64; ++tt) { cp *= CW[tt][tid]; CW[tt][tid] = cp; }
        cwL[hc * 64 + tid] = CW[63][tid];
    }
    __syncthreads();

    size_t base = (size_t)hc * 4096 + t * 64 + j0;
    size_t gin = rowb + (size_t)t * C_ + j0;
    float cwt[16], cwm[16], invc[16];
#pragma unroll
    for (int q = 0; q < 4; ++q) *(float4*)&cwt[q * 4] = *(const float4*)&CW[t][j0 + q * 4];
    if (t) {
#pragma unroll
        for (int q = 0; q < 4; ++q) *(float4*)&cwm[q * 4] = *(const float4*)&CW[t - 1][j0 + q * 4];
    } else {
#pragma unroll
        for (int e = 0; e < 16; ++e) cwm[e] = 1.f;
    }
#pragma unroll
    for (int e = 0; e < 16; ++e) invc[e] = 1.f / cwt[e];

    float kkv[16], tmp[16];
#pragma unroll
    for (int q = 0; q < 4; ++q) *(float4*)&kkv[q * 4] = *(const float4*)(kk + gin + q * 4);
    {   // A = -kk * cw_{t-1}
        u16x8 o0, o1;
#pragma unroll
        for (int e = 0; e < 8; ++e) { o0[e] = f2bf(-kkv[e] * cwm[e]); o1[e] = f2bf(-kkv[8 + e] * cwm[8 + e]); }
        *(u16x8*)(Abf + base) = o0; *(u16x8*)(Abf + base + 8) = o1;
    }
#pragma unroll
    for (int q = 0; q < 4; ++q) *(float4*)&tmp[q * 4] = *(const float4*)(asig + gin + q * 4);
    {   // B = kk * a / cw_t
        u16x8 o0, o1;
#pragma unroll
        for (int e = 0; e < 8; ++e) { o0[e] = f2bf(kkv[e] * tmp[e] * invc[e]); o1[e] = f2bf(kkv[8 + e] * tmp[8 + e] * invc[8 + e]); }
        *(u16x8*)(Bbf + base) = o0; *(u16x8*)(Bbf + base + 8) = o1;
    }
#pragma unroll
    for (int q = 0; q < 4; ++q) *(float4*)&tmp[q * 4] = *(const float4*)(kupd + gin + q * 4);
    {   // K = k / cw_t
        u16x8 o0, o1;
#pragma unroll
        for (int e = 0; e < 8; ++e) { o0[e] = f2bf(tmp[e] * invc[e]); o1[e] = f2bf(tmp[8 + e] * invc[8 + e]); }
        *(u16x8*)(Kbf + base) = o0; *(u16x8*)(Kbf + base + 8) = o1;
    }
#pragma unroll
    for (int q = 0; q < 4; ++q) *(float4*)&tmp[q * 4] = *(const float4*)(r + gin + q * 4);
    {   // R = r * cw_t
        u16x8 o0, o1;
#pragma unroll
        for (int e = 0; e < 8; ++e) { o0[e] = f2bf(tmp[e] * cwt[e]); o1[e] = f2bf(tmp[8 + e] * cwt[8 + e]); }
        *(u16x8*)(Rbf + base) = o0; *(u16x8*)(Rbf + base + 8) = o1;
    }
}

// ---------------- F1b: Gram matrices G(bf16,strict) H,P,Q(bf16) ----------------
__global__ __launch_bounds__(256) void k_gram(const unsigned short* __restrict__ Abf,
    const unsigned short* __restrict__ Bbf, const unsigned short* __restrict__ Kbf,
    const unsigned short* __restrict__ Rbf, unsigned short* __restrict__ Gbf,
    unsigned short* __restrict__ Hbf, unsigned short* __restrict__ Pbf, unsigned short* __restrict__ Qbf)
{
    __shared__ unsigned short SA[4][64][72];
    int hc = blockIdx.x, tid = threadIdx.x;
    size_t base = (size_t)hc * 4096;
    int r = tid >> 2, c0 = (tid & 3) * 16;
    const unsigned short* srcs[4] = {Abf, Bbf, Kbf, Rbf};
#pragma unroll
    for (int bu = 0; bu < 4; ++bu) {
        *(int4*)&SA[bu][r][c0]     = *(const int4*)(srcs[bu] + base + r * 64 + c0);
        *(int4*)&SA[bu][r][c0 + 8] = *(const int4*)(srcs[bu] + base + r * 64 + c0 + 8);
    }
    __syncthreads();
    int wave = tid >> 6, lane = tid & 63;
    int l15 = lane & 15, l16 = lane >> 4;
    const unsigned short (*Aop)[72] = (wave < 2) ? SA[0] : SA[3];
    const unsigned short (*Bop)[72] = (wave & 1) ? SA[2] : SA[1];
    f32x4 acc[4][4] = {};
    wave_gemm64(Aop, Bop, acc, lane);
    bool strict = (wave < 2);
#pragma unroll
    for (int m = 0; m < 4; ++m)
#pragma unroll
        for (int n = 0; n < 4; ++n)
#pragma unroll
            for (int jj = 0; jj < 4; ++jj) {
                int tt = m * 16 + l16 * 4 + jj;
                int ss = n * 16 + l15;
                float val = acc[m][n][jj];
                bool keep = strict ? (tt > ss) : (tt >= ss);
                val = keep ? val : 0.f;
                size_t oi = base + (size_t)tt * 64 + ss;
                if (wave == 0) Gbf[oi] = f2bf(val);
                else if (wave == 1) Hbf[oi] = f2bf(val);
                else if (wave == 2) Pbf[oi] = f2bf(val);
                else Qbf[oi] = f2bf(val);
            }
}

// ---------------- F2: P = (I-G)^-1 via nilpotent factorization, all MFMA ----------------
__global__ __launch_bounds__(256) void k_solve(const unsigned short* __restrict__ Gbf,
    const unsigned short* __restrict__ Hbf, const unsigned short* __restrict__ Abf,
    const float* __restrict__ vbuf, unsigned short* __restrict__ Wtbf, unsigned short* __restrict__ U0tbf)
{
    __shared__ unsigned short Gc[64][72], GcT[64][72], Sx[64][72], SxT[64][72], Pm[64][72];
    int hc = blockIdx.x, tid = threadIdx.x;
    int g = hc >> 4, c = hc & 15;
    int b = g / H_, h = g - (g / H_) * H_;
    size_t rowb = ((size_t)(b * T_ + c * 64)) * C_ + h * 64;
    size_t base = (size_t)hc * 4096;
    int r = tid >> 2, c0 = (tid & 3) * 16;
    int wave = tid >> 6, lane = tid & 63;
    int l15 = lane & 15, l16 = lane >> 4;

#pragma unroll
    for (int q = 0; q < 2; ++q) {
        u16x8 va = *(const u16x8*)(Gbf + base + (size_t)r * 64 + c0 + q * 8);
#pragma unroll
        for (int e = 0; e < 8; ++e) {
            int cc = c0 + q * 8 + e;
            unsigned short gb = va[e];
            Gc[r][cc] = gb;
            GcT[cc][r] = gb;
            Pm[r][cc] = (r == cc) ? (unsigned short)0x3F80 : gb;
        }
    }
    __syncthreads();

#pragma unroll
    for (int it = 0; it < 5; ++it) {
        const unsigned short (*Gs_)[72]  = (it & 1) ? Sx  : Gc;
        const unsigned short (*GsT_)[72] = (it & 1) ? SxT : GcT;
        unsigned short (*Ds_)[72]  = (it & 1) ? Gc  : Sx;
        unsigned short (*DsT_)[72] = (it & 1) ? GcT : SxT;
        {
            f32x4 acc[4] = {};
            gemm16(Gs_, GsT_, acc, wave, lane);
#pragma unroll
            for (int n = 0; n < 4; ++n)
#pragma unroll
                for (int jj = 0; jj < 4; ++jj) {
                    int ro = wave * 16 + l16 * 4 + jj, co = n * 16 + l15;
                    unsigned short sb = f2bf(acc[n][jj]);
                    Ds_[ro][co] = sb;
                    DsT_[co][ro] = sb;
                }
        }
        __syncthreads();
        {
            f32x4 acc[4] = {};
            gemm16(Pm, DsT_, acc, wave, lane);
#pragma unroll
            for (int n = 0; n < 4; ++n)
#pragma unroll
                for (int jj = 0; jj < 4; ++jj) {
                    int ro = wave * 16 + l16 * 4 + jj, co = n * 16 + l15;
                    Pm[ro][co] = f2bf(acc[n][jj] + bf2f(Pm[ro][co]));
                }
        }
        __syncthreads();
    }

    // reuse: Gc <- A^T, GcT <- V^T, Sx <- H
#pragma unroll
    for (int q = 0; q < 2; ++q) {
        u16x8 va = *(const u16x8*)(Abf + base + (size_t)r * 64 + c0 + q * 8);
#pragma unroll
        for (int e = 0; e < 8; ++e) Gc[c0 + q * 8 + e][r] = va[e];
    }
#pragma unroll
    for (int q = 0; q < 4; ++q) {
        float4 v4 = *(const float4*)(vbuf + rowb + (size_t)r * C_ + c0 + q * 4);
        GcT[c0 + q * 4 + 0][r] = f2bf(v4.x);
        GcT[c0 + q * 4 + 1][r] = f2bf(v4.y);
        GcT[c0 + q * 4 + 2][r] = f2bf(v4.z);
        GcT[c0 + q * 4 + 3][r] = f2bf(v4.w);
    }
    *(int4*)&Sx[r][c0]     = *(const int4*)(Hbf + base + (size_t)r * 64 + c0);
    *(int4*)&Sx[r][c0 + 8] = *(const int4*)(Hbf + base + (size_t)r * 64 + c0 + 8);
    __syncthreads();
    {
        f32x4 acc[4] = {};
        gemm16(Sx, GcT, acc, wave, lane);
#pragma unroll
        for (int n = 0; n < 4; ++n)
#pragma unroll
            for (int jj = 0; jj < 4; ++jj) {
                int ro = wave * 16 + l16 * 4 + jj, co = n * 16 + l15;
                SxT[co][ro] = f2bf(acc[n][jj]);
            }
    }
    __syncthreads();
    {
        f32x4 wacc[4] = {}, uacc[4] = {};
        gemm16(Pm, Gc, wacc, wave, lane);
        gemm16(Pm, SxT, uacc, wave, lane);
#pragma unroll
        for (int n = 0; n < 4; ++n)
#pragma unroll
            for (int jj = 0; jj < 4; ++jj) {
                int ro = wave * 16 + l16 * 4 + jj, co = n * 16 + l15;
                Wtbf[base + (size_t)co * 64 + ro]  = f2bf(wacc[n][jj]);
                U0tbf[base + (size_t)co * 64 + ro] = f2bf(uacc[n][jj]);
            }
    }
}

// ---------------- F3: combine -> Tt(bf16,transposed), Z(bf16), E(bf16), F(bf16) ----------------
__global__ __launch_bounds__(256) void k_combine(const unsigned short* __restrict__ Pbf,
    const unsigned short* __restrict__ Qbf, const unsigned short* __restrict__ Wtbf,
    const unsigned short* __restrict__ U0tbf, const unsigned short* __restrict__ Bbf,
    const unsigned short* __restrict__ Kbf, const unsigned short* __restrict__ Rbf,
    const float* __restrict__ vbuf, const float* __restrict__ cwL,
    unsigned short* __restrict__ Ttbf, unsigned short* __restrict__ Zbf,
    unsigned short* __restrict__ Ebf, unsigned short* __restrict__ Fbf)
{
    __shared__ unsigned short S7[7][64][72];   // 0=P 1=Q 2=Wt 3=U0t 4=Bt 5=Kt 6=Vt
    int hc = blockIdx.x, tid = threadIdx.x;
    int g = hc >> 4, c = hc & 15;
    int b = g / H_, h = g - (g / H_) * H_;
    size_t rowb = ((size_t)(b * T_ + c * 64)) * C_ + h * 64;
    size_t base = (size_t)hc * 4096;
    int r = tid >> 2, c0 = (tid & 3) * 16;
    const unsigned short* rm[4] = {Pbf, Qbf, Wtbf, U0tbf};
#pragma unroll
    for (int bu = 0; bu < 4; ++bu) {
        *(int4*)&S7[bu][r][c0]     = *(const int4*)(rm[bu] + base + r * 64 + c0);
        *(int4*)&S7[bu][r][c0 + 8] = *(const int4*)(rm[bu] + base + r * 64 + c0 + 8);
    }
    {
        u16x8 vb0 = *(const u16x8*)(Bbf + base + r * 64 + c0);
        u16x8 vb1 = *(const u16x8*)(Bbf + base + r * 64 + c0 + 8);
        u16x8 vk0 = *(const u16x8*)(Kbf + base + r * 64 + c0);
        u16x8 vk1 = *(const u16x8*)(Kbf + base + r * 64 + c0 + 8);
#pragma unroll
        for (int e = 0; e < 8; ++e) {
            S7[4][c0 + e][r] = vb0[e];
            S7[4][c0 + 8 + e][r] = vb1[e];
            S7[5][c0 + e][r] = vk0[e];
            S7[5][c0 + 8 + e][r] = vk1[e];
        }
#pragma unroll
        for (int q = 0; q < 4; ++q) {
            float4 v4 = *(const float4*)(vbuf + rowb + (size_t)r * C_ + c0 + q * 4);
            S7[6][c0 + q * 4 + 0][r] = f2bf(v4.x);
            S7[6][c0 + q * 4 + 1][r] = f2bf(v4.y);
            S7[6][c0 + q * 4 + 2][r] = f2bf(v4.z);
            S7[6][c0 + q * 4 + 3][r] = f2bf(v4.w);
        }
    }
    __syncthreads();
    int wave = tid >> 6, lane = tid & 63;
    int l15 = lane & 15, l16 = lane >> 4;
    f32x4 acc[4][4] = {};
    if (wave == 0) wave_gemm64(S7[2], S7[4], acc, lane);
    else if (wave == 1) { wave_gemm64(S7[3], S7[4], acc, lane); wave_gemm64(S7[6], S7[5], acc, lane); }
    else if (wave == 2) wave_gemm64(S7[0], S7[2], acc, lane);
    else { wave_gemm64(S7[0], S7[3], acc, lane); wave_gemm64(S7[1], S7[6], acc, lane); }
#pragma unroll
    for (int m = 0; m < 4; ++m)
#pragma unroll
        for (int n = 0; n < 4; ++n)
#pragma unroll
            for (int jj = 0; jj < 4; ++jj) {
                int ro = m * 16 + l16 * 4 + jj;
                int co = n * 16 + l15;
                float val = acc[m][n][jj];
                if (wave == 0) {
                    val = (val + (ro == co ? 1.f : 0.f)) * cwL[hc * 64 + co];
                    Ttbf[base + (size_t)co * 64 + ro] = f2bf(val);
                } else if (wave == 1) {
                    Zbf[base + (size_t)ro * 64 + co] = f2bf(val * cwL[hc * 64 + co]);
                } else if (wave == 2) {
                    val += bf2f(Rbf[base + (size_t)ro * 64 + co]);
                    Ebf[base + (size_t)ro * 64 + co] = f2bf(val);
                } else {
                    Fbf[base + (size_t)ro * 64 + co] = f2bf(val);
                }
            }
}

// ---------------- F4: per-head serial chunk recursion S <- S T + Z ----------------
__global__ __launch_bounds__(256) void k_phaseB(const unsigned short* __restrict__ Ttbf,
    const unsigned short* __restrict__ Zbf, unsigned short* __restrict__ Sbf)
{
    __shared__ unsigned short Sb[2][64][72];
    __shared__ unsigned short Tt[64][72];
    int g = blockIdx.x, tid = threadIdx.x;
    int r = tid >> 2, c0 = (tid & 3) * 16;
    int4 z4 = {0, 0, 0, 0};
    *(int4*)&Sb[0][r][c0] = z4;
    *(int4*)&Sb[0][r][c0 + 8] = z4;
    int cur = 0;
    int wave = tid >> 6, lane = tid & 63;
    int wr = wave >> 1, wc = wave & 1;
    int l15 = lane & 15, l16 = lane >> 4;
    for (int c = 0; c < NCH; ++c) {
        size_t base = ((size_t)g * NCH + c) * 4096;
        __syncthreads();
        *(int4*)(Sbf + base + r * 64 + c0)     = *(int4*)&Sb[cur][r][c0];
        *(int4*)(Sbf + base + r * 64 + c0 + 8) = *(int4*)&Sb[cur][r][c0 + 8];
        *(int4*)&Tt[r][c0]     = *(const int4*)(Ttbf + base + r * 64 + c0);
        *(int4*)&Tt[r][c0 + 8] = *(const int4*)(Ttbf + base + r * 64 + c0 + 8);
        __syncthreads();
        f32x4 acc[2][2] = {};
#pragma unroll
        for (int kk2 = 0; kk2 < 2; ++kk2) {
            bf16x8 af[2], bfv[2];
#pragma unroll
            for (int m = 0; m < 2; ++m) af[m] = *(const bf16x8*)&Sb[cur][wr * 32 + m * 16 + l15][kk2 * 32 + l16 * 8];
#pragma unroll
            for (int n = 0; n < 2; ++n) bfv[n] = *(const bf16x8*)&Tt[wc * 32 + n * 16 + l15][kk2 * 32 + l16 * 8];
#pragma unroll
            for (int m = 0; m < 2; ++m)
#pragma unroll
                for (int n = 0; n < 2; ++n)
                    acc[m][n] = mfma16(af[m], bfv[n], acc[m][n]);
        }
#pragma unroll
        for (int m = 0; m < 2; ++m)
#pragma unroll
            for (int n = 0; n < 2; ++n)
#pragma unroll
                for (int jj = 0; jj < 4; ++jj) {
                    int ro = wr * 32 + m * 16 + l16 * 4 + jj;
                    int co = wc * 32 + n * 16 + l15;
                    float val = acc[m][n][jj] + bf2f(Zbf[base + (size_t)ro * 64 + co]);
                    Sb[cur ^ 1][ro][co] = f2bf(val);
                }
        cur ^= 1;
    }
}

// ---------------- F5: O = E S0^T + F -> obuf ----------------
__global__ __launch_bounds__(256) void k_phaseC(const unsigned short* __restrict__ Ebf,
    const unsigned short* __restrict__ Sbf, const unsigned short* __restrict__ Fbf,
    float* __restrict__ obuf)
{
    __shared__ unsigned short Es[64][72], Ss[64][72];
    int hc = blockIdx.x, tid = threadIdx.x;
    int g = hc >> 4, c = hc & 15;
    int b = g / H_, h = g - (g / H_) * H_;
    size_t rowb = ((size_t)(b * T_ + c * 64)) * C_ + h * 64;
    size_t base = (size_t)hc * 4096;
    int r = tid >> 2, c0 = (tid & 3) * 16;
    *(int4*)&Es[r][c0]     = *(const int4*)(Ebf + base + r * 64 + c0);
    *(int4*)&Es[r][c0 + 8] = *(const int4*)(Ebf + base + r * 64 + c0 + 8);
    *(int4*)&Ss[r][c0]     = *(const int4*)(Sbf + base + r * 64 + c0);
    *(int4*)&Ss[r][c0 + 8] = *(const int4*)(Sbf + base + r * 64 + c0 + 8);
    __syncthreads();
    int wave = tid >> 6, lane = tid & 63;
    int wr = wave >> 1, wc = wave & 1;
    int l15 = lane & 15, l16 = lane >> 4;
    f32x4 acc[2][2] = {};
#pragma unroll
    for (int kk2 = 0; kk2 < 2; ++kk2) {
        bf16x8 af[2], bfv[2];
#pragma unroll
        for (int m = 0; m < 2; ++m) af[m] = *(const bf16x8*)&Es[wr * 32 + m * 16 + l15][kk2 * 32 + l16 * 8];
#pragma unroll
        for (int n = 0; n < 2; ++n) bfv[n] = *(const bf16x8*)&Ss[wc * 32 + n * 16 + l15][kk2 * 32 + l16 * 8];
#pragma unroll
        for (int m = 0; m < 2; ++m)
#pragma unroll
            for (int n = 0; n < 2; ++n)
                acc[m][n] = mfma16(af[m], bfv[n], acc[m][n]);
    }
#pragma unroll
    for (int m = 0; m < 2; ++m)
#pragma unroll
        for (int n = 0; n < 2; ++n)
#pragma unroll
            for (int jj = 0; jj < 4; ++jj) {
                int tt = wr * 32 + m * 16 + l16 * 4 + jj;
                int ii = wc * 32 + n * 16 + l15;
                float val = acc[m][n][jj] + bf2f(Fbf[base + (size_t)tt * 64 + ii]);
                obuf[rowb + (size_t)tt * C_ + ii] = val;
            }
}

// ---------------- kernel 6: groupnorm + bonus + gate -> bf16 ----------------
__global__ __launch_bounds__(256) void k_gnorm(const float* __restrict__ o,
    const float* __restrict__ v, const float* __restrict__ g, const float* __restrict__ dotb,
    const float* __restrict__ gamma, const float* __restrict__ beta,
    unsigned short* __restrict__ yb)
{
    int gw = blockIdx.x * 4 + (threadIdx.x >> 6);
    int lane = threadIdx.x & 63;
    int bt = gw / H_, h = gw - (gw / H_) * H_;
    int c = h * 64 + lane;
    size_t idx = (size_t)bt * C_ + c;
    float ov = o[idx];
    float mean = red64(ov) * 0.015625f;
    float d = ov - mean;
    float var = red64(d * d) * 0.015625f;
    float yn = d * rsqrtf(var + EPS_GN) * gamma[c] + beta[c];
    float dot = dotb[bt * H_ + h];
    float y = (yn + dot * v[idx]) * g[idx];
    yb[idx] = f2bf(y);
}

// ---------------- host ----------------
extern "C" void kernel_launch(void* const* d_in, const int* in_sizes, int n_in,
                              void* d_out, int out_size, void* d_ws, size_t ws_size,
                              hipStream_t stream)
{
    (void)in_sizes; (void)n_in; (void)out_size; (void)ws_size;
    const float* x   = (const float*)d_in[0];
    const float* mr  = (const float*)d_in[1];
    const float* mw  = (const float*)d_in[2];
    const float* mk  = (const float*)d_in[3];
    const float* mv  = (const float*)d_in[4];
    const float* ma  = (const float*)d_in[5];
    const float* mg  = (const float*)d_in[6];
    const float* w0  = (const float*)d_in[7];
    const float* w1  = (const float*)d_in[8];
    const float* w2  = (const float*)d_in[9];
    const float* a0  = (const float*)d_in[10];
    const float* a1  = (const float*)d_in[11];
    const float* a2  = (const float*)d_in[12];
    const float* g1  = (const float*)d_in[13];
    const float* g2  = (const float*)d_in[14];
    const float* k_k = (const float*)d_in[15];
    const float* k_a = (const float*)d_in[16];
    const float* r_k = (const float*)d_in[17];
    const float* Wr  = (const float*)d_in[18];
    const float* Wk  = (const float*)d_in[19];
    const float* Wv  = (const float*)d_in[20];
    const float* Wo  = (const float*)d_in[21];
    const float* gam = (const float*)d_in[22];
    const float* bet = (const float*)d_in[23];

    char* ws = (char*)d_ws;
    constexpr size_t SZF = BTC * 4;
    constexpr size_t SZH = BTC * 2;
    unsigned short* X6  = (unsigned short*)ws;
    unsigned short* Abf = (unsigned short*)(ws + 0 * SZH);
    unsigned short* Bbf = (unsigned short*)(ws + 1 * SZH);
    unsigned short* Kbf = (unsigned short*)(ws + 2 * SZH);
    unsigned short* Rbf = (unsigned short*)(ws + 3 * SZH);
    unsigned short* Gbf = (unsigned short*)(ws + 4 * SZH);
    unsigned short* Ttbf = Abf;
    unsigned short* Zbf  = Gbf;
    float*          obuf = (float*)(ws + 1 * SZH);
    unsigned short* ybf  = (unsigned short*)(ws + 3 * SZH);

    size_t off = 6 * SZH;
    unsigned short* WrT = (unsigned short*)(ws + off); off += (size_t)768 * 768 * 2;
    unsigned short* WkT = (unsigned short*)(ws + off); off += (size_t)768 * 768 * 2;
    unsigned short* WvT = (unsigned short*)(ws + off); off += (size_t)768 * 768 * 2;
    unsigned short* WoT = (unsigned short*)(ws + off); off += (size_t)768 * 768 * 2;
    unsigned short* w1T = (unsigned short*)(ws + off); off += (size_t)64 * 768 * 2;
    unsigned short* w2T = (unsigned short*)(ws + off); off += (size_t)64 * 768 * 2;
    unsigned short* a1T = (unsigned short*)(ws + off); off += (size_t)64 * 768 * 2;
    unsigned short* a2T = (unsigned short*)(ws + off); off += (size_t)64 * 768 * 2;
    unsigned short* g1T = (unsigned short*)(ws + off); off += (size_t)128 * 768 * 2;
    unsigned short* g2T = (unsigned short*)(ws + off); off += (size_t)128 * 768 * 2;
    float* rbuf  = (float*)(ws + off); off += SZF;
    float* kbuf  = (float*)(ws + off); off += SZF;
    float* vbuf  = (float*)(ws + off); off += SZF;
    float* wdec  = (float*)(ws + off); off += SZF;
    float* abuf  = (float*)(ws + off); off += SZF;
    float* kkbuf = (float*)(ws + off); off += SZF;
    float* gbuf  = (float*)(ws + off); off += SZF;
    unsigned short* hw = (unsigned short*)(ws + off); off += (size_t)4096 * 64 * 2;
    unsigned short* ha = (unsigned short*)(ws + off); off += (size_t)4096 * 64 * 2;
    unsigned short* hg = (unsigned short*)(ws + off); off += (size_t)4096 * 128 * 2;
    unsigned short* Hbf   = (unsigned short*)abuf;
    unsigned short* Pbf   = (unsigned short*)((char*)abuf + SZH);
    unsigned short* Qbf   = (unsigned short*)kkbuf;
    unsigned short* Fbf   = (unsigned short*)((char*)kkbuf + SZH);
    unsigned short* Ebf   = Hbf;
    unsigned short* Sbf   = Pbf;
    unsigned short* Wtbf  = (unsigned short*)wdec;
    unsigned short* U0tbf = (unsigned short*)((char*)wdec + SZH);
    float* cwL  = (float*)hw;
    float* dotb = (float*)ha;

    k_prep<<<3072, 256, 0, stream>>>(x, mr, mw, mk, mv, ma, mg, X6);
    k_transpose<<<dim3(24, 24), 256, 0, stream>>>(Wr, WrT, 768, 768);
    k_transpose<<<dim3(24, 24), 256, 0, stream>>>(Wk, WkT, 768, 768);
    k_transpose<<<dim3(24, 24), 256, 0, stream>>>(Wv, WvT, 768, 768);
    k_transpose<<<dim3(24, 24), 256, 0, stream>>>(Wo, WoT, 768, 768);
    k_transpose<<<dim3(2, 24), 256, 0, stream>>>(w1, w1T, 768, 64);
    k_transpose<<<dim3(24, 2), 256, 0, stream>>>(w2, w2T, 64, 768);
    k_transpose<<<dim3(2, 24), 256, 0, stream>>>(a1, a1T, 768, 64);
    k_transpose<<<dim3(24, 2), 256, 0, stream>>>(a2, a2T, 64, 768);
    k_transpose<<<dim3(4, 24), 256, 0, stream>>>(g1, g1T, 768, 128);
    k_transpose<<<dim3(24, 4), 256, 0, stream>>>(g2, g2T, 128, 768);
    // low-rank chains
    k_gemm<2><<<dim3(1, 64), 256, 0, stream>>>(X6 + 1 * BTC, w1T, hw, nullptr, 4096, 64, 768);
    k_gemm128<3><<<dim3(6, 32), 256, 0, stream>>>(hw, w2T, wdec, w0, 4096, 768, 64);
    k_gemm<1><<<dim3(1, 64), 256, 0, stream>>>(X6 + 4 * BTC, a1T, ha, nullptr, 4096, 64, 768);
    k_gemm128<4><<<dim3(6, 32), 256, 0, stream>>>(ha, a2T, abuf, a0, 4096, 768, 64);
    k_gemm<5><<<dim3(2, 64), 256, 0, stream>>>(X6 + 5 * BTC, g1T, hg, nullptr, 4096, 128, 768);
    k_gemm128<0><<<dim3(6, 32), 256, 0, stream>>>(hg, g2T, gbuf, nullptr, 4096, 768, 128);
    // r,k,v projections
    k_gemm128<0><<<dim3(6, 32), 256, 0, stream>>>(X6 + 0 * BTC, WrT, rbuf, nullptr, 4096, 768, 768);
    k_gemm128<0><<<dim3(6, 32), 256, 0, stream>>>(X6 + 2 * BTC, WkT, kbuf, nullptr, 4096, 768, 768);
    k_gemm128<0><<<dim3(6, 32), 256, 0, stream>>>(X6 + 3 * BTC, WvT, vbuf, nullptr, 4096, 768, 768);
    k_kproc<<<12288, 256, 0, stream>>>(kbuf, abuf, rbuf, k_k, k_a, r_k, kkbuf, dotb);
    // chunked generalized delta rule
    k_scanprep<<<HC_, 256, 0, stream>>>(wdec, kkbuf, abuf, kbuf, rbuf, Abf, Bbf, Kbf, Rbf, cwL);
    k_gram<<<HC_, 256, 0, stream>>>(Abf, Bbf, Kbf, Rbf, Gbf, Hbf, Pbf, Qbf);
    k_solve<<<HC_, 256, 0, stream>>>(Gbf, Hbf, Abf, vbuf, Wtbf, U0tbf);
    k_combine<<<HC_, 256, 0, stream>>>(Pbf, Qbf, Wtbf, U0tbf, Bbf, Kbf, Rbf, vbuf, cwL,
                                       Ttbf, Zbf, Ebf, Fbf);
    k_phaseB<<<48, 256, 0, stream>>>(Ttbf, Zbf, Sbf);
    k_phaseC<<<HC_, 256, 0, stream>>>(Ebf, Sbf, Fbf, obuf);
    k_gnorm<<<12288, 256, 0, stream>>>(obuf, vbuf, gbuf, dotb, gam, bet, ybf);
    k_gemm128<0><<<dim3(6, 32), 256, 0, stream>>>(ybf, WoT, (float*)d_out, nullptr, 4096, 768, 768);
}

// Round 7
// 432.929 us; speedup vs baseline: 3.7988x; 1.0361x over previous
//
#include <hip/hip_runtime.h>
#include <math.h>

// ---------------- constants ----------------
constexpr int B_ = 4, T_ = 1024, C_ = 768, H_ = 12, N_ = 64;
constexpr int BT_ = B_ * T_;                    // 4096
constexpr size_t BTC = (size_t)BT_ * C_;        // 3145728
constexpr float EPS_GN = 0.00064f;
constexpr int NCH = 16;                         // chunks per sequence (1024/64)
constexpr int HC_ = 48 * NCH;                   // 768 head-chunks

typedef __attribute__((ext_vector_type(8))) short bf16x8;
typedef __attribute__((ext_vector_type(4))) float f32x4;
typedef __attribute__((ext_vector_type(4))) unsigned short u16x4;
typedef __attribute__((ext_vector_type(8))) unsigned short u16x8;

#define DEVFN static __device__ __forceinline__

DEVFN unsigned short f2bf(float f) {
    unsigned u = __float_as_uint(f);
    unsigned r = u + 0x7FFFu + ((u >> 16) & 1u);
    return (unsigned short)(r >> 16);
}
DEVFN float bf2f(unsigned short u) { return __uint_as_float(((unsigned)u) << 16); }

template<int CTRL>
DEVFN float dppadd(float x) {
    return x + __int_as_float(__builtin_amdgcn_update_dpp(0, __float_as_int(x), CTRL, 0xF, 0xF, true));
}
#define SWZ_ADD(x, imm) ((x) + __int_as_float(__builtin_amdgcn_ds_swizzle(__float_as_int(x), (imm))))

DEVFN float red64(float x) {
    x = dppadd<0xB1>(x);
    x = dppadd<0x4E>(x);
    x = SWZ_ADD(x, 0x101F);
    x = SWZ_ADD(x, 0x201F);
    x = SWZ_ADD(x, 0x401F);
    x += __shfl_xor(x, 32, 64);
    return x;
}

DEVFN f32x4 mfma16(bf16x8 a, bf16x8 b, f32x4 c) {
    return __builtin_amdgcn_mfma_f32_16x16x32_bf16(a, b, c, 0, 0, 0);
}

typedef const __attribute__((address_space(1))) unsigned int* gas_t;
typedef __attribute__((address_space(3))) unsigned int* las_t;
DEVFN void gload16(const void* g, void* l) {
    __builtin_amdgcn_global_load_lds((gas_t)g, (las_t)l, 16, 0, 0);
}

// full 64x64x64 GEMM for one wave from LDS [64][72] bf16 operands; ACCUMULATES into acc
DEVFN void wave_gemm64(const unsigned short (*A)[72], const unsigned short (*Bt)[72],
                       f32x4 acc[4][4], int lane) {
    int l15 = lane & 15, l16 = lane >> 4;
#pragma unroll
    for (int kk2 = 0; kk2 < 2; ++kk2) {
        bf16x8 af[4], bfv[4];
#pragma unroll
        for (int m = 0; m < 4; ++m) af[m] = *(const bf16x8*)&A[m * 16 + l15][kk2 * 32 + l16 * 8];
#pragma unroll
        for (int n = 0; n < 4; ++n) bfv[n] = *(const bf16x8*)&Bt[n * 16 + l15][kk2 * 32 + l16 * 8];
#pragma unroll
        for (int m = 0; m < 4; ++m)
#pragma unroll
            for (int n = 0; n < 4; ++n)
                acc[m][n] = mfma16(af[m], bfv[n], acc[m][n]);
    }
}

// 16-rows-per-wave 64x64x64 GEMM: wave w computes output rows [w*16, w*16+16)
DEVFN void gemm16(const unsigned short (*A)[72], const unsigned short (*Bt)[72],
                  f32x4 acc[4], int wave, int lane) {
    int l15 = lane & 15, l16 = lane >> 4;
#pragma unroll
    for (int kk2 = 0; kk2 < 2; ++kk2) {
        bf16x8 af = *(const bf16x8*)&A[wave * 16 + l15][kk2 * 32 + l16 * 8];
        bf16x8 bfv[4];
#pragma unroll
        for (int n = 0; n < 4; ++n) bfv[n] = *(const bf16x8*)&Bt[n * 16 + l15][kk2 * 32 + l16 * 8];
#pragma unroll
        for (int n = 0; n < 4; ++n) acc[n] = mfma16(af, bfv[n], acc[n]);
    }
}

// ---------------- kernel 1: timeshift + 6 mixes -> bf16 ----------------
__global__ __launch_bounds__(256) void k_prep(const float* __restrict__ x,
    const float* __restrict__ m0, const float* __restrict__ m1, const float* __restrict__ m2,
    const float* __restrict__ m3, const float* __restrict__ m4, const float* __restrict__ m5,
    unsigned short* __restrict__ X6)
{
    int gid = blockIdx.x * 256 + threadIdx.x;
    int i4 = gid * 4;
    int bt = i4 / C_;
    int c  = i4 - bt * C_;
    const float4 xv = *(const float4*)(x + (size_t)bt * C_ + c);
    float px = 0.f, py = 0.f, pz = 0.f, pw = 0.f;
    if ((bt % T_) != 0) {
        const float4 p = *(const float4*)(x + (size_t)(bt - 1) * C_ + c);
        px = p.x; py = p.y; pz = p.z; pw = p.w;
    }
    float d0 = px - xv.x, d1 = py - xv.y, d2 = pz - xv.z, d3 = pw - xv.w;
    const float* mixes[6] = {m0, m1, m2, m3, m4, m5};
#pragma unroll
    for (int m = 0; m < 6; ++m) {
        const float4 mv = *(const float4*)(mixes[m] + c);
        u16x4 pk;
        pk[0] = f2bf(fmaf(d0, mv.x, xv.x));
        pk[1] = f2bf(fmaf(d1, mv.y, xv.y));
        pk[2] = f2bf(fmaf(d2, mv.z, xv.z));
        pk[3] = f2bf(fmaf(d3, mv.w, xv.w));
        *(u16x4*)(X6 + (size_t)m * BTC + (size_t)bt * C_ + c) = pk;
    }
}

// ---------------- kernel 2: ALL weight transposes in one dispatch ----------------
// fp32 W[R][Cc] -> bf16 W^T[Cc][R]; 2688 blocks segmented by blockIdx.x
__global__ __launch_bounds__(256) void k_transpose_all(
    const float* __restrict__ s0, const float* __restrict__ s1, const float* __restrict__ s2,
    const float* __restrict__ s3, const float* __restrict__ s4, const float* __restrict__ s5,
    const float* __restrict__ s6, const float* __restrict__ s7, const float* __restrict__ s8,
    const float* __restrict__ s9,
    unsigned short* __restrict__ d0, unsigned short* __restrict__ d1, unsigned short* __restrict__ d2,
    unsigned short* __restrict__ d3, unsigned short* __restrict__ d4, unsigned short* __restrict__ d5,
    unsigned short* __restrict__ d6, unsigned short* __restrict__ d7, unsigned short* __restrict__ d8,
    unsigned short* __restrict__ d9)
{
    __shared__ float tile[32][33];
    int bid = blockIdx.x;
    const float* W; unsigned short* WT; int R, Cc, loc;
    if (bid < 2304) {                 // 4x 768x768, 576 blocks each
        int w = bid / 576; loc = bid - w * 576;
        W = (w == 0) ? s0 : (w == 1) ? s1 : (w == 2) ? s2 : s3;
        WT = (w == 0) ? d0 : (w == 1) ? d1 : (w == 2) ? d2 : d3;
        R = 768; Cc = 768;
    } else if (bid < 2496) {          // w1(768x64) w2(64x768) a1 a2, 48 blocks each
        int w = (bid - 2304) / 48; loc = (bid - 2304) % 48;
        W = (w == 0) ? s4 : (w == 1) ? s5 : (w == 2) ? s6 : s7;
        WT = (w == 0) ? d4 : (w == 1) ? d5 : (w == 2) ? d6 : d7;
        R = (w & 1) ? 64 : 768; Cc = (w & 1) ? 768 : 64;
    } else {                          // g1(768x128) g2(128x768), 96 blocks each
        int w = (bid - 2496) / 96; loc = (bid - 2496) % 96;
        W = (w == 0) ? s8 : s9;
        WT = (w == 0) ? d8 : d9;
        R = (w == 0) ? 768 : 128; Cc = (w == 0) ? 128 : 768;
    }
    int bx = Cc / 32;
    int bxi = loc % bx, byi = loc / bx;
    int tx = threadIdx.x & 31, ty = threadIdx.x >> 5;
#pragma unroll
    for (int j = 0; j < 4; ++j) {
        int rr = byi * 32 + ty + j * 8;
        int cc = bxi * 32 + tx;
        tile[ty + j * 8][tx] = W[(size_t)rr * Cc + cc];
    }
    __syncthreads();
#pragma unroll
    for (int j = 0; j < 4; ++j) {
        int ro = bxi * 32 + ty + j * 8;
        int co = byi * 32 + tx;
        WT[(size_t)ro * R + co] = f2bf(tile[tx][ty + j * 8]);
    }
}

// ---------------- kernel 3a: 64-tile bf16 GEMM (small N) ----------------
// EPI: 1 raw bf16, 2 tanh bf16, 5 sigmoid bf16
template<int EPI>
__global__ __launch_bounds__(256) void k_gemm(const unsigned short* __restrict__ A,
    const unsigned short* __restrict__ Bt, void* __restrict__ Cp,
    const float* __restrict__ bias, int M, int Nn, int K)
{
    __shared__ unsigned short As[64][40];
    __shared__ unsigned short Bs[64][40];
    const int t = threadIdx.x, lane = t & 63, wave = t >> 6;
    const int wr = wave >> 1, wc = wave & 1;
    const int bM = blockIdx.y * 64, bN = blockIdx.x * 64;
    const int srow = t >> 2, skc = (t & 3) * 8;
    const int l15 = lane & 15, l16 = lane >> 4;
    f32x4 acc[2][2] = {};

    for (int k0 = 0; k0 < K; k0 += 32) {
        __syncthreads();
        *(int4*)&As[srow][skc] = *(const int4*)(A + (size_t)(bM + srow) * K + k0 + skc);
        *(int4*)&Bs[srow][skc] = *(const int4*)(Bt + (size_t)(bN + srow) * K + k0 + skc);
        __syncthreads();
        bf16x8 af0 = *(const bf16x8*)&As[wr * 32 + l15][l16 * 8];
        bf16x8 af1 = *(const bf16x8*)&As[wr * 32 + 16 + l15][l16 * 8];
        bf16x8 bf0 = *(const bf16x8*)&Bs[wc * 32 + l15][l16 * 8];
        bf16x8 bf1 = *(const bf16x8*)&Bs[wc * 32 + 16 + l15][l16 * 8];
        acc[0][0] = mfma16(af0, bf0, acc[0][0]);
        acc[0][1] = mfma16(af0, bf1, acc[0][1]);
        acc[1][0] = mfma16(af1, bf0, acc[1][0]);
        acc[1][1] = mfma16(af1, bf1, acc[1][1]);
    }

#pragma unroll
    for (int fm = 0; fm < 2; ++fm)
#pragma unroll
        for (int fn = 0; fn < 2; ++fn)
#pragma unroll
            for (int jj = 0; jj < 4; ++jj) {
                int gr = bM + wr * 32 + fm * 16 + l16 * 4 + jj;
                int gc = bN + wc * 32 + fn * 16 + l15;
                float val = acc[fm][fn][jj];
                size_t oi = (size_t)gr * Nn + gc;
                if constexpr (EPI == 1) {
                    ((unsigned short*)Cp)[oi] = f2bf(val);
                } else if constexpr (EPI == 2) {
                    ((unsigned short*)Cp)[oi] = f2bf(tanhf(val));
                } else {
                    ((unsigned short*)Cp)[oi] = f2bf(1.f / (1.f + expf(-val)));
                }
            }
}

// ---------------- kernel 3b: 128x128-tile GEMM with global_load_lds (m97 structure) ----------------
// EPI: 0 raw f32, 3 w-decay f32(bias), 4 sigmoid f32(bias)
template<int EPI>
__global__ __launch_bounds__(256) void k_gemm128(const unsigned short* __restrict__ A,
    const unsigned short* __restrict__ Bt, void* __restrict__ Cp,
    const float* __restrict__ bias, int M, int Nn, int K)
{
    __shared__ unsigned short As[128][32];
    __shared__ unsigned short Bs[128][32];
    const int tid = threadIdx.x, lane = tid & 63, wave = tid >> 6;
    const int wr = wave >> 1, wc = wave & 1;
    const int bM = blockIdx.y * 128, bN = blockIdx.x * 128;
    const int l15 = lane & 15, l16 = lane >> 4;
    const int srow = lane >> 2, scol = (lane & 3) * 8;
    f32x4 acc[4][4] = {};

    for (int k0 = 0; k0 < K; k0 += 32) {
        __syncthreads();
#pragma unroll
        for (int i = 0; i < 2; ++i) {
            int ch = i * 4 + wave;                 // chunk 0..7 (16 rows each)
            int row = ch * 16 + srow;
            gload16(A  + (size_t)(bM + row) * K + k0 + scol, &As[0][0] + ch * 512 + lane * 8);
            gload16(Bt + (size_t)(bN + row) * K + k0 + scol, &Bs[0][0] + ch * 512 + lane * 8);
        }
        __syncthreads();
        bf16x8 af[4], bfv[4];
#pragma unroll
        for (int m = 0; m < 4; ++m) af[m]  = *(const bf16x8*)&As[wr * 64 + m * 16 + l15][l16 * 8];
#pragma unroll
        for (int n = 0; n < 4; ++n) bfv[n] = *(const bf16x8*)&Bs[wc * 64 + n * 16 + l15][l16 * 8];
#pragma unroll
        for (int m = 0; m < 4; ++m)
#pragma unroll
            for (int n = 0; n < 4; ++n)
                acc[m][n] = mfma16(af[m], bfv[n], acc[m][n]);
    }

#pragma unroll
    for (int m = 0; m < 4; ++m)
#pragma unroll
        for (int n = 0; n < 4; ++n)
#pragma unroll
            for (int jj = 0; jj < 4; ++jj) {
                int gr = bM + wr * 64 + m * 16 + l16 * 4 + jj;
                int gc = bN + wc * 64 + n * 16 + l15;
                float val = acc[m][n][jj];
                size_t oi = (size_t)gr * Nn + gc;
                if constexpr (EPI == 0) {
                    ((float*)Cp)[oi] = val;
                } else if constexpr (EPI == 3) {
                    float z = bias[gc] + val;
                    float sg = 1.f / (1.f + expf(-z));
                    ((float*)Cp)[oi] = expf(-0.60653065971f * sg);
                } else {
                    float z = bias[gc] + val;
                    ((float*)Cp)[oi] = 1.f / (1.f + expf(-z));
                }
            }
}

// ---------------- kernel 4: kk normalize + k update + bonus dot ----------------
__global__ __launch_bounds__(256) void k_kproc(float* __restrict__ k, const float* __restrict__ a,
    const float* __restrict__ r, const float* __restrict__ k_k, const float* __restrict__ k_a,
    const float* __restrict__ r_k, float* __restrict__ kk, float* __restrict__ dotb)
{
    int gw = blockIdx.x * 4 + (threadIdx.x >> 6);
    int lane = threadIdx.x & 63;
    int bt = gw / H_, h = gw - (gw / H_) * H_;
    int c = h * 64 + lane;
    size_t idx = (size_t)bt * C_ + c;
    float kv = k[idx], av = a[idx], rv = r[idx];
    float kkv = kv * k_k[c];
    float ss = red64(kkv * kkv);
    float inv = 1.f / fmaxf(sqrtf(ss), 1e-12f);
    kk[idx] = kkv * inv;
    float knew = kv * (1.f + (av - 1.f) * k_a[c]);
    k[idx] = knew;
    float dot = red64(rv * knew * r_k[c]);
    if (lane == 0) dotb[bt * H_ + h] = dot;
}

// ---------------- F1a: cumprod + transforms, coalesced 32B stores ----------------
__global__ __launch_bounds__(256) void k_scanprep(const float* __restrict__ wdec,
    const float* __restrict__ kk, const float* __restrict__ asig, const float* __restrict__ kupd,
    const float* __restrict__ r, unsigned short* __restrict__ Abf, unsigned short* __restrict__ Bbf,
    unsigned short* __restrict__ Kbf, unsigned short* __restrict__ Rbf, float* __restrict__ cwL)
{
    __shared__ float CW[64][68];
    int hc = blockIdx.x;
    int g = hc >> 4, c = hc & 15;
    int b = g / H_, h = g - (g / H_) * H_;
    size_t rowb = ((size_t)(b * T_ + c * 64)) * C_ + h * 64;
    int tid = threadIdx.x;
    int t = tid >> 2, j0 = (tid & 3) * 16;
#pragma unroll
    for (int e = 0; e < 16; e += 4)
        *(float4*)&CW[t][j0 + e] = *(const float4*)(wdec + rowb + (size_t)t * C_ + j0 + e);
    __syncthreads();
    if (tid < 64) {
        float cp = 1.f;
#pragma unroll 4
        for (int tt = 0; tt < 64; ++tt) { cp *= CW[tt][tid]; CW[tt][tid] = cp; }
        cwL[hc * 64 + tid] = CW[63][tid];
    }
    __syncthreads();

    size_t base = (size_t)hc * 4096 + t * 64 + j0;
    size_t gin = rowb + (size_t)t * C_ + j0;
    float cwt[16], cwm[16], invc[16];
#pragma unroll
    for (int q = 0; q < 4; ++q) *(float4*)&cwt[q * 4] = *(const float4*)&CW[t][j0 + q * 4];
    if (t) {
#pragma unroll
        for (int q = 0; q < 4; ++q) *(float4*)&cwm[q * 4] = *(const float4*)&CW[t - 1][j0 + q * 4];
    } else {
#pragma unroll
        for (int e = 0; e < 16; ++e) cwm[e] = 1.f;
    }
#pragma unroll
    for (int e = 0; e < 16; ++e) invc[e] = 1.f / cwt[e];

    float kkv[16], tmp[16];
#pragma unroll
    for (int q = 0; q < 4; ++q) *(float4*)&kkv[q * 4] = *(const float4*)(kk + gin + q * 4);
    {   // A = -kk * cw_{t-1}
        u16x8 o0, o1;
#pragma unroll
        for (int e = 0; e < 8; ++e) { o0[e] = f2bf(-kkv[e] * cwm[e]); o1[e] = f2bf(-kkv[8 + e] * cwm[8 + e]); }
        *(u16x8*)(Abf + base) = o0; *(u16x8*)(Abf + base + 8) = o1;
    }
#pragma unroll
    for (int q = 0; q < 4; ++q) *(float4*)&tmp[q * 4] = *(const float4*)(asig + gin + q * 4);
    {   // B = kk * a / cw_t
        u16x8 o0, o1;
#pragma unroll
        for (int e = 0; e < 8; ++e) { o0[e] = f2bf(kkv[e] * tmp[e] * invc[e]); o1[e] = f2bf(kkv[8 + e] * tmp[8 + e] * invc[8 + e]); }
        *(u16x8*)(Bbf + base) = o0; *(u16x8*)(Bbf + base + 8) = o1;
    }
#pragma unroll
    for (int q = 0; q < 4; ++q) *(float4*)&tmp[q * 4] = *(const float4*)(kupd + gin + q * 4);
    {   // K = k / cw_t
        u16x8 o0, o1;
#pragma unroll
        for (int e = 0; e < 8; ++e) { o0[e] = f2bf(tmp[e] * invc[e]); o1[e] = f2bf(tmp[8 + e] * invc[8 + e]); }
        *(u16x8*)(Kbf + base) = o0; *(u16x8*)(Kbf + base + 8) = o1;
    }
#pragma unroll
    for (int q = 0; q < 4; ++q) *(float4*)&tmp[q * 4] = *(const float4*)(r + gin + q * 4);
    {   // R = r * cw_t
        u16x8 o0, o1;
#pragma unroll
        for (int e = 0; e < 8; ++e) { o0[e] = f2bf(tmp[e] * cwt[e]); o1[e] = f2bf(tmp[8 + e] * cwt[8 + e]); }
        *(u16x8*)(Rbf + base) = o0; *(u16x8*)(Rbf + base + 8) = o1;
    }
}

// ---------------- F1b: Gram matrices G(bf16,strict) H,P,Q(bf16) ----------------
__global__ __launch_bounds__(256) void k_gram(const unsigned short* __restrict__ Abf,
    const unsigned short* __restrict__ Bbf, const unsigned short* __restrict__ Kbf,
    const unsigned short* __restrict__ Rbf, unsigned short* __restrict__ Gbf,
    unsigned short* __restrict__ Hbf, unsigned short* __restrict__ Pbf, unsigned short* __restrict__ Qbf)
{
    __shared__ unsigned short SA[4][64][72];
    int hc = blockIdx.x, tid = threadIdx.x;
    size_t base = (size_t)hc * 4096;
    int r = tid >> 2, c0 = (tid & 3) * 16;
    const unsigned short* srcs[4] = {Abf, Bbf, Kbf, Rbf};
#pragma unroll
    for (int bu = 0; bu < 4; ++bu) {
        *(int4*)&SA[bu][r][c0]     = *(const int4*)(srcs[bu] + base + r * 64 + c0);
        *(int4*)&SA[bu][r][c0 + 8] = *(const int4*)(srcs[bu] + base + r * 64 + c0 + 8);
    }
    __syncthreads();
    int wave = tid >> 6, lane = tid & 63;
    int l15 = lane & 15, l16 = lane >> 4;
    const unsigned short (*Aop)[72] = (wave < 2) ? SA[0] : SA[3];
    const unsigned short (*Bop)[72] = (wave & 1) ? SA[2] : SA[1];
    f32x4 acc[4][4] = {};
    wave_gemm64(Aop, Bop, acc, lane);
    bool strict = (wave < 2);
#pragma unroll
    for (int m = 0; m < 4; ++m)
#pragma unroll
        for (int n = 0; n < 4; ++n)
#pragma unroll
            for (int jj = 0; jj < 4; ++jj) {
                int tt = m * 16 + l16 * 4 + jj;
                int ss = n * 16 + l15;
                float val = acc[m][n][jj];
                bool keep = strict ? (tt > ss) : (tt >= ss);
                val = keep ? val : 0.f;
                size_t oi = base + (size_t)tt * 64 + ss;
                if (wave == 0) Gbf[oi] = f2bf(val);
                else if (wave == 1) Hbf[oi] = f2bf(val);
                else if (wave == 2) Pbf[oi] = f2bf(val);
                else Qbf[oi] = f2bf(val);
            }
}

// ---------------- F2: P = (I-G)^-1 via nilpotent factorization, all MFMA ----------------
// Conflict-free staging: transposed LDS writes use lane=column mapping (rl, cl0).
__global__ __launch_bounds__(256) void k_solve(const unsigned short* __restrict__ Gbf,
    const unsigned short* __restrict__ Hbf, const unsigned short* __restrict__ Abf,
    const float* __restrict__ vbuf, unsigned short* __restrict__ Wtbf, unsigned short* __restrict__ U0tbf)
{
    __shared__ unsigned short Gc[64][72], GcT[64][72], Sx[64][72], SxT[64][72], Pm[64][72];
    int hc = blockIdx.x, tid = threadIdx.x;
    int g = hc >> 4, c = hc & 15;
    int b = g / H_, h = g - (g / H_) * H_;
    size_t rowb = ((size_t)(b * T_ + c * 64)) * C_ + h * 64;
    size_t base = (size_t)hc * 4096;
    int r = tid >> 2, c0 = (tid & 3) * 16;
    int rl = tid & 63, cl0 = (tid >> 6) * 16;
    int wave = tid >> 6, lane = tid & 63;
    int l15 = lane & 15, l16 = lane >> 4;

    // row-major Gc, Pm (int4 packed; diag of Pm = 1.0)
    {
        u16x8 va = *(const u16x8*)(Gbf + base + (size_t)r * 64 + c0);
        u16x8 vb = *(const u16x8*)(Gbf + base + (size_t)r * 64 + c0 + 8);
        *(u16x8*)&Gc[r][c0] = va;
        *(u16x8*)&Gc[r][c0 + 8] = vb;
        u16x8 pa = va, pb = vb;
        if (r >= c0 && r < c0 + 8) pa[r - c0] = 0x3F80;
        else if (r >= c0 + 8 && r < c0 + 16) pb[r - c0 - 8] = 0x3F80;
        *(u16x8*)&Pm[r][c0] = pa;
        *(u16x8*)&Pm[r][c0 + 8] = pb;
    }
    // transposed GcT: lane = column -> conflict-free
    {
        u16x8 va = *(const u16x8*)(Gbf + base + (size_t)rl * 64 + cl0);
        u16x8 vb = *(const u16x8*)(Gbf + base + (size_t)rl * 64 + cl0 + 8);
#pragma unroll
        for (int e = 0; e < 8; ++e) {
            GcT[cl0 + e][rl] = va[e];
            GcT[cl0 + 8 + e][rl] = vb[e];
        }
    }
    __syncthreads();

#pragma unroll
    for (int it = 0; it < 5; ++it) {
        const unsigned short (*Gs_)[72]  = (it & 1) ? Sx  : Gc;
        const unsigned short (*GsT_)[72] = (it & 1) ? SxT : GcT;
        unsigned short (*Ds_)[72]  = (it & 1) ? Gc  : Sx;
        unsigned short (*DsT_)[72] = (it & 1) ? GcT : SxT;
        {
            f32x4 acc[4] = {};
            gemm16(Gs_, GsT_, acc, wave, lane);
#pragma unroll
            for (int n = 0; n < 4; ++n)
#pragma unroll
                for (int jj = 0; jj < 4; ++jj) {
                    int ro = wave * 16 + l16 * 4 + jj, co = n * 16 + l15;
                    unsigned short sb = f2bf(acc[n][jj]);
                    Ds_[ro][co] = sb;
                    DsT_[co][ro] = sb;
                }
        }
        __syncthreads();
        {
            f32x4 acc[4] = {};
            gemm16(Pm, DsT_, acc, wave, lane);
#pragma unroll
            for (int n = 0; n < 4; ++n)
#pragma unroll
                for (int jj = 0; jj < 4; ++jj) {
                    int ro = wave * 16 + l16 * 4 + jj, co = n * 16 + l15;
                    Pm[ro][co] = f2bf(acc[n][jj] + bf2f(Pm[ro][co]));
                }
        }
        __syncthreads();
    }

    // reuse: Gc <- A^T, GcT <- V^T (lane=column, conflict-free), Sx <- H (row-major)
    {
        u16x8 va = *(const u16x8*)(Abf + base + (size_t)rl * 64 + cl0);
        u16x8 vb = *(const u16x8*)(Abf + base + (size_t)rl * 64 + cl0 + 8);
#pragma unroll
        for (int e = 0; e < 8; ++e) {
            Gc[cl0 + e][rl] = va[e];
            Gc[cl0 + 8 + e][rl] = vb[e];
        }
    }
#pragma unroll
    for (int q = 0; q < 4; ++q) {
        float4 v4 = *(const float4*)(vbuf + rowb + (size_t)rl * C_ + cl0 + q * 4);
        GcT[cl0 + q * 4 + 0][rl] = f2bf(v4.x);
        GcT[cl0 + q * 4 + 1][rl] = f2bf(v4.y);
        GcT[cl0 + q * 4 + 2][rl] = f2bf(v4.z);
        GcT[cl0 + q * 4 + 3][rl] = f2bf(v4.w);
    }
    *(int4*)&Sx[r][c0]     = *(const int4*)(Hbf + base + (size_t)r * 64 + c0);
    *(int4*)&Sx[r][c0 + 8] = *(const int4*)(Hbf + base + (size_t)r * 64 + c0 + 8);
    __syncthreads();
    {
        f32x4 acc[4] = {};
        gemm16(Sx, GcT, acc, wave, lane);
#pragma unroll
        for (int n = 0; n < 4; ++n)
#pragma unroll
            for (int jj = 0; jj < 4; ++jj) {
                int ro = wave * 16 + l16 * 4 + jj, co = n * 16 + l15;
                SxT[co][ro] = f2bf(acc[n][jj]);
            }
    }
    __syncthreads();
    {
        f32x4 wacc[4] = {}, uacc[4] = {};
        gemm16(Pm, Gc, wacc, wave, lane);
        gemm16(Pm, SxT, uacc, wave, lane);
#pragma unroll
        for (int n = 0; n < 4; ++n)
#pragma unroll
            for (int jj = 0; jj < 4; ++jj) {
                int ro = wave * 16 + l16 * 4 + jj, co = n * 16 + l15;
                Wtbf[base + (size_t)co * 64 + ro]  = f2bf(wacc[n][jj]);
                U0tbf[base + (size_t)co * 64 + ro] = f2bf(uacc[n][jj]);
            }
    }
}

// ---------------- F3: combine -> Tt(bf16,transposed), Z(bf16), E(bf16), F(bf16) ----------------
__global__ __launch_bounds__(256) void k_combine(const unsigned short* __restrict__ Pbf,
    const unsigned short* __restrict__ Qbf, const unsigned short* __restrict__ Wtbf,
    const unsigned short* __restrict__ U0tbf, const unsigned short* __restrict__ Bbf,
    const unsigned short* __restrict__ Kbf, const unsigned short* __restrict__ Rbf,
    const float* __restrict__ vbuf, const float* __restrict__ cwL,
    unsigned short* __restrict__ Ttbf, unsigned short* __restrict__ Zbf,
    unsigned short* __restrict__ Ebf, unsigned short* __restrict__ Fbf)
{
    __shared__ unsigned short S7[7][64][72];   // 0=P 1=Q 2=Wt 3=U0t 4=Bt 5=Kt 6=Vt
    int hc = blockIdx.x, tid = threadIdx.x;
    int g = hc >> 4, c = hc & 15;
    int b = g / H_, h = g - (g / H_) * H_;
    size_t rowb = ((size_t)(b * T_ + c * 64)) * C_ + h * 64;
    size_t base = (size_t)hc * 4096;
    int r = tid >> 2, c0 = (tid & 3) * 16;
    int rl = tid & 63, cl0 = (tid >> 6) * 16;
    const unsigned short* rm[4] = {Pbf, Qbf, Wtbf, U0tbf};
#pragma unroll
    for (int bu = 0; bu < 4; ++bu) {
        *(int4*)&S7[bu][r][c0]     = *(const int4*)(rm[bu] + base + r * 64 + c0);
        *(int4*)&S7[bu][r][c0 + 8] = *(const int4*)(rm[bu] + base + r * 64 + c0 + 8);
    }
    {   // transposed staging, lane = column -> conflict-free
        u16x8 vb0 = *(const u16x8*)(Bbf + base + (size_t)rl * 64 + cl0);
        u16x8 vb1 = *(const u16x8*)(Bbf + base + (size_t)rl * 64 + cl0 + 8);
        u16x8 vk0 = *(const u16x8*)(Kbf + base + (size_t)rl * 64 + cl0);
        u16x8 vk1 = *(const u16x8*)(Kbf + base + (size_t)rl * 64 + cl0 + 8);
#pragma unroll
        for (int e = 0; e < 8; ++e) {
            S7[4][cl0 + e][rl] = vb0[e];
            S7[4][cl0 + 8 + e][rl] = vb1[e];
            S7[5][cl0 + e][rl] = vk0[e];
            S7[5][cl0 + 8 + e][rl] = vk1[e];
        }
#pragma unroll
        for (int q = 0; q < 4; ++q) {
            float4 v4 = *(const float4*)(vbuf + rowb + (size_t)rl * C_ + cl0 + q * 4);
            S7[6][cl0 + q * 4 + 0][rl] = f2bf(v4.x);
            S7[6][cl0 + q * 4 + 1][rl] = f2bf(v4.y);
            S7[6][cl0 + q * 4 + 2][rl] = f2bf(v4.z);
            S7[6][cl0 + q * 4 + 3][rl] = f2bf(v4.w);
        }
    }
    __syncthreads();
    int wave = tid >> 6, lane = tid & 63;
    int l15 = lane & 15, l16 = lane >> 4;
    f32x4 acc[4][4] = {};
    if (wave == 0) wave_gemm64(S7[2], S7[4], acc, lane);
    else if (wave == 1) { wave_gemm64(S7[3], S7[4], acc, lane); wave_gemm64(S7[6], S7[5], acc, lane); }
    else if (wave == 2) wave_gemm64(S7[0], S7[2], acc, lane);
    else { wave_gemm64(S7[0], S7[3], acc, lane); wave_gemm64(S7[1], S7[6], acc, lane); }
#pragma unroll
    for (int m = 0; m < 4; ++m)
#pragma unroll
        for (int n = 0; n < 4; ++n)
#pragma unroll
            for (int jj = 0; jj < 4; ++jj) {
                int ro = m * 16 + l16 * 4 + jj;
                int co = n * 16 + l15;
                float val = acc[m][n][jj];
                if (wave == 0) {
                    val = (val + (ro == co ? 1.f : 0.f)) * cwL[hc * 64 + co];
                    Ttbf[base + (size_t)co * 64 + ro] = f2bf(val);
                } else if (wave == 1) {
                    Zbf[base + (size_t)ro * 64 + co] = f2bf(val * cwL[hc * 64 + co]);
                } else if (wave == 2) {
                    val += bf2f(Rbf[base + (size_t)ro * 64 + co]);
                    Ebf[base + (size_t)ro * 64 + co] = f2bf(val);
                } else {
                    Fbf[base + (size_t)ro * 64 + co] = f2bf(val);
                }
            }
}

// ---------------- F4: per-head serial chunk recursion S <- S T + Z ----------------
__global__ __launch_bounds__(256) void k_phaseB(const unsigned short* __restrict__ Ttbf,
    const unsigned short* __restrict__ Zbf, unsigned short* __restrict__ Sbf)
{
    __shared__ unsigned short Sb[2][64][72];
    __shared__ unsigned short Tt[64][72];
    int g = blockIdx.x, tid = threadIdx.x;
    int r = tid >> 2, c0 = (tid & 3) * 16;
    int4 z4 = {0, 0, 0, 0};
    *(int4*)&Sb[0][r][c0] = z4;
    *(int4*)&Sb[0][r][c0 + 8] = z4;
    int cur = 0;
    int wave = tid >> 6, lane = tid & 63;
    int wr = wave >> 1, wc = wave & 1;
    int l15 = lane & 15, l16 = lane >> 4;
    for (int c = 0; c < NCH; ++c) {
        size_t base = ((size_t)g * NCH + c) * 4096;
        __syncthreads();
        *(int4*)(Sbf + base + r * 64 + c0)     = *(int4*)&Sb[cur][r][c0];
        *(int4*)(Sbf + base + r * 64 + c0 + 8) = *(int4*)&Sb[cur][r][c0 + 8];
        *(int4*)&Tt[r][c0]     = *(const int4*)(Ttbf + base + r * 64 + c0);
        *(int4*)&Tt[r][c0 + 8] = *(const int4*)(Ttbf + base + r * 64 + c0 + 8);
        __syncthreads();
        f32x4 acc[2][2] = {};
#pragma unroll
        for (int kk2 = 0; kk2 < 2; ++kk2) {
            bf16x8 af[2], bfv[2];
#pragma unroll
            for (int m = 0; m < 2; ++m) af[m] = *(const bf16x8*)&Sb[cur][wr * 32 + m * 16 + l15][kk2 * 32 + l16 * 8];
#pragma unroll
            for (int n = 0; n < 2; ++n) bfv[n] = *(const bf16x8*)&Tt[wc * 32 + n * 16 + l15][kk2 * 32 + l16 * 8];
#pragma unroll
            for (int m = 0; m < 2; ++m)
#pragma unroll
                for (int n = 0; n < 2; ++n)
                    acc[m][n] = mfma16(af[m], bfv[n], acc[m][n]);
        }
#pragma unroll
        for (int m = 0; m < 2; ++m)
#pragma unroll
            for (int n = 0; n < 2; ++n)
#pragma unroll
                for (int jj = 0; jj < 4; ++jj) {
                    int ro = wr * 32 + m * 16 + l16 * 4 + jj;
                    int co = wc * 32 + n * 16 + l15;
                    float val = acc[m][n][jj] + bf2f(Zbf[base + (size_t)ro * 64 + co]);
                    Sb[cur ^ 1][ro][co] = f2bf(val);
                }
        cur ^= 1;
    }
}

// ---------------- F5: O = E S0^T + F -> obuf ----------------
__global__ __launch_bounds__(256) void k_phaseC(const unsigned short* __restrict__ Ebf,
    const unsigned short* __restrict__ Sbf, const unsigned short* __restrict__ Fbf,
    float* __restrict__ obuf)
{
    __shared__ unsigned short Es[64][72], Ss[64][72];
    int hc = blockIdx.x, tid = threadIdx.x;
    int g = hc >> 4, c = hc & 15;
    int b = g / H_, h = g - (g / H_) * H_;
    size_t rowb = ((size_t)(b * T_ + c * 64)) * C_ + h * 64;
    size_t base = (size_t)hc * 4096;
    int r = tid >> 2, c0 = (tid & 3) * 16;
    *(int4*)&Es[r][c0]     = *(const int4*)(Ebf + base + r * 64 + c0);
    *(int4*)&Es[r][c0 + 8] = *(const int4*)(Ebf + base + r * 64 + c0 + 8);
    *(int4*)&Ss[r][c0]     = *(const int4*)(Sbf + base + r * 64 + c0);
    *(int4*)&Ss[r][c0 + 8] = *(const int4*)(Sbf + base + r * 64 + c0 + 8);
    __syncthreads();
    int wave = tid >> 6, lane = tid & 63;
    int wr = wave >> 1, wc = wave & 1;
    int l15 = lane & 15, l16 = lane >> 4;
    f32x4 acc[2][2] = {};
#pragma unroll
    for (int kk2 = 0; kk2 < 2; ++kk2) {
        bf16x8 af[2], bfv[2];
#pragma unroll
        for (int m = 0; m < 2; ++m) af[m] = *(const bf16x8*)&Es[wr * 32 + m * 16 + l15][kk2 * 32 + l16 * 8];
#pragma unroll
        for (int n = 0; n < 2; ++n) bfv[n] = *(const bf16x8*)&Ss[wc * 32 + n * 16 + l15][kk2 * 32 + l16 * 8];
#pragma unroll
        for (int m = 0; m < 2; ++m)
#pragma unroll
            for (int n = 0; n < 2; ++n)
                acc[m][n] = mfma16(af[m], bfv[n], acc[m][n]);
    }
#pragma unroll
    for (int m = 0; m < 2; ++m)
#pragma unroll
        for (int n = 0; n < 2; ++n)
#pragma unroll
            for (int jj = 0; jj < 4; ++jj) {
                int tt = wr * 32 + m * 16 + l16 * 4 + jj;
                int ii = wc * 32 + n * 16 + l15;
                float val = acc[m][n][jj] + bf2f(Fbf[base + (size_t)tt * 64 + ii]);
                obuf[rowb + (size_t)tt * C_ + ii] = val;
            }
}

// ---------------- kernel 6: groupnorm + bonus + gate -> bf16 ----------------
__global__ __launch_bounds__(256) void k_gnorm(const float* __restrict__ o,
    const float* __restrict__ v, const float* __restrict__ g, const float* __restrict__ dotb,
    const float* __restrict__ gamma, const float* __restrict__ beta,
    unsigned short* __restrict__ yb)
{
    int gw = blockIdx.x * 4 + (threadIdx.x >> 6);
    int lane = threadIdx.x & 63;
    int bt = gw / H_, h = gw - (gw / H_) * H_;
    int c = h * 64 + lane;
    size_t idx = (size_t)bt * C_ + c;
    float ov = o[idx];
    float mean = red64(ov) * 0.015625f;
    float d = ov - mean;
    float var = red64(d * d) * 0.015625f;
    float yn = d * rsqrtf(var + EPS_GN) * gamma[c] + beta[c];
    float dot = dotb[bt * H_ + h];
    float y = (yn + dot * v[idx]) * g[idx];
    yb[idx] = f2bf(y);
}

// ---------------- host ----------------
extern "C" void kernel_launch(void* const* d_in, const int* in_sizes, int n_in,
                              void* d_out, int out_size, void* d_ws, size_t ws_size,
                              hipStream_t stream)
{
    (void)in_sizes; (void)n_in; (void)out_size; (void)ws_size;
    const float* x   = (const float*)d_in[0];
    const float* mr  = (const float*)d_in[1];
    const float* mw  = (const float*)d_in[2];
    const float* mk  = (const float*)d_in[3];
    const float* mv  = (const float*)d_in[4];
    const float* ma  = (const float*)d_in[5];
    const float* mg  = (const float*)d_in[6];
    const float* w0  = (const float*)d_in[7];
    const float* w1  = (const float*)d_in[8];
    const float* w2  = (const float*)d_in[9];
    const float* a0  = (const float*)d_in[10];
    const float* a1  = (const float*)d_in[11];
    const float* a2  = (const float*)d_in[12];
    const float* g1  = (const float*)d_in[13];
    const float* g2  = (const float*)d_in[14];
    const float* k_k = (const float*)d_in[15];
    const float* k_a = (const float*)d_in[16];
    const float* r_k = (const float*)d_in[17];
    const float* Wr  = (const float*)d_in[18];
    const float* Wk  = (const float*)d_in[19];
    const float* Wv  = (const float*)d_in[20];
    const float* Wo  = (const float*)d_in[21];
    const float* gam = (const float*)d_in[22];
    const float* bet = (const float*)d_in[23];

    char* ws = (char*)d_ws;
    constexpr size_t SZF = BTC * 4;
    constexpr size_t SZH = BTC * 2;
    unsigned short* X6  = (unsigned short*)ws;
    unsigned short* Abf = (unsigned short*)(ws + 0 * SZH);
    unsigned short* Bbf = (unsigned short*)(ws + 1 * SZH);
    unsigned short* Kbf = (unsigned short*)(ws + 2 * SZH);
    unsigned short* Rbf = (unsigned short*)(ws + 3 * SZH);
    unsigned short* Gbf = (unsigned short*)(ws + 4 * SZH);
    unsigned short* Ttbf = Abf;
    unsigned short* Zbf  = Gbf;
    float*          obuf = (float*)(ws + 1 * SZH);
    unsigned short* ybf  = (unsigned short*)(ws + 3 * SZH);

    size_t off = 6 * SZH;
    unsigned short* WrT = (unsigned short*)(ws + off); off += (size_t)768 * 768 * 2;
    unsigned short* WkT = (unsigned short*)(ws + off); off += (size_t)768 * 768 * 2;
    unsigned short* WvT = (unsigned short*)(ws + off); off += (size_t)768 * 768 * 2;
    unsigned short* WoT = (unsigned short*)(ws + off); off += (size_t)768 * 768 * 2;
    unsigned short* w1T = (unsigned short*)(ws + off); off += (size_t)64 * 768 * 2;
    unsigned short* w2T = (unsigned short*)(ws + off); off += (size_t)64 * 768 * 2;
    unsigned short* a1T = (unsigned short*)(ws + off); off += (size_t)64 * 768 * 2;
    unsigned short* a2T = (unsigned short*)(ws + off); off += (size_t)64 * 768 * 2;
    unsigned short* g1T = (unsigned short*)(ws + off); off += (size_t)128 * 768 * 2;
    unsigned short* g2T = (unsigned short*)(ws + off); off += (size_t)128 * 768 * 2;
    float* rbuf  = (float*)(ws + off); off += SZF;
    float* kbuf  = (float*)(ws + off); off += SZF;
    float* vbuf  = (float*)(ws + off); off += SZF;
    float* wdec  = (float*)(ws + off); off += SZF;
    float* abuf  = (float*)(ws + off); off += SZF;
    float* kkbuf = (float*)(ws + off); off += SZF;
    float* gbuf  = (float*)(ws + off); off += SZF;
    unsigned short* hw = (unsigned short*)(ws + off); off += (size_t)4096 * 64 * 2;
    unsigned short* ha = (unsigned short*)(ws + off); off += (size_t)4096 * 64 * 2;
    unsigned short* hg = (unsigned short*)(ws + off); off += (size_t)4096 * 128 * 2;
    unsigned short* Hbf   = (unsigned short*)abuf;
    unsigned short* Pbf   = (unsigned short*)((char*)abuf + SZH);
    unsigned short* Qbf   = (unsigned short*)kkbuf;
    unsigned short* Fbf   = (unsigned short*)((char*)kkbuf + SZH);
    unsigned short* Ebf   = Hbf;
    unsigned short* Sbf   = Pbf;
    unsigned short* Wtbf  = (unsigned short*)wdec;
    unsigned short* U0tbf = (unsigned short*)((char*)wdec + SZH);
    float* cwL  = (float*)hw;
    float* dotb = (float*)ha;

    k_prep<<<3072, 256, 0, stream>>>(x, mr, mw, mk, mv, ma, mg, X6);
    k_transpose_all<<<2688, 256, 0, stream>>>(Wr, Wk, Wv, Wo, w1, w2, a1, a2, g1, g2,
                                              WrT, WkT, WvT, WoT, w1T, w2T, a1T, a2T, g1T, g2T);
    // low-rank chains
    k_gemm<2><<<dim3(1, 64), 256, 0, stream>>>(X6 + 1 * BTC, w1T, hw, nullptr, 4096, 64, 768);
    k_gemm128<3><<<dim3(6, 32), 256, 0, stream>>>(hw, w2T, wdec, w0, 4096, 768, 64);
    k_gemm<1><<<dim3(1, 64), 256, 0, stream>>>(X6 + 4 * BTC, a1T, ha, nullptr, 4096, 64, 768);
    k_gemm128<4><<<dim3(6, 32), 256, 0, stream>>>(ha, a2T, abuf, a0, 4096, 768, 64);
    k_gemm<5><<<dim3(2, 64), 256, 0, stream>>>(X6 + 5 * BTC, g1T, hg, nullptr, 4096, 128, 768);
    k_gemm128<0><<<dim3(6, 32), 256, 0, stream>>>(hg, g2T, gbuf, nullptr, 4096, 768, 128);
    // r,k,v projections
    k_gemm128<0><<<dim3(6, 32), 256, 0, stream>>>(X6 + 0 * BTC, WrT, rbuf, nullptr, 4096, 768, 768);
    k_gemm128<0><<<dim3(6, 32), 256, 0, stream>>>(X6 + 2 * BTC, WkT, kbuf, nullptr, 4096, 768, 768);
    k_gemm128<0><<<dim3(6, 32), 256, 0, stream>>>(X6 + 3 * BTC, WvT, vbuf, nullptr, 4096, 768, 768);
    k_kproc<<<12288, 256, 0, stream>>>(kbuf, abuf, rbuf, k_k, k_a, r_k, kkbuf, dotb);
    // chunked generalized delta rule
    k_scanprep<<<HC_, 256, 0, stream>>>(wdec, kkbuf, abuf, kbuf, rbuf, Abf, Bbf, Kbf, Rbf, cwL);
    k_gram<<<HC_, 256, 0, stream>>>(Abf, Bbf, Kbf, Rbf, Gbf, Hbf, Pbf, Qbf);
    k_solve<<<HC_, 256, 0, stream>>>(Gbf, Hbf, Abf, vbuf, Wtbf, U0tbf);
    k_combine<<<HC_, 256, 0, stream>>>(Pbf, Qbf, Wtbf, U0tbf, Bbf, Kbf, Rbf, vbuf, cwL,
                                       Ttbf, Zbf, Ebf, Fbf);
    k_phaseB<<<48, 256, 0, stream>>>(Ttbf, Zbf, Sbf);
    k_phaseC<<<HC_, 256, 0, stream>>>(Ebf, Sbf, Fbf, obuf);
    k_gnorm<<<12288, 256, 0, stream>>>(obuf, vbuf, gbuf, dotb, gam, bet, ybf);
    k_gemm128<0><<<dim3(6, 32), 256, 0, stream>>>(ybf, WoT, (float*)d_out, nullptr, 4096, 768, 768);
}

// Round 8
// 418.956 us; speedup vs baseline: 3.9255x; 1.0334x over previous
//
#include <hip/hip_runtime.h>
#include <math.h>

// ---------------- constants ----------------
constexpr int B_ = 4, T_ = 1024, C_ = 768, H_ = 12, N_ = 64;
constexpr int BT_ = B_ * T_;                    // 4096
constexpr size_t BTC = (size_t)BT_ * C_;        // 3145728
constexpr float EPS_GN = 0.00064f;
constexpr int NCH = 16;                         // chunks per sequence (1024/64)
constexpr int HC_ = 48 * NCH;                   // 768 head-chunks

typedef __attribute__((ext_vector_type(8))) short bf16x8;
typedef __attribute__((ext_vector_type(4))) float f32x4;
typedef __attribute__((ext_vector_type(4))) unsigned short u16x4;
typedef __attribute__((ext_vector_type(8))) unsigned short u16x8;

#define DEVFN static __device__ __forceinline__

DEVFN unsigned short f2bf(float f) {
    unsigned u = __float_as_uint(f);
    unsigned r = u + 0x7FFFu + ((u >> 16) & 1u);
    return (unsigned short)(r >> 16);
}
DEVFN float bf2f(unsigned short u) { return __uint_as_float(((unsigned)u) << 16); }

template<int CTRL>
DEVFN float dppadd(float x) {
    return x + __int_as_float(__builtin_amdgcn_update_dpp(0, __float_as_int(x), CTRL, 0xF, 0xF, true));
}
#define SWZ_ADD(x, imm) ((x) + __int_as_float(__builtin_amdgcn_ds_swizzle(__float_as_int(x), (imm))))

DEVFN float red64(float x) {
    x = dppadd<0xB1>(x);
    x = dppadd<0x4E>(x);
    x = SWZ_ADD(x, 0x101F);
    x = SWZ_ADD(x, 0x201F);
    x = SWZ_ADD(x, 0x401F);
    x += __shfl_xor(x, 32, 64);
    return x;
}

DEVFN f32x4 mfma16(bf16x8 a, bf16x8 b, f32x4 c) {
    return __builtin_amdgcn_mfma_f32_16x16x32_bf16(a, b, c, 0, 0, 0);
}

typedef const __attribute__((address_space(1))) unsigned int* gas_t;
typedef __attribute__((address_space(3))) unsigned int* las_t;
DEVFN void gload16(const void* g, void* l) {
    __builtin_amdgcn_global_load_lds((gas_t)g, (las_t)l, 16, 0, 0);
}

// full 64x64x64 GEMM for one wave from LDS [64][72] bf16 operands; ACCUMULATES into acc
// out[ro][co] = sum_k A[ro][k] * Bt[co][k]
DEVFN void wave_gemm64(const unsigned short (*A)[72], const unsigned short (*Bt)[72],
                       f32x4 acc[4][4], int lane) {
    int l15 = lane & 15, l16 = lane >> 4;
#pragma unroll
    for (int kk2 = 0; kk2 < 2; ++kk2) {
        bf16x8 af[4], bfv[4];
#pragma unroll
        for (int m = 0; m < 4; ++m) af[m] = *(const bf16x8*)&A[m * 16 + l15][kk2 * 32 + l16 * 8];
#pragma unroll
        for (int n = 0; n < 4; ++n) bfv[n] = *(const bf16x8*)&Bt[n * 16 + l15][kk2 * 32 + l16 * 8];
#pragma unroll
        for (int m = 0; m < 4; ++m)
#pragma unroll
            for (int n = 0; n < 4; ++n)
                acc[m][n] = mfma16(af[m], bfv[n], acc[m][n]);
    }
}

// 16-rows-per-wave 64x64x64 GEMM: wave w computes output rows [w*16, w*16+16)
DEVFN void gemm16(const unsigned short (*A)[72], const unsigned short (*Bt)[72],
                  f32x4 acc[4], int wave, int lane) {
    int l15 = lane & 15, l16 = lane >> 4;
#pragma unroll
    for (int kk2 = 0; kk2 < 2; ++kk2) {
        bf16x8 af = *(const bf16x8*)&A[wave * 16 + l15][kk2 * 32 + l16 * 8];
        bf16x8 bfv[4];
#pragma unroll
        for (int n = 0; n < 4; ++n) bfv[n] = *(const bf16x8*)&Bt[n * 16 + l15][kk2 * 32 + l16 * 8];
#pragma unroll
        for (int n = 0; n < 4; ++n) acc[n] = mfma16(af, bfv[n], acc[n]);
    }
}

// ---------------- kernel 1: timeshift + 6 mixes -> bf16 ----------------
__global__ __launch_bounds__(256) void k_prep(const float* __restrict__ x,
    const float* __restrict__ m0, const float* __restrict__ m1, const float* __restrict__ m2,
    const float* __restrict__ m3, const float* __restrict__ m4, const float* __restrict__ m5,
    unsigned short* __restrict__ X6)
{
    int gid = blockIdx.x * 256 + threadIdx.x;
    int i4 = gid * 4;
    int bt = i4 / C_;
    int c  = i4 - bt * C_;
    const float4 xv = *(const float4*)(x + (size_t)bt * C_ + c);
    float px = 0.f, py = 0.f, pz = 0.f, pw = 0.f;
    if ((bt % T_) != 0) {
        const float4 p = *(const float4*)(x + (size_t)(bt - 1) * C_ + c);
        px = p.x; py = p.y; pz = p.z; pw = p.w;
    }
    float d0 = px - xv.x, d1 = py - xv.y, d2 = pz - xv.z, d3 = pw - xv.w;
    const float* mixes[6] = {m0, m1, m2, m3, m4, m5};
#pragma unroll
    for (int m = 0; m < 6; ++m) {
        const float4 mv = *(const float4*)(mixes[m] + c);
        u16x4 pk;
        pk[0] = f2bf(fmaf(d0, mv.x, xv.x));
        pk[1] = f2bf(fmaf(d1, mv.y, xv.y));
        pk[2] = f2bf(fmaf(d2, mv.z, xv.z));
        pk[3] = f2bf(fmaf(d3, mv.w, xv.w));
        *(u16x4*)(X6 + (size_t)m * BTC + (size_t)bt * C_ + c) = pk;
    }
}

// ---------------- kernel 2: ALL weight transposes in one dispatch ----------------
__global__ __launch_bounds__(256) void k_transpose_all(
    const float* __restrict__ s0, const float* __restrict__ s1, const float* __restrict__ s2,
    const float* __restrict__ s3, const float* __restrict__ s4, const float* __restrict__ s5,
    const float* __restrict__ s6, const float* __restrict__ s7, const float* __restrict__ s8,
    const float* __restrict__ s9,
    unsigned short* __restrict__ d0, unsigned short* __restrict__ d1, unsigned short* __restrict__ d2,
    unsigned short* __restrict__ d3, unsigned short* __restrict__ d4, unsigned short* __restrict__ d5,
    unsigned short* __restrict__ d6, unsigned short* __restrict__ d7, unsigned short* __restrict__ d8,
    unsigned short* __restrict__ d9)
{
    __shared__ float tile[32][33];
    int bid = blockIdx.x;
    const float* W; unsigned short* WT; int R, Cc, loc;
    if (bid < 2304) {
        int w = bid / 576; loc = bid - w * 576;
        W = (w == 0) ? s0 : (w == 1) ? s1 : (w == 2) ? s2 : s3;
        WT = (w == 0) ? d0 : (w == 1) ? d1 : (w == 2) ? d2 : d3;
        R = 768; Cc = 768;
    } else if (bid < 2496) {
        int w = (bid - 2304) / 48; loc = (bid - 2304) % 48;
        W = (w == 0) ? s4 : (w == 1) ? s5 : (w == 2) ? s6 : s7;
        WT = (w == 0) ? d4 : (w == 1) ? d5 : (w == 2) ? d6 : d7;
        R = (w & 1) ? 64 : 768; Cc = (w & 1) ? 768 : 64;
    } else {
        int w = (bid - 2496) / 96; loc = (bid - 2496) % 96;
        W = (w == 0) ? s8 : s9;
        WT = (w == 0) ? d8 : d9;
        R = (w == 0) ? 768 : 128; Cc = (w == 0) ? 128 : 768;
    }
    int bx = Cc / 32;
    int bxi = loc % bx, byi = loc / bx;
    int tx = threadIdx.x & 31, ty = threadIdx.x >> 5;
#pragma unroll
    for (int j = 0; j < 4; ++j) {
        int rr = byi * 32 + ty + j * 8;
        int cc = bxi * 32 + tx;
        tile[ty + j * 8][tx] = W[(size_t)rr * Cc + cc];
    }
    __syncthreads();
#pragma unroll
    for (int j = 0; j < 4; ++j) {
        int ro = bxi * 32 + ty + j * 8;
        int co = byi * 32 + tx;
        WT[(size_t)ro * R + co] = f2bf(tile[tx][ty + j * 8]);
    }
}

// ---------------- kernel 3a: 64-tile bf16 GEMM (small N) ----------------
template<int EPI>
__global__ __launch_bounds__(256) void k_gemm(const unsigned short* __restrict__ A,
    const unsigned short* __restrict__ Bt, void* __restrict__ Cp,
    const float* __restrict__ bias, int M, int Nn, int K)
{
    __shared__ unsigned short As[64][40];
    __shared__ unsigned short Bs[64][40];
    const int t = threadIdx.x, lane = t & 63, wave = t >> 6;
    const int wr = wave >> 1, wc = wave & 1;
    const int bM = blockIdx.y * 64, bN = blockIdx.x * 64;
    const int srow = t >> 2, skc = (t & 3) * 8;
    const int l15 = lane & 15, l16 = lane >> 4;
    f32x4 acc[2][2] = {};

    for (int k0 = 0; k0 < K; k0 += 32) {
        __syncthreads();
        *(int4*)&As[srow][skc] = *(const int4*)(A + (size_t)(bM + srow) * K + k0 + skc);
        *(int4*)&Bs[srow][skc] = *(const int4*)(Bt + (size_t)(bN + srow) * K + k0 + skc);
        __syncthreads();
        bf16x8 af0 = *(const bf16x8*)&As[wr * 32 + l15][l16 * 8];
        bf16x8 af1 = *(const bf16x8*)&As[wr * 32 + 16 + l15][l16 * 8];
        bf16x8 bf0 = *(const bf16x8*)&Bs[wc * 32 + l15][l16 * 8];
        bf16x8 bf1 = *(const bf16x8*)&Bs[wc * 32 + 16 + l15][l16 * 8];
        acc[0][0] = mfma16(af0, bf0, acc[0][0]);
        acc[0][1] = mfma16(af0, bf1, acc[0][1]);
        acc[1][0] = mfma16(af1, bf0, acc[1][0]);
        acc[1][1] = mfma16(af1, bf1, acc[1][1]);
    }

#pragma unroll
    for (int fm = 0; fm < 2; ++fm)
#pragma unroll
        for (int fn = 0; fn < 2; ++fn)
#pragma unroll
            for (int jj = 0; jj < 4; ++jj) {
                int gr = bM + wr * 32 + fm * 16 + l16 * 4 + jj;
                int gc = bN + wc * 32 + fn * 16 + l15;
                float val = acc[fm][fn][jj];
                size_t oi = (size_t)gr * Nn + gc;
                if constexpr (EPI == 1) {
                    ((unsigned short*)Cp)[oi] = f2bf(val);
                } else if constexpr (EPI == 2) {
                    ((unsigned short*)Cp)[oi] = f2bf(tanhf(val));
                } else {
                    ((unsigned short*)Cp)[oi] = f2bf(1.f / (1.f + expf(-val)));
                }
            }
}

// ---------------- kernel 3b: 128x128-tile GEMM with global_load_lds ----------------
template<int EPI>
__global__ __launch_bounds__(256) void k_gemm128(const unsigned short* __restrict__ A,
    const unsigned short* __restrict__ Bt, void* __restrict__ Cp,
    const float* __restrict__ bias, int M, int Nn, int K)
{
    __shared__ unsigned short As[128][32];
    __shared__ unsigned short Bs[128][32];
    const int tid = threadIdx.x, lane = tid & 63, wave = tid >> 6;
    const int wr = wave >> 1, wc = wave & 1;
    const int bM = blockIdx.y * 128, bN = blockIdx.x * 128;
    const int l15 = lane & 15, l16 = lane >> 4;
    const int srow = lane >> 2, scol = (lane & 3) * 8;
    f32x4 acc[4][4] = {};

    for (int k0 = 0; k0 < K; k0 += 32) {
        __syncthreads();
#pragma unroll
        for (int i = 0; i < 2; ++i) {
            int ch = i * 4 + wave;
            int row = ch * 16 + srow;
            gload16(A  + (size_t)(bM + row) * K + k0 + scol, &As[0][0] + ch * 512 + lane * 8);
            gload16(Bt + (size_t)(bN + row) * K + k0 + scol, &Bs[0][0] + ch * 512 + lane * 8);
        }
        __syncthreads();
        bf16x8 af[4], bfv[4];
#pragma unroll
        for (int m = 0; m < 4; ++m) af[m]  = *(const bf16x8*)&As[wr * 64 + m * 16 + l15][l16 * 8];
#pragma unroll
        for (int n = 0; n < 4; ++n) bfv[n] = *(const bf16x8*)&Bs[wc * 64 + n * 16 + l15][l16 * 8];
#pragma unroll
        for (int m = 0; m < 4; ++m)
#pragma unroll
            for (int n = 0; n < 4; ++n)
                acc[m][n] = mfma16(af[m], bfv[n], acc[m][n]);
    }

#pragma unroll
    for (int m = 0; m < 4; ++m)
#pragma unroll
        for (int n = 0; n < 4; ++n)
#pragma unroll
            for (int jj = 0; jj < 4; ++jj) {
                int gr = bM + wr * 64 + m * 16 + l16 * 4 + jj;
                int gc = bN + wc * 64 + n * 16 + l15;
                float val = acc[m][n][jj];
                size_t oi = (size_t)gr * Nn + gc;
                if constexpr (EPI == 0) {
                    ((float*)Cp)[oi] = val;
                } else if constexpr (EPI == 3) {
                    float z = bias[gc] + val;
                    float sg = 1.f / (1.f + expf(-z));
                    ((float*)Cp)[oi] = expf(-0.60653065971f * sg);
                } else {
                    float z = bias[gc] + val;
                    ((float*)Cp)[oi] = 1.f / (1.f + expf(-z));
                }
            }
}

// ---------------- kernel 4: kk normalize + k update + bonus dot ----------------
__global__ __launch_bounds__(256) void k_kproc(float* __restrict__ k, const float* __restrict__ a,
    const float* __restrict__ r, const float* __restrict__ k_k, const float* __restrict__ k_a,
    const float* __restrict__ r_k, float* __restrict__ kk, float* __restrict__ dotb)
{
    int gw = blockIdx.x * 4 + (threadIdx.x >> 6);
    int lane = threadIdx.x & 63;
    int bt = gw / H_, h = gw - (gw / H_) * H_;
    int c = h * 64 + lane;
    size_t idx = (size_t)bt * C_ + c;
    float kv = k[idx], av = a[idx], rv = r[idx];
    float kkv = kv * k_k[c];
    float ss = red64(kkv * kkv);
    float inv = 1.f / fmaxf(sqrtf(ss), 1e-12f);
    kk[idx] = kkv * inv;
    float knew = kv * (1.f + (av - 1.f) * k_a[c]);
    k[idx] = knew;
    float dot = red64(rv * knew * r_k[c]);
    if (lane == 0) dotb[bt * H_ + h] = dot;
}

// ---------------- F1a: cumprod + transforms, coalesced 32B stores ----------------
__global__ __launch_bounds__(256) void k_scanprep(const float* __restrict__ wdec,
    const float* __restrict__ kk, const float* __restrict__ asig, const float* __restrict__ kupd,
    const float* __restrict__ r, unsigned short* __restrict__ Abf, unsigned short* __restrict__ Bbf,
    unsigned short* __restrict__ Kbf, unsigned short* __restrict__ Rbf, float* __restrict__ cwL)
{
    __shared__ float CW[64][68];
    int hc = blockIdx.x;
    int g = hc >> 4, c = hc & 15;
    int b = g / H_, h = g - (g / H_) * H_;
    size_t rowb = ((size_t)(b * T_ + c * 64)) * C_ + h * 64;
    int tid = threadIdx.x;
    int t = tid >> 2, j0 = (tid & 3) * 16;
#pragma unroll
    for (int e = 0; e < 16; e += 4)
        *(float4*)&CW[t][j0 + e] = *(const float4*)(wdec + rowb + (size_t)t * C_ + j0 + e);
    __syncthreads();
    if (tid < 64) {
        float cp = 1.f;
#pragma unroll 4
        for (int tt = 0; tt < 64; ++tt) { cp *= CW[tt][tid]; CW[tt][tid] = cp; }
        cwL[hc * 64 + tid] = CW[63][tid];
    }
    __syncthreads();

    size_t base = (size_t)hc * 4096 + t * 64 + j0;
    size_t gin = rowb + (size_t)t * C_ + j0;
    float cwt[16], cwm[16], invc[16];
#pragma unroll
    for (int q = 0; q < 4; ++q) *(float4*)&cwt[q * 4] = *(const float4*)&CW[t][j0 + q * 4];
    if (t) {
#pragma unroll
        for (int q = 0; q < 4; ++q) *(float4*)&cwm[q * 4] = *(const float4*)&CW[t - 1][j0 + q * 4];
    } else {
#pragma unroll
        for (int e = 0; e < 16; ++e) cwm[e] = 1.f;
    }
#pragma unroll
    for (int e = 0; e < 16; ++e) invc[e] = 1.f / cwt[e];

    float kkv[16], tmp[16];
#pragma unroll
    for (int q = 0; q < 4; ++q) *(float4*)&kkv[q * 4] = *(const float4*)(kk + gin + q * 4);
    {
        u16x8 o0, o1;
#pragma unroll
        for (int e = 0; e < 8; ++e) { o0[e] = f2bf(-kkv[e] * cwm[e]); o1[e] = f2bf(-kkv[8 + e] * cwm[8 + e]); }
        *(u16x8*)(Abf + base) = o0; *(u16x8*)(Abf + base + 8) = o1;
    }
#pragma unroll
    for (int q = 0; q < 4; ++q) *(float4*)&tmp[q * 4] = *(const float4*)(asig + gin + q * 4);
    {
        u16x8 o0, o1;
#pragma unroll
        for (int e = 0; e < 8; ++e) { o0[e] = f2bf(kkv[e] * tmp[e] * invc[e]); o1[e] = f2bf(kkv[8 + e] * tmp[8 + e] * invc[8 + e]); }
        *(u16x8*)(Bbf + base) = o0; *(u16x8*)(Bbf + base + 8) = o1;
    }
#pragma unroll
    for (int q = 0; q < 4; ++q) *(float4*)&tmp[q * 4] = *(const float4*)(kupd + gin + q * 4);
    {
        u16x8 o0, o1;
#pragma unroll
        for (int e = 0; e < 8; ++e) { o0[e] = f2bf(tmp[e] * invc[e]); o1[e] = f2bf(tmp[8 + e] * invc[8 + e]); }
        *(u16x8*)(Kbf + base) = o0; *(u16x8*)(Kbf + base + 8) = o1;
    }
#pragma unroll
    for (int q = 0; q < 4; ++q) *(float4*)&tmp[q * 4] = *(const float4*)(r + gin + q * 4);
    {
        u16x8 o0, o1;
#pragma unroll
        for (int e = 0; e < 8; ++e) { o0[e] = f2bf(tmp[e] * cwt[e]); o1[e] = f2bf(tmp[8 + e] * cwt[8 + e]); }
        *(u16x8*)(Rbf + base) = o0; *(u16x8*)(Rbf + base + 8) = o1;
    }
}

// ---------------- k_chunk: FUSED gram + solve + combine (all intermediates in LDS) ----------------
// LDS slots: 0=G 1=G^T 2=A->A^T 3=B->B^T 4=K->K^T 5=R 6=V^T 7=H->(HV)^T 8=P 9=Q
//            10=Sx/W^T 11=SxT/U0^T 12=Pm     (13 x 9216B = 117KB, 1 block/CU)
__global__ __launch_bounds__(256) void k_chunk(const unsigned short* __restrict__ Abf,
    const unsigned short* __restrict__ Bbf, const unsigned short* __restrict__ Kbf,
    const unsigned short* __restrict__ Rbf, const float* __restrict__ vbuf,
    const float* __restrict__ cwL,
    unsigned short* __restrict__ Ttbf, unsigned short* __restrict__ Zbf,
    unsigned short* __restrict__ Ebf, unsigned short* __restrict__ Fbf)
{
    __shared__ unsigned short L[13][64][72];
    int hc = blockIdx.x, tid = threadIdx.x;
    int g = hc >> 4, c = hc & 15;
    int b = g / H_, h = g - (g / H_) * H_;
    size_t rowb = ((size_t)(b * T_ + c * 64)) * C_ + h * 64;
    size_t base = (size_t)hc * 4096;
    int r = tid >> 2, c0 = (tid & 3) * 16;
    int rl = tid & 63, cl0 = (tid >> 6) * 16;
    int wave = tid >> 6, lane = tid & 63;
    int l15 = lane & 15, l16 = lane >> 4;

    // ---- stage A,B,K,R row-major + V^T (lane=col, conflict-free) ----
    *(int4*)&L[2][r][c0]     = *(const int4*)(Abf + base + r * 64 + c0);
    *(int4*)&L[2][r][c0 + 8] = *(const int4*)(Abf + base + r * 64 + c0 + 8);
    *(int4*)&L[3][r][c0]     = *(const int4*)(Bbf + base + r * 64 + c0);
    *(int4*)&L[3][r][c0 + 8] = *(const int4*)(Bbf + base + r * 64 + c0 + 8);
    *(int4*)&L[4][r][c0]     = *(const int4*)(Kbf + base + r * 64 + c0);
    *(int4*)&L[4][r][c0 + 8] = *(const int4*)(Kbf + base + r * 64 + c0 + 8);
    *(int4*)&L[5][r][c0]     = *(const int4*)(Rbf + base + r * 64 + c0);
    *(int4*)&L[5][r][c0 + 8] = *(const int4*)(Rbf + base + r * 64 + c0 + 8);
#pragma unroll
    for (int q = 0; q < 4; ++q) {
        float4 v4 = *(const float4*)(vbuf + rowb + (size_t)rl * C_ + cl0 + q * 4);
        L[6][cl0 + q * 4 + 0][rl] = f2bf(v4.x);
        L[6][cl0 + q * 4 + 1][rl] = f2bf(v4.y);
        L[6][cl0 + q * 4 + 2][rl] = f2bf(v4.z);
        L[6][cl0 + q * 4 + 3][rl] = f2bf(v4.w);
    }
    __syncthreads();

    // ---- phase A: G (strict, dual + Pm init), H (strict), P (tril), Q (tril) ----
    {
        f32x4 ga[4] = {};
        gemm16(L[2], L[3], ga, wave, lane);
#pragma unroll
        for (int n = 0; n < 4; ++n)
#pragma unroll
            for (int jj = 0; jj < 4; ++jj) {
                int ro = wave * 16 + l16 * 4 + jj, co = n * 16 + l15;
                float val = (ro > co) ? ga[n][jj] : 0.f;
                unsigned short gb = f2bf(val);
                L[0][ro][co] = gb;
                L[1][co][ro] = gb;
                L[12][ro][co] = (ro == co) ? (unsigned short)0x3F80 : gb;
            }
    }
    {
        f32x4 ha[4] = {};
        gemm16(L[2], L[4], ha, wave, lane);
#pragma unroll
        for (int n = 0; n < 4; ++n)
#pragma unroll
            for (int jj = 0; jj < 4; ++jj) {
                int ro = wave * 16 + l16 * 4 + jj, co = n * 16 + l15;
                L[7][ro][co] = f2bf((ro > co) ? ha[n][jj] : 0.f);
            }
    }
    {
        f32x4 pa[4] = {};
        gemm16(L[5], L[3], pa, wave, lane);
#pragma unroll
        for (int n = 0; n < 4; ++n)
#pragma unroll
            for (int jj = 0; jj < 4; ++jj) {
                int ro = wave * 16 + l16 * 4 + jj, co = n * 16 + l15;
                L[8][ro][co] = f2bf((ro >= co) ? pa[n][jj] : 0.f);
            }
    }
    {
        f32x4 qa[4] = {};
        gemm16(L[5], L[4], qa, wave, lane);
#pragma unroll
        for (int n = 0; n < 4; ++n)
#pragma unroll
            for (int jj = 0; jj < 4; ++jj) {
                int ro = wave * 16 + l16 * 4 + jj, co = n * 16 + l15;
                L[9][ro][co] = f2bf((ro >= co) ? qa[n][jj] : 0.f);
            }
    }
    __syncthreads();

    // ---- phase B: HV into regs; read rows of A,B,K for in-place transpose ----
    f32x4 hv[4] = {};
    gemm16(L[7], L[6], hv, wave, lane);
    u16x8 ta0 = *(const u16x8*)&L[2][rl][cl0], ta1 = *(const u16x8*)&L[2][rl][cl0 + 8];
    u16x8 tb0 = *(const u16x8*)&L[3][rl][cl0], tb1 = *(const u16x8*)&L[3][rl][cl0 + 8];
    u16x8 tk0 = *(const u16x8*)&L[4][rl][cl0], tk1 = *(const u16x8*)&L[4][rl][cl0 + 8];
    __syncthreads();
    // write transposed A,B,K (lane=col, conflict-free); (HV)^T over H
#pragma unroll
    for (int e = 0; e < 8; ++e) {
        L[2][cl0 + e][rl] = ta0[e]; L[2][cl0 + 8 + e][rl] = ta1[e];
        L[3][cl0 + e][rl] = tb0[e]; L[3][cl0 + 8 + e][rl] = tb1[e];
        L[4][cl0 + e][rl] = tk0[e]; L[4][cl0 + 8 + e][rl] = tk1[e];
    }
#pragma unroll
    for (int n = 0; n < 4; ++n)
#pragma unroll
        for (int jj = 0; jj < 4; ++jj) {
            int ro = wave * 16 + l16 * 4 + jj, co = n * 16 + l15;
            L[7][co][ro] = f2bf(hv[n][jj]);
        }
    __syncthreads();

    // ---- solve: Pm = (I-G)^-1 via 5 squarings ----
#pragma unroll
    for (int it = 0; it < 5; ++it) {
        const unsigned short (*Gs_)[72]  = (it & 1) ? L[10] : L[0];
        const unsigned short (*GsT_)[72] = (it & 1) ? L[11] : L[1];
        unsigned short (*Ds_)[72]  = (it & 1) ? L[0] : L[10];
        unsigned short (*DsT_)[72] = (it & 1) ? L[1] : L[11];
        {
            f32x4 acc[4] = {};
            gemm16(Gs_, GsT_, acc, wave, lane);
#pragma unroll
            for (int n = 0; n < 4; ++n)
#pragma unroll
                for (int jj = 0; jj < 4; ++jj) {
                    int ro = wave * 16 + l16 * 4 + jj, co = n * 16 + l15;
                    unsigned short sb = f2bf(acc[n][jj]);
                    Ds_[ro][co] = sb;
                    DsT_[co][ro] = sb;
                }
        }
        __syncthreads();
        {
            f32x4 acc[4] = {};
            gemm16(L[12], DsT_, acc, wave, lane);
#pragma unroll
            for (int n = 0; n < 4; ++n)
#pragma unroll
                for (int jj = 0; jj < 4; ++jj) {
                    int ro = wave * 16 + l16 * 4 + jj, co = n * 16 + l15;
                    L[12][ro][co] = f2bf(acc[n][jj] + bf2f(L[12][ro][co]));
                }
        }
        __syncthreads();
    }

    // ---- W = Pm·A (B-op = A^T in L2), U0 = Pm·(HV) (B-op = (HV)^T in L7) ----
    {
        f32x4 wv[4] = {}, uv[4] = {};
        gemm16(L[12], L[2], wv, wave, lane);
        gemm16(L[12], L[7], uv, wave, lane);
#pragma unroll
        for (int n = 0; n < 4; ++n)
#pragma unroll
            for (int jj = 0; jj < 4; ++jj) {
                int ro = wave * 16 + l16 * 4 + jj, co = n * 16 + l15;
                L[10][co][ro] = f2bf(wv[n][jj]);   // W^T
                L[11][co][ro] = f2bf(uv[n][jj]);   // U0^T
            }
    }
    __syncthreads();

    // ---- combine (wave-specialized, identical semantics to verified k_combine) ----
    f32x4 acc[4][4] = {};
    if (wave == 0) wave_gemm64(L[10], L[3], acc, lane);
    else if (wave == 1) { wave_gemm64(L[11], L[3], acc, lane); wave_gemm64(L[6], L[4], acc, lane); }
    else if (wave == 2) wave_gemm64(L[8], L[10], acc, lane);
    else { wave_gemm64(L[8], L[11], acc, lane); wave_gemm64(L[9], L[6], acc, lane); }
#pragma unroll
    for (int m = 0; m < 4; ++m)
#pragma unroll
        for (int n = 0; n < 4; ++n)
#pragma unroll
            for (int jj = 0; jj < 4; ++jj) {
                int ro = m * 16 + l16 * 4 + jj;
                int co = n * 16 + l15;
                float val = acc[m][n][jj];
                if (wave == 0) {
                    val = (val + (ro == co ? 1.f : 0.f)) * cwL[hc * 64 + co];
                    Ttbf[base + (size_t)co * 64 + ro] = f2bf(val);
                } else if (wave == 1) {
                    Zbf[base + (size_t)ro * 64 + co] = f2bf(val * cwL[hc * 64 + co]);
                } else if (wave == 2) {
                    val += bf2f(L[5][ro][co]);
                    Ebf[base + (size_t)ro * 64 + co] = f2bf(val);
                } else {
                    Fbf[base + (size_t)ro * 64 + co] = f2bf(val);
                }
            }
}

// ---------------- F4: per-head serial chunk recursion S <- S T + Z ----------------
__global__ __launch_bounds__(256) void k_phaseB(const unsigned short* __restrict__ Ttbf,
    const unsigned short* __restrict__ Zbf, unsigned short* __restrict__ Sbf)
{
    __shared__ unsigned short Sb[2][64][72];
    __shared__ unsigned short Tt[64][72];
    int g = blockIdx.x, tid = threadIdx.x;
    int r = tid >> 2, c0 = (tid & 3) * 16;
    int4 z4 = {0, 0, 0, 0};
    *(int4*)&Sb[0][r][c0] = z4;
    *(int4*)&Sb[0][r][c0 + 8] = z4;
    int cur = 0;
    int wave = tid >> 6, lane = tid & 63;
    int wr = wave >> 1, wc = wave & 1;
    int l15 = lane & 15, l16 = lane >> 4;
    for (int c = 0; c < NCH; ++c) {
        size_t base = ((size_t)g * NCH + c) * 4096;
        __syncthreads();
        *(int4*)(Sbf + base + r * 64 + c0)     = *(int4*)&Sb[cur][r][c0];
        *(int4*)(Sbf + base + r * 64 + c0 + 8) = *(int4*)&Sb[cur][r][c0 + 8];
        *(int4*)&Tt[r][c0]     = *(const int4*)(Ttbf + base + r * 64 + c0);
        *(int4*)&Tt[r][c0 + 8] = *(const int4*)(Ttbf + base + r * 64 + c0 + 8);
        __syncthreads();
        f32x4 acc[2][2] = {};
#pragma unroll
        for (int kk2 = 0; kk2 < 2; ++kk2) {
            bf16x8 af[2], bfv[2];
#pragma unroll
            for (int m = 0; m < 2; ++m) af[m] = *(const bf16x8*)&Sb[cur][wr * 32 + m * 16 + l15][kk2 * 32 + l16 * 8];
#pragma unroll
            for (int n = 0; n < 2; ++n) bfv[n] = *(const bf16x8*)&Tt[wc * 32 + n * 16 + l15][kk2 * 32 + l16 * 8];
#pragma unroll
            for (int m = 0; m < 2; ++m)
#pragma unroll
                for (int n = 0; n < 2; ++n)
                    acc[m][n] = mfma16(af[m], bfv[n], acc[m][n]);
        }
#pragma unroll
        for (int m = 0; m < 2; ++m)
#pragma unroll
            for (int n = 0; n < 2; ++n)
#pragma unroll
                for (int jj = 0; jj < 4; ++jj) {
                    int ro = wr * 32 + m * 16 + l16 * 4 + jj;
                    int co = wc * 32 + n * 16 + l15;
                    float val = acc[m][n][jj] + bf2f(Zbf[base + (size_t)ro * 64 + co]);
                    Sb[cur ^ 1][ro][co] = f2bf(val);
                }
        cur ^= 1;
    }
}

// ---------------- F5: O = E S0^T + F -> obuf ----------------
__global__ __launch_bounds__(256) void k_phaseC(const unsigned short* __restrict__ Ebf,
    const unsigned short* __restrict__ Sbf, const unsigned short* __restrict__ Fbf,
    float* __restrict__ obuf)
{
    __shared__ unsigned short Es[64][72], Ss[64][72];
    int hc = blockIdx.x, tid = threadIdx.x;
    int g = hc >> 4, c = hc & 15;
    int b = g / H_, h = g - (g / H_) * H_;
    size_t rowb = ((size_t)(b * T_ + c * 64)) * C_ + h * 64;
    size_t base = (size_t)hc * 4096;
    int r = tid >> 2, c0 = (tid & 3) * 16;
    *(int4*)&Es[r][c0]     = *(const int4*)(Ebf + base + r * 64 + c0);
    *(int4*)&Es[r][c0 + 8] = *(const int4*)(Ebf + base + r * 64 + c0 + 8);
    *(int4*)&Ss[r][c0]     = *(const int4*)(Sbf + base + r * 64 + c0);
    *(int4*)&Ss[r][c0 + 8] = *(const int4*)(Sbf + base + r * 64 + c0 + 8);
    __syncthreads();
    int wave = tid >> 6, lane = tid & 63;
    int wr = wave >> 1, wc = wave & 1;
    int l15 = lane & 15, l16 = lane >> 4;
    f32x4 acc[2][2] = {};
#pragma unroll
    for (int kk2 = 0; kk2 < 2; ++kk2) {
        bf16x8 af[2], bfv[2];
#pragma unroll
        for (int m = 0; m < 2; ++m) af[m] = *(const bf16x8*)&Es[wr * 32 + m * 16 + l15][kk2 * 32 + l16 * 8];
#pragma unroll
        for (int n = 0; n < 2; ++n) bfv[n] = *(const bf16x8*)&Ss[wc * 32 + n * 16 + l15][kk2 * 32 + l16 * 8];
#pragma unroll
        for (int m = 0; m < 2; ++m)
#pragma unroll
            for (int n = 0; n < 2; ++n)
                acc[m][n] = mfma16(af[m], bfv[n], acc[m][n]);
    }
#pragma unroll
    for (int m = 0; m < 2; ++m)
#pragma unroll
        for (int n = 0; n < 2; ++n)
#pragma unroll
            for (int jj = 0; jj < 4; ++jj) {
                int tt = wr * 32 + m * 16 + l16 * 4 + jj;
                int ii = wc * 32 + n * 16 + l15;
                float val = acc[m][n][jj] + bf2f(Fbf[base + (size_t)tt * 64 + ii]);
                obuf[rowb + (size_t)tt * C_ + ii] = val;
            }
}

// ---------------- kernel 6: groupnorm + bonus + gate -> bf16 ----------------
__global__ __launch_bounds__(256) void k_gnorm(const float* __restrict__ o,
    const float* __restrict__ v, const float* __restrict__ g, const float* __restrict__ dotb,
    const float* __restrict__ gamma, const float* __restrict__ beta,
    unsigned short* __restrict__ yb)
{
    int gw = blockIdx.x * 4 + (threadIdx.x >> 6);
    int lane = threadIdx.x & 63;
    int bt = gw / H_, h = gw - (gw / H_) * H_;
    int c = h * 64 + lane;
    size_t idx = (size_t)bt * C_ + c;
    float ov = o[idx];
    float mean = red64(ov) * 0.015625f;
    float d = ov - mean;
    float var = red64(d * d) * 0.015625f;
    float yn = d * rsqrtf(var + EPS_GN) * gamma[c] + beta[c];
    float dot = dotb[bt * H_ + h];
    float y = (yn + dot * v[idx]) * g[idx];
    yb[idx] = f2bf(y);
}

// ---------------- host ----------------
extern "C" void kernel_launch(void* const* d_in, const int* in_sizes, int n_in,
                              void* d_out, int out_size, void* d_ws, size_t ws_size,
                              hipStream_t stream)
{
    (void)in_sizes; (void)n_in; (void)out_size; (void)ws_size;
    const float* x   = (const float*)d_in[0];
    const float* mr  = (const float*)d_in[1];
    const float* mw  = (const float*)d_in[2];
    const float* mk  = (const float*)d_in[3];
    const float* mv  = (const float*)d_in[4];
    const float* ma  = (const float*)d_in[5];
    const float* mg  = (const float*)d_in[6];
    const float* w0  = (const float*)d_in[7];
    const float* w1  = (const float*)d_in[8];
    const float* w2  = (const float*)d_in[9];
    const float* a0  = (const float*)d_in[10];
    const float* a1  = (const float*)d_in[11];
    const float* a2  = (const float*)d_in[12];
    const float* g1  = (const float*)d_in[13];
    const float* g2  = (const float*)d_in[14];
    const float* k_k = (const float*)d_in[15];
    const float* k_a = (const float*)d_in[16];
    const float* r_k = (const float*)d_in[17];
    const float* Wr  = (const float*)d_in[18];
    const float* Wk  = (const float*)d_in[19];
    const float* Wv  = (const float*)d_in[20];
    const float* Wo  = (const float*)d_in[21];
    const float* gam = (const float*)d_in[22];
    const float* bet = (const float*)d_in[23];

    char* ws = (char*)d_ws;
    constexpr size_t SZF = BTC * 4;
    constexpr size_t SZH = BTC * 2;
    unsigned short* X6  = (unsigned short*)ws;
    unsigned short* Abf = (unsigned short*)(ws + 0 * SZH);
    unsigned short* Bbf = (unsigned short*)(ws + 1 * SZH);
    unsigned short* Kbf = (unsigned short*)(ws + 2 * SZH);
    unsigned short* Rbf = (unsigned short*)(ws + 3 * SZH);
    unsigned short* Ttbf = Abf;                       // over A (read fully before write in k_chunk)
    unsigned short* Zbf  = (unsigned short*)(ws + 4 * SZH);
    float*          obuf = (float*)(ws + 1 * SZH);    // over B,K (dead after k_chunk)
    unsigned short* ybf  = (unsigned short*)(ws + 3 * SZH);

    size_t off = 6 * SZH;
    unsigned short* WrT = (unsigned short*)(ws + off); off += (size_t)768 * 768 * 2;
    unsigned short* WkT = (unsigned short*)(ws + off); off += (size_t)768 * 768 * 2;
    unsigned short* WvT = (unsigned short*)(ws + off); off += (size_t)768 * 768 * 2;
    unsigned short* WoT = (unsigned short*)(ws + off); off += (size_t)768 * 768 * 2;
    unsigned short* w1T = (unsigned short*)(ws + off); off += (size_t)64 * 768 * 2;
    unsigned short* w2T = (unsigned short*)(ws + off); off += (size_t)64 * 768 * 2;
    unsigned short* a1T = (unsigned short*)(ws + off); off += (size_t)64 * 768 * 2;
    unsigned short* a2T = (unsigned short*)(ws + off); off += (size_t)64 * 768 * 2;
    unsigned short* g1T = (unsigned short*)(ws + off); off += (size_t)128 * 768 * 2;
    unsigned short* g2T = (unsigned short*)(ws + off); off += (size_t)128 * 768 * 2;
    float* rbuf  = (float*)(ws + off); off += SZF;
    float* kbuf  = (float*)(ws + off); off += SZF;
    float* vbuf  = (float*)(ws + off); off += SZF;
    float* wdec  = (float*)(ws + off); off += SZF;
    float* abuf  = (float*)(ws + off); off += SZF;
    float* kkbuf = (float*)(ws + off); off += SZF;
    float* gbuf  = (float*)(ws + off); off += SZF;
    unsigned short* hw = (unsigned short*)(ws + off); off += (size_t)4096 * 64 * 2;
    unsigned short* ha = (unsigned short*)(ws + off); off += (size_t)4096 * 64 * 2;
    unsigned short* hg = (unsigned short*)(ws + off); off += (size_t)4096 * 128 * 2;
    unsigned short* Ebf = (unsigned short*)abuf;                   // k_chunk out (abuf dead post-scanprep)
    unsigned short* Sbf = (unsigned short*)((char*)abuf + SZH);    // phaseB out
    unsigned short* Fbf = (unsigned short*)((char*)kkbuf + SZH);   // k_chunk out (kkbuf dead post-scanprep)
    float* cwL  = (float*)hw;
    float* dotb = (float*)ha;

    k_prep<<<3072, 256, 0, stream>>>(x, mr, mw, mk, mv, ma, mg, X6);
    k_transpose_all<<<2688, 256, 0, stream>>>(Wr, Wk, Wv, Wo, w1, w2, a1, a2, g1, g2,
                                              WrT, WkT, WvT, WoT, w1T, w2T, a1T, a2T, g1T, g2T);
    // low-rank chains
    k_gemm<2><<<dim3(1, 64), 256, 0, stream>>>(X6 + 1 * BTC, w1T, hw, nullptr, 4096, 64, 768);
    k_gemm128<3><<<dim3(6, 32), 256, 0, stream>>>(hw, w2T, wdec, w0, 4096, 768, 64);
    k_gemm<1><<<dim3(1, 64), 256, 0, stream>>>(X6 + 4 * BTC, a1T, ha, nullptr, 4096, 64, 768);
    k_gemm128<4><<<dim3(6, 32), 256, 0, stream>>>(ha, a2T, abuf, a0, 4096, 768, 64);
    k_gemm<5><<<dim3(2, 64), 256, 0, stream>>>(X6 + 5 * BTC, g1T, hg, nullptr, 4096, 128, 768);
    k_gemm128<0><<<dim3(6, 32), 256, 0, stream>>>(hg, g2T, gbuf, nullptr, 4096, 768, 128);
    // r,k,v projections
    k_gemm128<0><<<dim3(6, 32), 256, 0, stream>>>(X6 + 0 * BTC, WrT, rbuf, nullptr, 4096, 768, 768);
    k_gemm128<0><<<dim3(6, 32), 256, 0, stream>>>(X6 + 2 * BTC, WkT, kbuf, nullptr, 4096, 768, 768);
    k_gemm128<0><<<dim3(6, 32), 256, 0, stream>>>(X6 + 3 * BTC, WvT, vbuf, nullptr, 4096, 768, 768);
    k_kproc<<<12288, 256, 0, stream>>>(kbuf, abuf, rbuf, k_k, k_a, r_k, kkbuf, dotb);
    // chunked generalized delta rule
    k_scanprep<<<HC_, 256, 0, stream>>>(wdec, kkbuf, abuf, kbuf, rbuf, Abf, Bbf, Kbf, Rbf, cwL);
    k_chunk<<<HC_, 256, 0, stream>>>(Abf, Bbf, Kbf, Rbf, vbuf, cwL, Ttbf, Zbf, Ebf, Fbf);
    k_phaseB<<<48, 256, 0, stream>>>(Ttbf, Zbf, Sbf);
    k_phaseC<<<HC_, 256, 0, stream>>>(Ebf, Sbf, Fbf, obuf);
    k_gnorm<<<12288, 256, 0, stream>>>(obuf, vbuf, gbuf, dotb, gam, bet, ybf);
    k_gemm128<0><<<dim3(6, 32), 256, 0, stream>>>(ybf, WoT, (float*)d_out, nullptr, 4096, 768, 768);
}

// Round 9
// 341.683 us; speedup vs baseline: 4.8133x; 1.2262x over previous
//
#include <hip/hip_runtime.h>
#include <math.h>

// ---------------- constants ----------------
constexpr int B_ = 4, T_ = 1024, C_ = 768, H_ = 12, N_ = 64;
constexpr int BT_ = B_ * T_;                    // 4096
constexpr size_t BTC = (size_t)BT_ * C_;        // 3145728
constexpr float EPS_GN = 0.00064f;
constexpr int NCH = 16;                         // chunks per sequence (1024/64)
constexpr int HC_ = 48 * NCH;                   // 768 head-chunks

typedef __attribute__((ext_vector_type(8))) short bf16x8;
typedef __attribute__((ext_vector_type(4))) float f32x4;
typedef __attribute__((ext_vector_type(4))) unsigned short u16x4;
typedef __attribute__((ext_vector_type(8))) unsigned short u16x8;

#define DEVFN static __device__ __forceinline__

DEVFN unsigned short f2bf(float f) {
    unsigned u = __float_as_uint(f);
    unsigned r = u + 0x7FFFu + ((u >> 16) & 1u);
    return (unsigned short)(r >> 16);
}
DEVFN float bf2f(unsigned short u) { return __uint_as_float(((unsigned)u) << 16); }

template<int CTRL>
DEVFN float dppadd(float x) {
    return x + __int_as_float(__builtin_amdgcn_update_dpp(0, __float_as_int(x), CTRL, 0xF, 0xF, true));
}
#define SWZ_ADD(x, imm) ((x) + __int_as_float(__builtin_amdgcn_ds_swizzle(__float_as_int(x), (imm))))

DEVFN float red64(float x) {
    x = dppadd<0xB1>(x);
    x = dppadd<0x4E>(x);
    x = SWZ_ADD(x, 0x101F);
    x = SWZ_ADD(x, 0x201F);
    x = SWZ_ADD(x, 0x401F);
    x += __shfl_xor(x, 32, 64);
    return x;
}

DEVFN f32x4 mfma16(bf16x8 a, bf16x8 b, f32x4 c) {
    return __builtin_amdgcn_mfma_f32_16x16x32_bf16(a, b, c, 0, 0, 0);
}

typedef const __attribute__((address_space(1))) unsigned int* gas_t;
typedef __attribute__((address_space(3))) unsigned int* las_t;
DEVFN void gload16(const void* g, void* l) {
    __builtin_amdgcn_global_load_lds((gas_t)g, (las_t)l, 16, 0, 0);
}

// half-band GEMM piece: wave (band,half) computes out rows [band*16,+16),
// cols [half*32,+32). out[ro][co] = sum_k A[ro][k]*Bt[co][k]. 4 MFMA.
DEVFN void gemm16h(const unsigned short (*A)[72], const unsigned short (*Bt)[72],
                   f32x4 acc[2], int band, int half, int lane) {
    int l15 = lane & 15, l16 = lane >> 4;
#pragma unroll
    for (int kk2 = 0; kk2 < 2; ++kk2) {
        bf16x8 af = *(const bf16x8*)&A[band * 16 + l15][kk2 * 32 + l16 * 8];
#pragma unroll
        for (int n = 0; n < 2; ++n) {
            bf16x8 bfv = *(const bf16x8*)&Bt[(half * 2 + n) * 16 + l15][kk2 * 32 + l16 * 8];
            acc[n] = mfma16(af, bfv, acc[n]);
        }
    }
}

// ---------------- kernel 1: timeshift + 6 mixes -> bf16 ----------------
__global__ __launch_bounds__(256) void k_prep(const float* __restrict__ x,
    const float* __restrict__ m0, const float* __restrict__ m1, const float* __restrict__ m2,
    const float* __restrict__ m3, const float* __restrict__ m4, const float* __restrict__ m5,
    unsigned short* __restrict__ X6)
{
    int gid = blockIdx.x * 256 + threadIdx.x;
    int i4 = gid * 4;
    int bt = i4 / C_;
    int c  = i4 - bt * C_;
    const float4 xv = *(const float4*)(x + (size_t)bt * C_ + c);
    float px = 0.f, py = 0.f, pz = 0.f, pw = 0.f;
    if ((bt % T_) != 0) {
        const float4 p = *(const float4*)(x + (size_t)(bt - 1) * C_ + c);
        px = p.x; py = p.y; pz = p.z; pw = p.w;
    }
    float d0 = px - xv.x, d1 = py - xv.y, d2 = pz - xv.z, d3 = pw - xv.w;
    const float* mixes[6] = {m0, m1, m2, m3, m4, m5};
#pragma unroll
    for (int m = 0; m < 6; ++m) {
        const float4 mv = *(const float4*)(mixes[m] + c);
        u16x4 pk;
        pk[0] = f2bf(fmaf(d0, mv.x, xv.x));
        pk[1] = f2bf(fmaf(d1, mv.y, xv.y));
        pk[2] = f2bf(fmaf(d2, mv.z, xv.z));
        pk[3] = f2bf(fmaf(d3, mv.w, xv.w));
        *(u16x4*)(X6 + (size_t)m * BTC + (size_t)bt * C_ + c) = pk;
    }
}

// ---------------- kernel 2: ALL weight transposes in one dispatch ----------------
__global__ __launch_bounds__(256) void k_transpose_all(
    const float* __restrict__ s0, const float* __restrict__ s1, const float* __restrict__ s2,
    const float* __restrict__ s3, const float* __restrict__ s4, const float* __restrict__ s5,
    const float* __restrict__ s6, const float* __restrict__ s7, const float* __restrict__ s8,
    const float* __restrict__ s9,
    unsigned short* __restrict__ d0, unsigned short* __restrict__ d1, unsigned short* __restrict__ d2,
    unsigned short* __restrict__ d3, unsigned short* __restrict__ d4, unsigned short* __restrict__ d5,
    unsigned short* __restrict__ d6, unsigned short* __restrict__ d7, unsigned short* __restrict__ d8,
    unsigned short* __restrict__ d9)
{
    __shared__ float tile[32][33];
    int bid = blockIdx.x;
    const float* W; unsigned short* WT; int R, Cc, loc;
    if (bid < 2304) {
        int w = bid / 576; loc = bid - w * 576;
        W = (w == 0) ? s0 : (w == 1) ? s1 : (w == 2) ? s2 : s3;
        WT = (w == 0) ? d0 : (w == 1) ? d1 : (w == 2) ? d2 : d3;
        R = 768; Cc = 768;
    } else if (bid < 2496) {
        int w = (bid - 2304) / 48; loc = (bid - 2304) % 48;
        W = (w == 0) ? s4 : (w == 1) ? s5 : (w == 2) ? s6 : s7;
        WT = (w == 0) ? d4 : (w == 1) ? d5 : (w == 2) ? d6 : d7;
        R = (w & 1) ? 64 : 768; Cc = (w & 1) ? 768 : 64;
    } else {
        int w = (bid - 2496) / 96; loc = (bid - 2496) % 96;
        W = (w == 0) ? s8 : s9;
        WT = (w == 0) ? d8 : d9;
        R = (w == 0) ? 768 : 128; Cc = (w == 0) ? 128 : 768;
    }
    int bx = Cc / 32;
    int bxi = loc % bx, byi = loc / bx;
    int tx = threadIdx.x & 31, ty = threadIdx.x >> 5;
#pragma unroll
    for (int j = 0; j < 4; ++j) {
        int rr = byi * 32 + ty + j * 8;
        int cc = bxi * 32 + tx;
        tile[ty + j * 8][tx] = W[(size_t)rr * Cc + cc];
    }
    __syncthreads();
#pragma unroll
    for (int j = 0; j < 4; ++j) {
        int ro = bxi * 32 + ty + j * 8;
        int co = byi * 32 + tx;
        WT[(size_t)ro * R + co] = f2bf(tile[tx][ty + j * 8]);
    }
}

// ---------------- kernel 3a: 64-tile bf16 GEMM (small N) ----------------
template<int EPI>
__global__ __launch_bounds__(256) void k_gemm(const unsigned short* __restrict__ A,
    const unsigned short* __restrict__ Bt, void* __restrict__ Cp,
    const float* __restrict__ bias, int M, int Nn, int K)
{
    __shared__ unsigned short As[64][40];
    __shared__ unsigned short Bs[64][40];
    const int t = threadIdx.x, lane = t & 63, wave = t >> 6;
    const int wr = wave >> 1, wc = wave & 1;
    const int bM = blockIdx.y * 64, bN = blockIdx.x * 64;
    const int srow = t >> 2, skc = (t & 3) * 8;
    const int l15 = lane & 15, l16 = lane >> 4;
    f32x4 acc[2][2] = {};

    for (int k0 = 0; k0 < K; k0 += 32) {
        __syncthreads();
        *(int4*)&As[srow][skc] = *(const int4*)(A + (size_t)(bM + srow) * K + k0 + skc);
        *(int4*)&Bs[srow][skc] = *(const int4*)(Bt + (size_t)(bN + srow) * K + k0 + skc);
        __syncthreads();
        bf16x8 af0 = *(const bf16x8*)&As[wr * 32 + l15][l16 * 8];
        bf16x8 af1 = *(const bf16x8*)&As[wr * 32 + 16 + l15][l16 * 8];
        bf16x8 bf0 = *(const bf16x8*)&Bs[wc * 32 + l15][l16 * 8];
        bf16x8 bf1 = *(const bf16x8*)&Bs[wc * 32 + 16 + l15][l16 * 8];
        acc[0][0] = mfma16(af0, bf0, acc[0][0]);
        acc[0][1] = mfma16(af0, bf1, acc[0][1]);
        acc[1][0] = mfma16(af1, bf0, acc[1][0]);
        acc[1][1] = mfma16(af1, bf1, acc[1][1]);
    }

#pragma unroll
    for (int fm = 0; fm < 2; ++fm)
#pragma unroll
        for (int fn = 0; fn < 2; ++fn)
#pragma unroll
            for (int jj = 0; jj < 4; ++jj) {
                int gr = bM + wr * 32 + fm * 16 + l16 * 4 + jj;
                int gc = bN + wc * 32 + fn * 16 + l15;
                float val = acc[fm][fn][jj];
                size_t oi = (size_t)gr * Nn + gc;
                if constexpr (EPI == 1) {
                    ((unsigned short*)Cp)[oi] = f2bf(val);
                } else if constexpr (EPI == 2) {
                    ((unsigned short*)Cp)[oi] = f2bf(tanhf(val));
                } else {
                    ((unsigned short*)Cp)[oi] = f2bf(1.f / (1.f + expf(-val)));
                }
            }
}

// ---------------- kernel 3b: 128x128-tile GEMM with global_load_lds ----------------
template<int EPI>
__global__ __launch_bounds__(256) void k_gemm128(const unsigned short* __restrict__ A,
    const unsigned short* __restrict__ Bt, void* __restrict__ Cp,
    const float* __restrict__ bias, int M, int Nn, int K)
{
    __shared__ unsigned short As[128][32];
    __shared__ unsigned short Bs[128][32];
    const int tid = threadIdx.x, lane = tid & 63, wave = tid >> 6;
    const int wr = wave >> 1, wc = wave & 1;
    const int bM = blockIdx.y * 128, bN = blockIdx.x * 128;
    const int l15 = lane & 15, l16 = lane >> 4;
    const int srow = lane >> 2, scol = (lane & 3) * 8;
    f32x4 acc[4][4] = {};

    for (int k0 = 0; k0 < K; k0 += 32) {
        __syncthreads();
#pragma unroll
        for (int i = 0; i < 2; ++i) {
            int ch = i * 4 + wave;
            int row = ch * 16 + srow;
            gload16(A  + (size_t)(bM + row) * K + k0 + scol, &As[0][0] + ch * 512 + lane * 8);
            gload16(Bt + (size_t)(bN + row) * K + k0 + scol, &Bs[0][0] + ch * 512 + lane * 8);
        }
        __syncthreads();
        bf16x8 af[4], bfv[4];
#pragma unroll
        for (int m = 0; m < 4; ++m) af[m]  = *(const bf16x8*)&As[wr * 64 + m * 16 + l15][l16 * 8];
#pragma unroll
        for (int n = 0; n < 4; ++n) bfv[n] = *(const bf16x8*)&Bs[wc * 64 + n * 16 + l15][l16 * 8];
#pragma unroll
        for (int m = 0; m < 4; ++m)
#pragma unroll
            for (int n = 0; n < 4; ++n)
                acc[m][n] = mfma16(af[m], bfv[n], acc[m][n]);
    }

#pragma unroll
    for (int m = 0; m < 4; ++m)
#pragma unroll
        for (int n = 0; n < 4; ++n)
#pragma unroll
            for (int jj = 0; jj < 4; ++jj) {
                int gr = bM + wr * 64 + m * 16 + l16 * 4 + jj;
                int gc = bN + wc * 64 + n * 16 + l15;
                float val = acc[m][n][jj];
                size_t oi = (size_t)gr * Nn + gc;
                if constexpr (EPI == 0) {
                    ((float*)Cp)[oi] = val;
                } else if constexpr (EPI == 3) {
                    float z = bias[gc] + val;
                    float sg = 1.f / (1.f + expf(-z));
                    ((float*)Cp)[oi] = expf(-0.60653065971f * sg);
                } else {
                    float z = bias[gc] + val;
                    ((float*)Cp)[oi] = 1.f / (1.f + expf(-z));
                }
            }
}

// ---------------- kernel 3c: batched EPI-0 gemm128 ----------------
struct GemmSet {
    const unsigned short* A[4];
    const unsigned short* Bt[4];
    float* C[4];
    int K[4];
};
__global__ __launch_bounds__(256) void k_gemm128b(GemmSet S)
{
    __shared__ unsigned short As[128][32];
    __shared__ unsigned short Bs[128][32];
    const int z = blockIdx.z;
    const unsigned short* A = S.A[z];
    const unsigned short* Bt = S.Bt[z];
    float* Cp = S.C[z];
    const int K = S.K[z];
    const int tid = threadIdx.x, lane = tid & 63, wave = tid >> 6;
    const int wr = wave >> 1, wc = wave & 1;
    const int bM = blockIdx.y * 128, bN = blockIdx.x * 128;
    const int l15 = lane & 15, l16 = lane >> 4;
    const int srow = lane >> 2, scol = (lane & 3) * 8;
    f32x4 acc[4][4] = {};

    for (int k0 = 0; k0 < K; k0 += 32) {
        __syncthreads();
#pragma unroll
        for (int i = 0; i < 2; ++i) {
            int ch = i * 4 + wave;
            int row = ch * 16 + srow;
            gload16(A  + (size_t)(bM + row) * K + k0 + scol, &As[0][0] + ch * 512 + lane * 8);
            gload16(Bt + (size_t)(bN + row) * K + k0 + scol, &Bs[0][0] + ch * 512 + lane * 8);
        }
        __syncthreads();
        bf16x8 af[4], bfv[4];
#pragma unroll
        for (int m = 0; m < 4; ++m) af[m]  = *(const bf16x8*)&As[wr * 64 + m * 16 + l15][l16 * 8];
#pragma unroll
        for (int n = 0; n < 4; ++n) bfv[n] = *(const bf16x8*)&Bs[wc * 64 + n * 16 + l15][l16 * 8];
#pragma unroll
        for (int m = 0; m < 4; ++m)
#pragma unroll
            for (int n = 0; n < 4; ++n)
                acc[m][n] = mfma16(af[m], bfv[n], acc[m][n]);
    }
#pragma unroll
    for (int m = 0; m < 4; ++m)
#pragma unroll
        for (int n = 0; n < 4; ++n)
#pragma unroll
            for (int jj = 0; jj < 4; ++jj) {
                int gr = bM + wr * 64 + m * 16 + l16 * 4 + jj;
                int gc = bN + wc * 64 + n * 16 + l15;
                Cp[(size_t)gr * 768 + gc] = acc[m][n][jj];
            }
}

// batched {wdec(z=0), abuf(z=1)}
__global__ __launch_bounds__(256) void k_gemm128wa(const unsigned short* __restrict__ Ahw,
    const unsigned short* __restrict__ Aha, const unsigned short* __restrict__ BtW,
    const unsigned short* __restrict__ BtA, float* __restrict__ Cw, float* __restrict__ Ca,
    const float* __restrict__ bw, const float* __restrict__ ba)
{
    __shared__ unsigned short As[128][32];
    __shared__ unsigned short Bs[128][32];
    const int z = blockIdx.z;
    const unsigned short* A = z ? Aha : Ahw;
    const unsigned short* Bt = z ? BtA : BtW;
    float* Cp = z ? Ca : Cw;
    const float* bias = z ? ba : bw;
    const int K = 64;
    const int tid = threadIdx.x, lane = tid & 63, wave = tid >> 6;
    const int wr = wave >> 1, wc = wave & 1;
    const int bM = blockIdx.y * 128, bN = blockIdx.x * 128;
    const int l15 = lane & 15, l16 = lane >> 4;
    const int srow = lane >> 2, scol = (lane & 3) * 8;
    f32x4 acc[4][4] = {};

    for (int k0 = 0; k0 < K; k0 += 32) {
        __syncthreads();
#pragma unroll
        for (int i = 0; i < 2; ++i) {
            int ch = i * 4 + wave;
            int row = ch * 16 + srow;
            gload16(A  + (size_t)(bM + row) * K + k0 + scol, &As[0][0] + ch * 512 + lane * 8);
            gload16(Bt + (size_t)(bN + row) * K + k0 + scol, &Bs[0][0] + ch * 512 + lane * 8);
        }
        __syncthreads();
        bf16x8 af[4], bfv[4];
#pragma unroll
        for (int m = 0; m < 4; ++m) af[m]  = *(const bf16x8*)&As[wr * 64 + m * 16 + l15][l16 * 8];
#pragma unroll
        for (int n = 0; n < 4; ++n) bfv[n] = *(const bf16x8*)&Bs[wc * 64 + n * 16 + l15][l16 * 8];
#pragma unroll
        for (int m = 0; m < 4; ++m)
#pragma unroll
            for (int n = 0; n < 4; ++n)
                acc[m][n] = mfma16(af[m], bfv[n], acc[m][n]);
    }
#pragma unroll
    for (int m = 0; m < 4; ++m)
#pragma unroll
        for (int n = 0; n < 4; ++n)
#pragma unroll
            for (int jj = 0; jj < 4; ++jj) {
                int gr = bM + wr * 64 + m * 16 + l16 * 4 + jj;
                int gc = bN + wc * 64 + n * 16 + l15;
                float zv = bias[gc] + acc[m][n][jj];
                float sg = 1.f / (1.f + expf(-zv));
                Cp[(size_t)gr * 768 + gc] = z ? sg : expf(-0.60653065971f * sg);
            }
}

// ---------------- kernel 4: kk normalize + k update + bonus dot ----------------
__global__ __launch_bounds__(256) void k_kproc(float* __restrict__ k, const float* __restrict__ a,
    const float* __restrict__ r, const float* __restrict__ k_k, const float* __restrict__ k_a,
    const float* __restrict__ r_k, float* __restrict__ kk, float* __restrict__ dotb)
{
    int gw = blockIdx.x * 4 + (threadIdx.x >> 6);
    int lane = threadIdx.x & 63;
    int bt = gw / H_, h = gw - (gw / H_) * H_;
    int c = h * 64 + lane;
    size_t idx = (size_t)bt * C_ + c;
    float kv = k[idx], av = a[idx], rv = r[idx];
    float kkv = kv * k_k[c];
    float ss = red64(kkv * kkv);
    float inv = 1.f / fmaxf(sqrtf(ss), 1e-12f);
    kk[idx] = kkv * inv;
    float knew = kv * (1.f + (av - 1.f) * k_a[c]);
    k[idx] = knew;
    float dot = red64(rv * knew * r_k[c]);
    if (lane == 0) dotb[bt * H_ + h] = dot;
}

// ---------------- F1a: cumprod + transforms ----------------
__global__ __launch_bounds__(256) void k_scanprep(const float* __restrict__ wdec,
    const float* __restrict__ kk, const float* __restrict__ asig, const float* __restrict__ kupd,
    const float* __restrict__ r, unsigned short* __restrict__ Abf, unsigned short* __restrict__ Bbf,
    unsigned short* __restrict__ Kbf, unsigned short* __restrict__ Rbf, float* __restrict__ cwL)
{
    __shared__ float CW[64][68];
    int hc = blockIdx.x;
    int g = hc >> 4, c = hc & 15;
    int b = g / H_, h = g - (g / H_) * H_;
    size_t rowb = ((size_t)(b * T_ + c * 64)) * C_ + h * 64;
    int tid = threadIdx.x;
    int t = tid >> 2, j0 = (tid & 3) * 16;
#pragma unroll
    for (int e = 0; e < 16; e += 4)
        *(float4*)&CW[t][j0 + e] = *(const float4*)(wdec + rowb + (size_t)t * C_ + j0 + e);
    __syncthreads();
    if (tid < 64) {
        float cp = 1.f;
#pragma unroll 4
        for (int tt = 0; tt < 64; ++tt) { cp *= CW[tt][tid]; CW[tt][tid] = cp; }
        cwL[hc * 64 + tid] = CW[63][tid];
    }
    __syncthreads();

    size_t base = (size_t)hc * 4096 + t * 64 + j0;
    size_t gin = rowb + (size_t)t * C_ + j0;
    float cwt[16], cwm[16], invc[16];
#pragma unroll
    for (int q = 0; q < 4; ++q) *(float4*)&cwt[q * 4] = *(const float4*)&CW[t][j0 + q * 4];
    if (t) {
#pragma unroll
        for (int q = 0; q < 4; ++q) *(float4*)&cwm[q * 4] = *(const float4*)&CW[t - 1][j0 + q * 4];
    } else {
#pragma unroll
        for (int e = 0; e < 16; ++e) cwm[e] = 1.f;
    }
#pragma unroll
    for (int e = 0; e < 16; ++e) invc[e] = 1.f / cwt[e];

    float kkv[16], tmp[16];
#pragma unroll
    for (int q = 0; q < 4; ++q) *(float4*)&kkv[q * 4] = *(const float4*)(kk + gin + q * 4);
    {
        u16x8 o0, o1;
#pragma unroll
        for (int e = 0; e < 8; ++e) { o0[e] = f2bf(-kkv[e] * cwm[e]); o1[e] = f2bf(-kkv[8 + e] * cwm[8 + e]); }
        *(u16x8*)(Abf + base) = o0; *(u16x8*)(Abf + base + 8) = o1;
    }
#pragma unroll
    for (int q = 0; q < 4; ++q) *(float4*)&tmp[q * 4] = *(const float4*)(asig + gin + q * 4);
    {
        u16x8 o0, o1;
#pragma unroll
        for (int e = 0; e < 8; ++e) { o0[e] = f2bf(kkv[e] * tmp[e] * invc[e]); o1[e] = f2bf(kkv[8 + e] * tmp[8 + e] * invc[8 + e]); }
        *(u16x8*)(Bbf + base) = o0; *(u16x8*)(Bbf + base + 8) = o1;
    }
#pragma unroll
    for (int q = 0; q < 4; ++q) *(float4*)&tmp[q * 4] = *(const float4*)(kupd + gin + q * 4);
    {
        u16x8 o0, o1;
#pragma unroll
        for (int e = 0; e < 8; ++e) { o0[e] = f2bf(tmp[e] * invc[e]); o1[e] = f2bf(tmp[8 + e] * invc[8 + e]); }
        *(u16x8*)(Kbf + base) = o0; *(u16x8*)(Kbf + base + 8) = o1;
    }
#pragma unroll
    for (int q = 0; q < 4; ++q) *(float4*)&tmp[q * 4] = *(const float4*)(r + gin + q * 4);
    {
        u16x8 o0, o1;
#pragma unroll
        for (int e = 0; e < 8; ++e) { o0[e] = f2bf(tmp[e] * cwt[e]); o1[e] = f2bf(tmp[8 + e] * cwt[8 + e]); }
        *(u16x8*)(Rbf + base) = o0; *(u16x8*)(Rbf + base + 8) = o1;
    }
}

// ---------------- k_chunk v2: fused gram+solve+combine, 8 waves ----------------
__global__ __launch_bounds__(512) void k_chunk(const unsigned short* __restrict__ Abf,
    const unsigned short* __restrict__ Bbf, const unsigned short* __restrict__ Kbf,
    const unsigned short* __restrict__ Rbf, const float* __restrict__ vbuf,
    const float* __restrict__ cwL,
    unsigned short* __restrict__ Ttbf, unsigned short* __restrict__ Zbf,
    unsigned short* __restrict__ Ebf, unsigned short* __restrict__ Fbf)
{
    __shared__ unsigned short L[11][64][72];
    int hc = blockIdx.x, tid = threadIdx.x;
    int g = hc >> 4, c = hc & 15;
    int b = g / H_, h = g - (g / H_) * H_;
    size_t rowb = ((size_t)(b * T_ + c * 64)) * C_ + h * 64;
    size_t base = (size_t)hc * 4096;
    int r8 = tid >> 3, c8 = (tid & 7) * 8;
    int rl = tid & 63, cl8 = (tid >> 6) * 8;
    int wave = tid >> 6, lane = tid & 63;
    int band = wave >> 1, half = wave & 1;
    int l15 = lane & 15, l16 = lane >> 4;

    *(u16x8*)&L[2][r8][c8] = *(const u16x8*)(Abf + base + r8 * 64 + c8);
    *(u16x8*)&L[3][r8][c8] = *(const u16x8*)(Bbf + base + r8 * 64 + c8);
    *(u16x8*)&L[4][r8][c8] = *(const u16x8*)(Kbf + base + r8 * 64 + c8);
    *(u16x8*)&L[5][r8][c8] = *(const u16x8*)(Rbf + base + r8 * 64 + c8);
#pragma unroll
    for (int q = 0; q < 2; ++q) {
        float4 v4 = *(const float4*)(vbuf + rowb + (size_t)rl * C_ + cl8 + q * 4);
        L[6][cl8 + q * 4 + 0][rl] = f2bf(v4.x);
        L[6][cl8 + q * 4 + 1][rl] = f2bf(v4.y);
        L[6][cl8 + q * 4 + 2][rl] = f2bf(v4.z);
        L[6][cl8 + q * 4 + 3][rl] = f2bf(v4.w);
    }
    __syncthreads();

    // phase A: grams
    {
        f32x4 ga[2] = {};
        gemm16h(L[2], L[3], ga, band, half, lane);
#pragma unroll
        for (int n = 0; n < 2; ++n)
#pragma unroll
            for (int jj = 0; jj < 4; ++jj) {
                int ro = band * 16 + l16 * 4 + jj, co = (half * 2 + n) * 16 + l15;
                unsigned short gb = f2bf((ro > co) ? ga[n][jj] : 0.f);
                L[0][ro][co] = gb;
                L[1][co][ro] = gb;
                L[10][ro][co] = (ro == co) ? (unsigned short)0x3F80 : gb;
            }
    }
    {
        f32x4 ha[2] = {};
        gemm16h(L[2], L[4], ha, band, half, lane);
#pragma unroll
        for (int n = 0; n < 2; ++n)
#pragma unroll
            for (int jj = 0; jj < 4; ++jj) {
                int ro = band * 16 + l16 * 4 + jj, co = (half * 2 + n) * 16 + l15;
                L[7][ro][co] = f2bf((ro > co) ? ha[n][jj] : 0.f);
            }
    }
    {
        f32x4 pa[2] = {};
        gemm16h(L[5], L[3], pa, band, half, lane);
#pragma unroll
        for (int n = 0; n < 2; ++n)
#pragma unroll
            for (int jj = 0; jj < 4; ++jj) {
                int ro = band * 16 + l16 * 4 + jj, co = (half * 2 + n) * 16 + l15;
                L[8][ro][co] = f2bf((ro >= co) ? pa[n][jj] : 0.f);
            }
    }
    {
        f32x4 qa[2] = {};
        gemm16h(L[5], L[4], qa, band, half, lane);
#pragma unroll
        for (int n = 0; n < 2; ++n)
#pragma unroll
            for (int jj = 0; jj < 4; ++jj) {
                int ro = band * 16 + l16 * 4 + jj, co = (half * 2 + n) * 16 + l15;
                L[9][ro][co] = f2bf((ro >= co) ? qa[n][jj] : 0.f);
            }
    }
    __syncthreads();

    // HV + transpose reads
    f32x4 hv[2] = {};
    gemm16h(L[7], L[6], hv, band, half, lane);
    u16x8 ta = *(const u16x8*)&L[2][rl][cl8];
    u16x8 tb = *(const u16x8*)&L[3][rl][cl8];
    u16x8 tk = *(const u16x8*)&L[4][rl][cl8];
    __syncthreads();
#pragma unroll
    for (int e = 0; e < 8; ++e) {
        L[2][cl8 + e][rl] = ta[e];
        L[3][cl8 + e][rl] = tb[e];
        L[4][cl8 + e][rl] = tk[e];
    }
#pragma unroll
    for (int n = 0; n < 2; ++n)
#pragma unroll
        for (int jj = 0; jj < 4; ++jj) {
            int ro = band * 16 + l16 * 4 + jj, co = (half * 2 + n) * 16 + l15;
            L[7][co][ro] = f2bf(hv[n][jj]);
        }
    f32x4 sacc[2] = {};
    gemm16h(L[0], L[1], sacc, band, half, lane);   // S1 = G^2
    f32x4 pacc[2] = {};

    // solve: in-place squarings, deferred Pm writes
#pragma unroll
    for (int it = 0; it < 5; ++it) {
        __syncthreads();
#pragma unroll
        for (int n = 0; n < 2; ++n)
#pragma unroll
            for (int jj = 0; jj < 4; ++jj) {
                int ro = band * 16 + l16 * 4 + jj, co = (half * 2 + n) * 16 + l15;
                unsigned short sb = f2bf(sacc[n][jj]);
                L[0][ro][co] = sb;
                L[1][co][ro] = sb;
            }
        if (it > 0) {
#pragma unroll
            for (int n = 0; n < 2; ++n)
#pragma unroll
                for (int jj = 0; jj < 4; ++jj) {
                    int ro = band * 16 + l16 * 4 + jj, co = (half * 2 + n) * 16 + l15;
                    L[10][ro][co] = f2bf(pacc[n][jj] + bf2f(L[10][ro][co]));
                }
        }
        __syncthreads();
        pacc[0] = (f32x4){0.f, 0.f, 0.f, 0.f}; pacc[1] = (f32x4){0.f, 0.f, 0.f, 0.f};
        gemm16h(L[10], L[1], pacc, band, half, lane);
        if (it < 4) {
            sacc[0] = (f32x4){0.f, 0.f, 0.f, 0.f}; sacc[1] = (f32x4){0.f, 0.f, 0.f, 0.f};
            gemm16h(L[0], L[1], sacc, band, half, lane);
        }
    }
    __syncthreads();
#pragma unroll
    for (int n = 0; n < 2; ++n)
#pragma unroll
        for (int jj = 0; jj < 4; ++jj) {
            int ro = band * 16 + l16 * 4 + jj, co = (half * 2 + n) * 16 + l15;
            L[10][ro][co] = f2bf(pacc[n][jj] + bf2f(L[10][ro][co]));
        }
    __syncthreads();

    // W = Pm*A, U0 = Pm*(HV); write transposed into L0/L1
    {
        f32x4 wv[2] = {}, uv[2] = {};
        gemm16h(L[10], L[2], wv, band, half, lane);
        gemm16h(L[10], L[7], uv, band, half, lane);
#pragma unroll
        for (int n = 0; n < 2; ++n)
#pragma unroll
            for (int jj = 0; jj < 4; ++jj) {
                int ro = band * 16 + l16 * 4 + jj, co = (half * 2 + n) * 16 + l15;
                L[0][co][ro] = f2bf(wv[n][jj]);
                L[1][co][ro] = f2bf(uv[n][jj]);
            }
    }
    __syncthreads();

    // combine
    {
        f32x4 tacc[2] = {};
        gemm16h(L[0], L[3], tacc, band, half, lane);
        f32x4 zacc[2] = {};
        gemm16h(L[1], L[3], zacc, band, half, lane);
        gemm16h(L[6], L[4], zacc, band, half, lane);
        f32x4 eacc[2] = {};
        gemm16h(L[8], L[0], eacc, band, half, lane);
        f32x4 facc[2] = {};
        gemm16h(L[8], L[1], facc, band, half, lane);
        gemm16h(L[9], L[6], facc, band, half, lane);
#pragma unroll
        for (int n = 0; n < 2; ++n)
#pragma unroll
            for (int jj = 0; jj < 4; ++jj) {
                int ro = band * 16 + l16 * 4 + jj, co = (half * 2 + n) * 16 + l15;
                float cw = cwL[hc * 64 + co];
                Ttbf[base + (size_t)co * 64 + ro] = f2bf((tacc[n][jj] + (ro == co ? 1.f : 0.f)) * cw);
                Zbf[base + (size_t)ro * 64 + co] = f2bf(zacc[n][jj] * cw);
                Ebf[base + (size_t)ro * 64 + co] = f2bf(eacc[n][jj] + bf2f(L[5][ro][co]));
                Fbf[base + (size_t)ro * 64 + co] = f2bf(facc[n][jj]);
            }
    }
}

// ---------------- F4: per-head serial chunk recursion S <- S T + Z ----------------
__global__ __launch_bounds__(256) void k_phaseB(const unsigned short* __restrict__ Ttbf,
    const unsigned short* __restrict__ Zbf, unsigned short* __restrict__ Sbf)
{
    __shared__ unsigned short Sb[2][64][72];
    __shared__ unsigned short Tt[64][72];
    int g = blockIdx.x, tid = threadIdx.x;
    int r = tid >> 2, c0 = (tid & 3) * 16;
    int4 z4 = {0, 0, 0, 0};
    *(int4*)&Sb[0][r][c0] = z4;
    *(int4*)&Sb[0][r][c0 + 8] = z4;
    int cur = 0;
    int wave = tid >> 6, lane = tid & 63;
    int wr = wave >> 1, wc = wave & 1;
    int l15 = lane & 15, l16 = lane >> 4;
    for (int c = 0; c < NCH; ++c) {
        size_t base = ((size_t)g * NCH + c) * 4096;
        __syncthreads();
        *(int4*)(Sbf + base + r * 64 + c0)     = *(int4*)&Sb[cur][r][c0];
        *(int4*)(Sbf + base + r * 64 + c0 + 8) = *(int4*)&Sb[cur][r][c0 + 8];
        *(int4*)&Tt[r][c0]     = *(const int4*)(Ttbf + base + r * 64 + c0);
        *(int4*)&Tt[r][c0 + 8] = *(const int4*)(Ttbf + base + r * 64 + c0 + 8);
        __syncthreads();
        f32x4 acc[2][2] = {};
#pragma unroll
        for (int kk2 = 0; kk2 < 2; ++kk2) {
            bf16x8 af[2], bfv[2];
#pragma unroll
            for (int m = 0; m < 2; ++m) af[m] = *(const bf16x8*)&Sb[cur][wr * 32 + m * 16 + l15][kk2 * 32 + l16 * 8];
#pragma unroll
            for (int n = 0; n < 2; ++n) bfv[n] = *(const bf16x8*)&Tt[wc * 32 + n * 16 + l15][kk2 * 32 + l16 * 8];
#pragma unroll
            for (int m = 0; m < 2; ++m)
#pragma unroll
                for (int n = 0; n < 2; ++n)
                    acc[m][n] = mfma16(af[m], bfv[n], acc[m][n]);
        }
#pragma unroll
        for (int m = 0; m < 2; ++m)
#pragma unroll
            for (int n = 0; n < 2; ++n)
#pragma unroll
                for (int jj = 0; jj < 4; ++jj) {
                    int ro = wr * 32 + m * 16 + l16 * 4 + jj;
                    int co = wc * 32 + n * 16 + l15;
                    float val = acc[m][n][jj] + bf2f(Zbf[base + (size_t)ro * 64 + co]);
                    Sb[cur ^ 1][ro][co] = f2bf(val);
                }
        cur ^= 1;
    }
}

// ---------------- F5: O = E S0^T + F -> obuf ----------------
__global__ __launch_bounds__(256) void k_phaseC(const unsigned short* __restrict__ Ebf,
    const unsigned short* __restrict__ Sbf, const unsigned short* __restrict__ Fbf,
    float* __restrict__ obuf)
{
    __shared__ unsigned short Es[64][72], Ss[64][72];
    int hc = blockIdx.x, tid = threadIdx.x;
    int g = hc >> 4, c = hc & 15;
    int b = g / H_, h = g - (g / H_) * H_;
    size_t rowb = ((size_t)(b * T_ + c * 64)) * C_ + h * 64;
    size_t base = (size_t)hc * 4096;
    int r = tid >> 2, c0 = (tid & 3) * 16;
    *(int4*)&Es[r][c0]     = *(const int4*)(Ebf + base + r * 64 + c0);
    *(int4*)&Es[r][c0 + 8] = *(const int4*)(Ebf + base + r * 64 + c0 + 8);
    *(int4*)&Ss[r][c0]     = *(const int4*)(Sbf + base + r * 64 + c0);
    *(int4*)&Ss[r][c0 + 8] = *(const int4*)(Sbf + base + r * 64 + c0 + 8);
    __syncthreads();
    int wave = tid >> 6, lane = tid & 63;
    int wr = wave >> 1, wc = wave & 1;
    int l15 = lane & 15, l16 = lane >> 4;
    f32x4 acc[2][2] = {};
#pragma unroll
    for (int kk2 = 0; kk2 < 2; ++kk2) {
        bf16x8 af[2], bfv[2];
#pragma unroll
        for (int m = 0; m < 2; ++m) af[m] = *(const bf16x8*)&Es[wr * 32 + m * 16 + l15][kk2 * 32 + l16 * 8];
#pragma unroll
        for (int n = 0; n < 2; ++n) bfv[n] = *(const bf16x8*)&Ss[wc * 32 + n * 16 + l15][kk2 * 32 + l16 * 8];
#pragma unroll
        for (int m = 0; m < 2; ++m)
#pragma unroll
            for (int n = 0; n < 2; ++n)
                acc[m][n] = mfma16(af[m], bfv[n], acc[m][n]);
    }
#pragma unroll
    for (int m = 0; m < 2; ++m)
#pragma unroll
        for (int n = 0; n < 2; ++n)
#pragma unroll
            for (int jj = 0; jj < 4; ++jj) {
                int tt = wr * 32 + m * 16 + l16 * 4 + jj;
                int ii = wc * 32 + n * 16 + l15;
                float val = acc[m][n][jj] + bf2f(Fbf[base + (size_t)tt * 64 + ii]);
                obuf[rowb + (size_t)tt * C_ + ii] = val;
            }
}

// ---------------- kernel 6: groupnorm + bonus + gate -> bf16 ----------------
__global__ __launch_bounds__(256) void k_gnorm(const float* __restrict__ o,
    const float* __restrict__ v, const float* __restrict__ g, const float* __restrict__ dotb,
    const float* __restrict__ gamma, const float* __restrict__ beta,
    unsigned short* __restrict__ yb)
{
    int gw = blockIdx.x * 4 + (threadIdx.x >> 6);
    int lane = threadIdx.x & 63;
    int bt = gw / H_, h = gw - (gw / H_) * H_;
    int c = h * 64 + lane;
    size_t idx = (size_t)bt * C_ + c;
    float ov = o[idx];
    float mean = red64(ov) * 0.015625f;
    float d = ov - mean;
    float var = red64(d * d) * 0.015625f;
    float yn = d * rsqrtf(var + EPS_GN) * gamma[c] + beta[c];
    float dot = dotb[bt * H_ + h];
    float y = (yn + dot * v[idx]) * g[idx];
    yb[idx] = f2bf(y);
}

// ---------------- host ----------------
extern "C" void kernel_launch(void* const* d_in, const int* in_sizes, int n_in,
                              void* d_out, int out_size, void* d_ws, size_t ws_size,
                              hipStream_t stream)
{
    (void)in_sizes; (void)n_in; (void)out_size; (void)ws_size;
    const float* x   = (const float*)d_in[0];
    const float* mr  = (const float*)d_in[1];
    const float* mw  = (const float*)d_in[2];
    const float* mk  = (const float*)d_in[3];
    const float* mv  = (const float*)d_in[4];
    const float* ma  = (const float*)d_in[5];
    const float* mg  = (const float*)d_in[6];
    const float* w0  = (const float*)d_in[7];
    const float* w1  = (const float*)d_in[8];
    const float* w2  = (const float*)d_in[9];
    const float* a0  = (const float*)d_in[10];
    const float* a1  = (const float*)d_in[11];
    const float* a2  = (const float*)d_in[12];
    const float* g1  = (const float*)d_in[13];
    const float* g2  = (const float*)d_in[14];
    const float* k_k = (const float*)d_in[15];
    const float* k_a = (const float*)d_in[16];
    const float* r_k = (const float*)d_in[17];
    const float* Wr  = (const float*)d_in[18];
    const float* Wk  = (const float*)d_in[19];
    const float* Wv  = (const float*)d_in[20];
    const float* Wo  = (const float*)d_in[21];
    const float* gam = (const float*)d_in[22];
    const float* bet = (const float*)d_in[23];

    char* ws = (char*)d_ws;
    constexpr size_t SZF = BTC * 4;
    constexpr size_t SZH = BTC * 2;
    unsigned short* X6  = (unsigned short*)ws;
    unsigned short* Abf = (unsigned short*)(ws + 0 * SZH);
    unsigned short* Bbf = (unsigned short*)(ws + 1 * SZH);
    unsigned short* Kbf = (unsigned short*)(ws + 2 * SZH);
    unsigned short* Rbf = (unsigned short*)(ws + 3 * SZH);
    unsigned short* Ttbf = Abf;
    unsigned short* Zbf  = (unsigned short*)(ws + 4 * SZH);
    float*          obuf = (float*)(ws + 1 * SZH);
    unsigned short* ybf  = (unsigned short*)(ws + 3 * SZH);

    size_t off = 6 * SZH;
    unsigned short* WrT = (unsigned short*)(ws + off); off += (size_t)768 * 768 * 2;
    unsigned short* WkT = (unsigned short*)(ws + off); off += (size_t)768 * 768 * 2;
    unsigned short* WvT = (unsigned short*)(ws + off); off += (size_t)768 * 768 * 2;
    unsigned short* WoT = (unsigned short*)(ws + off); off += (size_t)768 * 768 * 2;
    unsigned short* w1T = (unsigned short*)(ws + off); off += (size_t)64 * 768 * 2;
    unsigned short* w2T = (unsigned short*)(ws + off); off += (size_t)64 * 768 * 2;
    unsigned short* a1T = (unsigned short*)(ws + off); off += (size_t)64 * 768 * 2;
    unsigned short* a2T = (unsigned short*)(ws + off); off += (size_t)64 * 768 * 2;
    unsigned short* g1T = (unsigned short*)(ws + off); off += (size_t)128 * 768 * 2;
    unsigned short* g2T = (unsigned short*)(ws + off); off += (size_t)128 * 768 * 2;
    float* rbuf  = (float*)(ws + off); off += SZF;
    float* kbuf  = (float*)(ws + off); off += SZF;
    float* vbuf  = (float*)(ws + off); off += SZF;
    float* wdec  = (float*)(ws + off); off += SZF;
    float* abuf  = (float*)(ws + off); off += SZF;
    float* kkbuf = (float*)(ws + off); off += SZF;
    float* gbuf  = (float*)(ws + off); off += SZF;
    unsigned short* hw = (unsigned short*)(ws + off); off += (size_t)4096 * 64 * 2;
    unsigned short* ha = (unsigned short*)(ws + off); off += (size_t)4096 * 64 * 2;
    unsigned short* hg = (unsigned short*)(ws + off); off += (size_t)4096 * 128 * 2;
    unsigned short* Ebf = (unsigned short*)abuf;
    unsigned short* Sbf = (unsigned short*)((char*)abuf + SZH);
    unsigned short* Fbf = (unsigned short*)((char*)kkbuf + SZH);
    float* cwL  = (float*)hw;
    float* dotb = (float*)ha;

    k_prep<<<3072, 256, 0, stream>>>(x, mr, mw, mk, mv, ma, mg, X6);
    k_transpose_all<<<2688, 256, 0, stream>>>(Wr, Wk, Wv, Wo, w1, w2, a1, a2, g1, g2,
                                              WrT, WkT, WvT, WoT, w1T, w2T, a1T, a2T, g1T, g2T);
    k_gemm<2><<<dim3(1, 64), 256, 0, stream>>>(X6 + 1 * BTC, w1T, hw, nullptr, 4096, 64, 768);
    k_gemm<1><<<dim3(1, 64), 256, 0, stream>>>(X6 + 4 * BTC, a1T, ha, nullptr, 4096, 64, 768);
    k_gemm<5><<<dim3(2, 64), 256, 0, stream>>>(X6 + 5 * BTC, g1T, hg, nullptr, 4096, 128, 768);
    k_gemm128wa<<<dim3(6, 32, 2), 256, 0, stream>>>(hw, ha, w2T, a2T, wdec, abuf, w0, a0);
    {
        GemmSet S;
        S.A[0] = hg;            S.Bt[0] = g2T; S.C[0] = gbuf; S.K[0] = 128;
        S.A[1] = X6 + 0 * BTC;  S.Bt[1] = WrT; S.C[1] = rbuf; S.K[1] = 768;
        S.A[2] = X6 + 2 * BTC;  S.Bt[2] = WkT; S.C[2] = kbuf; S.K[2] = 768;
        S.A[3] = X6 + 3 * BTC;  S.Bt[3] = WvT; S.C[3] = vbuf; S.K[3] = 768;
        k_gemm128b<<<dim3(6, 32, 4), 256, 0, stream>>>(S);
    }
    k_kproc<<<12288, 256, 0, stream>>>(kbuf, abuf, rbuf, k_k, k_a, r_k, kkbuf, dotb);
    k_scanprep<<<HC_, 256, 0, stream>>>(wdec, kkbuf, abuf, kbuf, rbuf, Abf, Bbf, Kbf, Rbf, cwL);
    k_chunk<<<HC_, 512, 0, stream>>>(Abf, Bbf, Kbf, Rbf, vbuf, cwL, Ttbf, Zbf, Ebf, Fbf);
    k_phaseB<<<48, 256, 0, stream>>>(Ttbf, Zbf, Sbf);
    k_phaseC<<<HC_, 256, 0, stream>>>(Ebf, Sbf, Fbf, obuf);
    k_gnorm<<<12288, 256, 0, stream>>>(obuf, vbuf, gbuf, dotb, gam, bet, ybf);
    k_gemm128<0><<<dim3(6, 32), 256, 0, stream>>>(ybf, WoT, (float*)d_out, nullptr, 4096, 768, 768);
}